// Round 12
// baseline (615.719 us; speedup 1.0000x reference)
//
#include <hip/hip_runtime.h>
#include <cmath>
#include <cstdint>

// Problem constants (from reference)
constexpr int B_ = 8, N_ = 1024, M_ = 512, D_ = 128, S_ = 1536, L_ = 6, DFF_ = 512;
constexpr int ROWS = B_ * S_;    // 12288
constexpr int MAXDEG = 64;       // max attention row degree (actual ~4-20)
constexpr int LKEY = 32;         // LDS-cached keys per row
constexpr int RPB  = 24;         // real rows per block
constexpr int RPAD = 32;         // padded rows in LDS (2 x 16-row MFMA tiles)
constexpr int NBLK = ROWS / RPB; // 512 blocks = 2/CU (resident at ANY vgpr<=256)
constexpr int BPBATCH = S_ / RPB;// 64 blocks per batch (per-batch barrier group)

typedef __bf16 bf16x8 __attribute__((ext_vector_type(8)));
typedef float  f32x4  __attribute__((ext_vector_type(4)));
typedef unsigned short u16x8 __attribute__((ext_vector_type(8)));

__device__ inline unsigned short f2bf(float f) {  // RNE fp32 -> bf16
  unsigned u = __float_as_uint(f);
  u += 0x7fffu + ((u >> 16) & 1u);
  return (unsigned short)(u >> 16);
}
__device__ inline float bf2f(unsigned short u) {
  return __uint_as_float(((unsigned)u) << 16);
}
__device__ inline void ull2f4(unsigned long long u, float* f) {  // 4 bf16 -> fp32
  f[0] = bf2f((unsigned short)(u));
  f[1] = bf2f((unsigned short)(u >> 16));
  f[2] = bf2f((unsigned short)(u >> 32));
  f[3] = bf2f((unsigned short)(u >> 48));
}

// ---------------------------------------------------------------------------
// Adjacency from pcm (one wave per row). exp(-1e9-max) underflows to 0 in
// fp32 => sparse attention over this list == dense masked softmax.
// ---------------------------------------------------------------------------
__global__ void adj_kernel(const int* __restrict__ pcm, int* __restrict__ adj,
                           int* __restrict__ adjcnt) {
  int s = blockIdx.x;
  int lane = threadIdx.x;
  int count = 0;
  for (int base = 0; base < S_; base += 64) {
    int k = base + lane;
    bool allowed;
    if (k == s) allowed = true;
    else if (s < N_ && k >= N_) allowed = pcm[(k - N_) * N_ + s] != 0;
    else if (s >= N_ && k < N_) allowed = pcm[(s - N_) * N_ + k] != 0;
    else allowed = false;
    unsigned long long bal = __ballot(allowed);
    if (allowed) {
      int slot = count + __popcll(bal & ((1ull << lane) - 1ull));
      if (slot < MAXDEG) adj[s * MAXDEG + slot] = k;
    }
    count += __popcll(bal);
  }
  if (lane == 0) adjcnt[s] = count < MAXDEG ? count : MAXDEG;
}

// ---------------------------------------------------------------------------
// x init; also zeroes the 8 per-batch barrier counters (ws poisoned 0xAA).
// ---------------------------------------------------------------------------
__global__ void xinit_kernel(const float* __restrict__ r_t, const int* __restrict__ adj,
                             const int* __restrict__ adjcnt, const float* __restrict__ se,
                             const int* __restrict__ tt, const float* __restrict__ table,
                             float* __restrict__ x, unsigned* __restrict__ barrier_cnt) {
  int bs = blockIdx.x;
  int b = bs / S_, s = bs % S_;
  int d = threadIdx.x;
  if (bs < 8 && d == 0)
    __hip_atomic_store(barrier_cnt + bs * 32, 0u, __ATOMIC_RELAXED, __HIP_MEMORY_SCOPE_AGENT);
  float node;
  if (s < N_) {
    node = fabsf(r_t[b * N_ + s]);
  } else {
    int cnt = adjcnt[s];
    float sum = 0.f;
    for (int j = 0; j < cnt; ++j) {
      int k = adj[s * MAXDEG + j];
      if (k < N_) {
        float r = r_t[b * N_ + k];
        sum += (r < 0.f) ? 1.f : (r > 0.f ? 0.f : 0.5f);
      }
    }
    node = fmodf(sum, 2.0f);
  }
  x[(size_t)bs * D_ + d] = table[tt[b] * D_ + d] * se[s * D_ + d] * node;
}

// ---------------------------------------------------------------------------
// Weight convert: fp32 [K][N] -> bf16 transposed [N][K], per layer packed as
//   [3*128][128] (q,k,v) | [128][128] (o) | [512][128] (w1) | [128][512] (w2)
// ---------------------------------------------------------------------------
constexpr int WSEG_QKV = 3 * D_ * D_;
constexpr int WSEG_O   = D_ * D_;
constexpr int WSEG_1   = D_ * DFF_;
constexpr int WSEG_2   = DFF_ * D_;
constexpr int WLAYER   = WSEG_QKV + WSEG_O + WSEG_1 + WSEG_2;  // 196608

__global__ void wconv_kernel(const float* __restrict__ Wq, const float* __restrict__ Wk,
                             const float* __restrict__ Wv, const float* __restrict__ Wo,
                             const float* __restrict__ W1, const float* __restrict__ W2,
                             unsigned short* __restrict__ out) {
  int idx = blockIdx.x * blockDim.x + threadIdx.x;
  if (idx >= L_ * WLAYER) return;
  int l = idx / WLAYER, r = idx % WLAYER;
  float v;
  if (r < WSEG_QKV) {
    int which = r / (D_ * D_), i = r % (D_ * D_);
    int n = i / D_, kk = i % D_;
    const float* W = which == 0 ? Wq : (which == 1 ? Wk : Wv);
    v = W[(size_t)l * D_ * D_ + kk * D_ + n];
  } else if (r < WSEG_QKV + WSEG_O) {
    int i = r - WSEG_QKV;
    int n = i / D_, kk = i % D_;
    v = Wo[(size_t)l * D_ * D_ + kk * D_ + n];
  } else if (r < WSEG_QKV + WSEG_O + WSEG_1) {
    int i = r - WSEG_QKV - WSEG_O;
    int n = i / D_, kk = i % D_;
    v = W1[(size_t)l * D_ * DFF_ + kk * DFF_ + n];
  } else {
    int i = r - WSEG_QKV - WSEG_O - WSEG_1;
    int n = i / DFF_, kk = i % DFF_;
    v = W2[(size_t)l * DFF_ * D_ + kk * D_ + n];
  }
  out[idx] = f2bf(v);
}

// ---------------------------------------------------------------------------
// MFMA helper: wave tile = 16 rows x 64 cols (4 tiles of 16x16), K=128 in 4
// steps of 32. LDS: 16B chunks XOR-swizzled [row*128 + ((c^(row&15))<<3)].
// ---------------------------------------------------------------------------
__device__ __forceinline__ void mfma4(const unsigned short* As, const unsigned short* Bs,
                                      int rowbase, int colbase, int quad, int l16,
                                      f32x4 (&acc)[4]) {
#pragma unroll
  for (int kk = 0; kk < 4; ++kk) {
    int cb = kk * 4 + quad;
    int row = rowbase + l16;
    bf16x8 a = __builtin_bit_cast(bf16x8, *(const uint4*)&As[row * 128 + ((cb ^ (row & 15)) << 3)]);
    bf16x8 bb[4];
#pragma unroll
    for (int ct = 0; ct < 4; ++ct) {
      int n = colbase + ct * 16 + l16;
      bb[ct] = __builtin_bit_cast(bf16x8, *(const uint4*)&Bs[n * 128 + ((cb ^ (n & 15)) << 3)]);
    }
#pragma unroll
    for (int ct = 0; ct < 4; ++ct)
      acc[ct] = __builtin_amdgcn_mfma_f32_16x16x32_bf16(a, bb[ct], acc[ct], 0, 0, 0);
  }
}

// ---------------------------------------------------------------------------
// Fence-free grid barrier (R10-proven): kv is the only cross-block data and
// all kv traffic is agent-scope atomic (LLC-coherent, bypasses per-XCD L2).
// __syncthreads drains each wave's stores before the counter bump.
// Per-batch counters: only same-batch blocks (64) participate. All blocks
// hardware-resident by construction (2/CU fits at any VGPR<=256, LDS 53K*2).
// ---------------------------------------------------------------------------
__device__ __forceinline__ void grid_barrier(unsigned* cnt, unsigned target) {
  __syncthreads();
  if (threadIdx.x == 0) {
    __hip_atomic_fetch_add(cnt, 1u, __ATOMIC_RELAXED, __HIP_MEMORY_SCOPE_AGENT);
    while (__hip_atomic_load(cnt, __ATOMIC_RELAXED, __HIP_MEMORY_SCOPE_AGENT) < target)
      __builtin_amdgcn_s_sleep(4);
  }
  __syncthreads();
}

// ---------------------------------------------------------------------------
// Persistent mega-kernel: all 6 layers + fc head.
// grid = 512 blocks x 256 thr (4 waves); block owns 24 real rows (padded to
// 32 in LDS; pad rows carry garbage confined to the row dimension, discarded
// at every store). 2 blocks/CU so one block's staging/barrier stalls hide
// under the other's compute. Wave (wr,wc): rows [16wr,+16), cols [64wc,+64).
// x in registers; Q block-local (Cs); bf16 K/V cross blocks via agent
// atomics (dbuffered); per-batch fence-free barrier.
// LDS: As 8K + Bs 32K + Cs 8K + sKeys 3K + red 0.5K ~= 52 KB -> 2/CU.
// ---------------------------------------------------------------------------
__global__ void __launch_bounds__(256) mega_kernel(
    const float* __restrict__ x0, unsigned short* __restrict__ kv0,
    unsigned short* __restrict__ kv1, const unsigned short* __restrict__ wbf,
    const float* __restrict__ g1, const float* __restrict__ b1,
    const float* __restrict__ g2, const float* __restrict__ b2,
    const int* __restrict__ tt, const float* __restrict__ table,
    const int* __restrict__ adj, const int* __restrict__ adjc,
    const float* __restrict__ fcw, const float* __restrict__ fcb,
    float* __restrict__ out, unsigned* barrier_cnt) {
  __shared__ unsigned short As[RPAD * 128];   // 8 KB
  __shared__ unsigned short Bs[128 * 128];    // 32 KB
  __shared__ unsigned short Cs[RPAD * 128];   // 8 KB (Q, then FFN hf)
  __shared__ float red1[2][RPAD], red2[2][RPAD];
  __shared__ int sKeys[RPB * LKEY];           // 3 KB
  __shared__ int sCnt[RPB];
  const int row0 = blockIdx.x * RPB;
  const int b = row0 / S_;
  const int bS = b * S_;
  const int t = threadIdx.x, w = t >> 6, lane = t & 63, quad = lane >> 4, l16 = lane & 15;
  const int wr = w >> 1, wc = w & 1;
  const int rowbase = wr * 16, colbase = wc * 64;
  const int tbase = tt[b] * D_;
  unsigned* bcnt = barrier_cnt + b * 32;  // per-batch counter, 128 B apart

  // persistent x in registers (MFMA C-layout); pad rows = 0
  f32x4 xreg[4];
#pragma unroll
  for (int ct = 0; ct < 4; ++ct)
#pragma unroll
    for (int i = 0; i < 4; ++i) {
      int rowL = rowbase + quad * 4 + i;
      int col = colbase + ct * 16 + l16;
      xreg[ct][i] = (rowL < RPB) ? x0[(size_t)(row0 + rowL) * D_ + col] : 0.f;
    }
  if (t < RPB) sCnt[t] = adjc[row0 + t - bS];
  for (int i = t; i < RPB * LKEY; i += 256) {
    int r = i / LKEY, j = i % LKEY;
    sKeys[i] = adj[(row0 + r - bS) * MAXDEG + j];  // tail values unused (clamped)
  }

  for (int l = 0; l < L_; ++l) {
    const unsigned short* wl = wbf + (size_t)l * WLAYER;
    const float* g1l = g1 + l * D_;
    const float* b1l = b1 + l * D_;
    const float* g2l = g2 + l * D_;
    const float* b2l = b2 + l * D_;
    unsigned short* kv = (l & 1) ? kv1 : kv0;

    // ---------------- LN1 on register x -> bf16 h in As --------------------
    float mu1[4], rs1[4];
#pragma unroll
    for (int i = 0; i < 4; ++i) {
      float s = xreg[0][i] + xreg[1][i] + xreg[2][i] + xreg[3][i];
      for (int off = 1; off < 16; off <<= 1) s += __shfl_xor(s, off);
      if (l16 == 0) red1[wc][rowbase + quad * 4 + i] = s;
    }
    __syncthreads();
#pragma unroll
    for (int i = 0; i < 4; ++i) {
      int r = rowbase + quad * 4 + i;
      mu1[i] = (red1[0][r] + red1[1][r]) * (1.f / 128.f);
      float sq = 0.f;
#pragma unroll
      for (int ct = 0; ct < 4; ++ct) { float d = xreg[ct][i] - mu1[i]; sq += d * d; }
      for (int off = 1; off < 16; off <<= 1) sq += __shfl_xor(sq, off);
      if (l16 == 0) red2[wc][r] = sq;
    }
    __syncthreads();
#pragma unroll
    for (int i = 0; i < 4; ++i) {
      int r = rowbase + quad * 4 + i;
      rs1[i] = rsqrtf((red2[0][r] + red2[1][r]) * (1.f / 128.f) + 1e-5f);
    }
#pragma unroll
    for (int ct = 0; ct < 4; ++ct)
#pragma unroll
      for (int i = 0; i < 4; ++i) {
        int rowL = rowbase + quad * 4 + i;
        int col = colbase + ct * 16 + l16;
        float h = (xreg[ct][i] - mu1[i]) * rs1[i] * g1l[col] + b1l[col];
        As[rowL * 128 + (((col >> 3) ^ (rowL & 15)) << 3) + (col & 7)] = f2bf(h);
      }

    // ------- QKV GEMMs: K, V (via Cs -> atomic kv), then Q -> Cs -----------
    const int segs[3] = {1, 2, 0};
    for (int si = 0; si < 3; ++si) {
      const int seg = segs[si];
      for (int i = t; i < 2048; i += 256) {  // Bs <- seg's 128x128 tile
        int rr = i >> 4, cc = i & 15;
        uint4 vb = *(const uint4*)&wl[(size_t)(seg * 128 + rr) * 128 + cc * 8];
        *(uint4*)&Bs[rr * 128 + ((cc ^ (rr & 15)) << 3)] = vb;
      }
      __syncthreads();  // Bs staged; As/Cs hazards covered
      f32x4 acc[4];
#pragma unroll
      for (int j = 0; j < 4; ++j) acc[j] = f32x4{0.f, 0.f, 0.f, 0.f};
      mfma4(As, Bs, rowbase, colbase, quad, l16, acc);
      if (seg == 0) {  // Q -> Cs swizzled A-layout (kept for attention)
#pragma unroll
        for (int ct = 0; ct < 4; ++ct)
#pragma unroll
          for (int i = 0; i < 4; ++i) {
            int rowL = rowbase + quad * 4 + i;
            int col = colbase + ct * 16 + l16;
            Cs[rowL * 128 + (((col >> 3) ^ (rowL & 15)) << 3) + (col & 7)] = f2bf(acc[ct][i]);
          }
      } else {  // K or V: Cs linear -> coalesced agent-scope dword stores
#pragma unroll
        for (int ct = 0; ct < 4; ++ct)
#pragma unroll
          for (int i = 0; i < 4; ++i) {
            int rowL = rowbase + quad * 4 + i;
            int col = colbase + ct * 16 + l16;
            Cs[rowL * 128 + col] = f2bf(acc[ct][i]);
          }
        __syncthreads();
        const int cbase = (seg == 1) ? 0 : 128;
        for (int i = t; i < RPB * 64; i += 256) {  // real rows only
          int rL = i >> 6, cw = i & 63;
          unsigned u = *(const unsigned*)&Cs[rL * 128 + cw * 2];
          __hip_atomic_store((unsigned*)&kv[(size_t)(row0 + rL) * 256 + cbase + cw * 2],
                             u, __ATOMIC_RELAXED, __HIP_MEMORY_SCOPE_AGENT);
        }
      }
      __syncthreads();  // before next seg overwrites Bs/Cs
    }

    // -------- per-batch fence-free barrier: batch kv visible ---------------
    grid_barrier(bcnt, (unsigned)(BPBATCH * (l + 1)));

    // stage Bs <- Wo^T (flies under the attention gather)
    for (int i = t; i < 2048; i += 256) {
      int rr = i >> 4, cc = i & 15;
      uint4 vb = *(const uint4*)&wl[(size_t)(WSEG_QKV + rr * 128 + cc * 8)];
      *(uint4*)&Bs[rr * 128 + ((cc ^ (rr & 15)) << 3)] = vb;
    }

    // ---------------- attention (24 rows x 8 heads = 192 tasks) ------------
    if (t < RPB * 8) {
      const int rL = t >> 3, h = t & 7;
      const int s = row0 + rL - bS;
      const int cnt = sCnt[rL];
      float q[16];
      {
        u16x8 qa = *(const u16x8*)&Cs[rL * 128 + (((2 * h) ^ (rL & 15)) << 3)];
        u16x8 qb = *(const u16x8*)&Cs[rL * 128 + (((2 * h + 1) ^ (rL & 15)) << 3)];
#pragma unroll
        for (int j = 0; j < 8; ++j) { q[j] = bf2f(qa[j]); q[8 + j] = bf2f(qb[j]); }
      }
      float m = -1e30f, lsum = 0.f;
      float o16[16];
#pragma unroll
      for (int j = 0; j < 16; ++j) o16[j] = 0.f;
      for (int jb = 0; jb < cnt; jb += 4) {  // 4 neighbors in flight
        unsigned long long K[4][4], V[4][4];
#pragma unroll
        for (int u = 0; u < 4; ++u) {
          int j = jb + u;
          int key = 0;
          if (j < cnt) key = (j < LKEY) ? sKeys[rL * LKEY + j] : adj[s * MAXDEG + j];
          const unsigned long long* kp =
              (const unsigned long long*)(kv + (size_t)(bS + key) * 256 + h * 16);
#pragma unroll
          for (int c = 0; c < 4; ++c) {
            K[u][c] = __hip_atomic_load(kp + c, __ATOMIC_RELAXED, __HIP_MEMORY_SCOPE_AGENT);
            V[u][c] = __hip_atomic_load(kp + 32 + c, __ATOMIC_RELAXED, __HIP_MEMORY_SCOPE_AGENT);
          }
        }
#pragma unroll
        for (int u = 0; u < 4; ++u) {
          float kf[16], vf[16];
#pragma unroll
          for (int c = 0; c < 4; ++c) { ull2f4(K[u][c], kf + 4 * c); ull2f4(V[u][c], vf + 4 * c); }
          float dot = 0.f;
#pragma unroll
          for (int j = 0; j < 16; ++j) dot = fmaf(q[j], kf[j], dot);
          dot *= 0.25f;  // 1/sqrt(HD)
          if (jb + u >= cnt) dot = -1e30f;
          const float mn = fmaxf(m, dot);
          const float rescale = __expf(m - mn);
          const float e = __expf(dot - mn);
          lsum = lsum * rescale + e;
#pragma unroll
          for (int j = 0; j < 16; ++j) o16[j] = o16[j] * rescale + e * vf[j];
          m = mn;
        }
      }
      const float inv = 1.f / lsum;
      u16x8 pk0, pk1;
#pragma unroll
      for (int j = 0; j < 8; ++j) {
        pk0[j] = f2bf(o16[j] * inv);
        pk1[j] = f2bf(o16[8 + j] * inv);
      }
      *(u16x8*)&As[rL * 128 + (((2 * h) ^ (rL & 15)) << 3)] = pk0;
      *(u16x8*)&As[rL * 128 + (((2 * h + 1) ^ (rL & 15)) << 3)] = pk1;
    }
    __syncthreads();  // As(o) + Bs(Wo) ready (pad rows of As keep stale h)

    // ---------------- x' = x + o@Wo; LN2*te; FFN; residual -----------------
    f32x4 acc1[4];
#pragma unroll
    for (int j = 0; j < 4; ++j) acc1[j] = f32x4{0.f, 0.f, 0.f, 0.f};
    mfma4(As, Bs, rowbase, colbase, quad, l16, acc1);
    f32x4 xp[4];
#pragma unroll
    for (int ct = 0; ct < 4; ++ct)
#pragma unroll
      for (int i = 0; i < 4; ++i) xp[ct][i] = xreg[ct][i] + acc1[ct][i];
#pragma unroll
    for (int i = 0; i < 4; ++i) {
      float s = xp[0][i] + xp[1][i] + xp[2][i] + xp[3][i];
      for (int off = 1; off < 16; off <<= 1) s += __shfl_xor(s, off);
      if (l16 == 0) red1[wc][rowbase + quad * 4 + i] = s;
    }
    __syncthreads();
    float mu_[4], rs_[4];
#pragma unroll
    for (int i = 0; i < 4; ++i) {
      int r = rowbase + quad * 4 + i;
      mu_[i] = (red1[0][r] + red1[1][r]) * (1.f / 128.f);
      float sq = 0.f;
#pragma unroll
      for (int ct = 0; ct < 4; ++ct) { float d = xp[ct][i] - mu_[i]; sq += d * d; }
      for (int off = 1; off < 16; off <<= 1) sq += __shfl_xor(sq, off);
      if (l16 == 0) red2[wc][r] = sq;
    }
    __syncthreads();
#pragma unroll
    for (int i = 0; i < 4; ++i) {
      int r = rowbase + quad * 4 + i;
      rs_[i] = rsqrtf((red2[0][r] + red2[1][r]) * (1.f / 128.f) + 1e-5f);
    }
#pragma unroll
    for (int ct = 0; ct < 4; ++ct)
#pragma unroll
      for (int i = 0; i < 4; ++i) {
        int rowL = rowbase + quad * 4 + i;
        int col = colbase + ct * 16 + l16;
        float h2 = (xp[ct][i] - mu_[i]) * rs_[i] * g2l[col] + b2l[col];
        h2 *= table[tbase + col];
        As[rowL * 128 + (((col >> 3) ^ (rowL & 15)) << 3) + (col & 7)] = f2bf(h2);
      }
    f32x4 acc2[4];
#pragma unroll
    for (int j = 0; j < 4; ++j) acc2[j] = f32x4{0.f, 0.f, 0.f, 0.f};
    const unsigned short* w1 = wl + WSEG_QKV + WSEG_O;
    const unsigned short* w2 = wl + WSEG_QKV + WSEG_O + WSEG_1;
    for (int c = 0; c < 4; ++c) {
      for (int i = t; i < 2048; i += 256) {
        int rr = i >> 4, cc = i & 15;
        uint4 vb = *(const uint4*)&w1[(size_t)(c * 128 + rr) * 128 + cc * 8];
        *(uint4*)&Bs[rr * 128 + ((cc ^ (rr & 15)) << 3)] = vb;
      }
      __syncthreads();
      f32x4 accF[4];
#pragma unroll
      for (int j = 0; j < 4; ++j) accF[j] = f32x4{0.f, 0.f, 0.f, 0.f};
      mfma4(As, Bs, rowbase, colbase, quad, l16, accF);
#pragma unroll
      for (int ct = 0; ct < 4; ++ct)
#pragma unroll
        for (int i = 0; i < 4; ++i) {
          int rowL = rowbase + quad * 4 + i;
          int col = colbase + ct * 16 + l16;
          Cs[rowL * 128 + (((col >> 3) ^ (rowL & 15)) << 3) + (col & 7)] =
              f2bf(fmaxf(accF[ct][i], 0.f));
        }
      __syncthreads();  // Cs(hf) visible; Bs(W1c) reads done
      for (int i = t; i < 2048; i += 256) {
        int rr = i >> 4, cc = i & 15;
        uint4 vb = *(const uint4*)&w2[(size_t)rr * 512 + c * 128 + cc * 8];
        *(uint4*)&Bs[rr * 128 + ((cc ^ (rr & 15)) << 3)] = vb;
      }
      __syncthreads();
      mfma4(Cs, Bs, rowbase, colbase, quad, l16, acc2);
      __syncthreads();  // before next c overwrites Bs
    }
    // epilogue: x'' = x' + ffn (registers only)
    if (l < L_ - 1) {
#pragma unroll
      for (int ct = 0; ct < 4; ++ct)
#pragma unroll
        for (int i = 0; i < 4; ++i) xreg[ct][i] = xp[ct][i] + acc2[ct][i];
    } else {
      float pr[4] = {0.f, 0.f, 0.f, 0.f};
#pragma unroll
      for (int ct = 0; ct < 4; ++ct)
#pragma unroll
        for (int i = 0; i < 4; ++i)
          pr[i] += (xp[ct][i] + acc2[ct][i]) * fcw[colbase + ct * 16 + l16];
#pragma unroll
      for (int i = 0; i < 4; ++i) {
        float s = pr[i];
        for (int off = 1; off < 16; off <<= 1) s += __shfl_xor(s, off);
        if (l16 == 0) red1[wc][rowbase + quad * 4 + i] = s;
      }
      __syncthreads();
      if (wc == 0 && l16 == 0)
#pragma unroll
        for (int i = 0; i < 4; ++i) {
          int rowL = rowbase + quad * 4 + i;
          if (rowL < RPB) out[row0 + rowL] = red1[0][rowL] + red1[1][rowL] + fcb[0];
        }
    }
  }
}

// ---------------------------------------------------------------------------
extern "C" void kernel_launch(void* const* d_in, const int* in_sizes, int n_in,
                              void* d_out, int out_size, void* d_ws, size_t ws_size,
                              hipStream_t stream) {
  const float* r_t       = (const float*)d_in[0];
  const int*   t         = (const int*)d_in[1];
  const int*   pcm       = (const int*)d_in[2];
  const float* src_embed = (const float*)d_in[4];
  const float* time_tab  = (const float*)d_in[5];
  const float* Wq = (const float*)d_in[6];
  const float* Wk = (const float*)d_in[7];
  const float* Wv = (const float*)d_in[8];
  const float* Wo = (const float*)d_in[9];
  const float* W1 = (const float*)d_in[10];
  const float* W2 = (const float*)d_in[11];
  const float* g1 = (const float*)d_in[12];
  const float* b1 = (const float*)d_in[13];
  const float* g2 = (const float*)d_in[14];
  const float* b2 = (const float*)d_in[15];
  const float* fc_w = (const float*)d_in[16];
  const float* fc_b = (const float*)d_in[17];
  float* out = (float*)d_out;

  char* ws = (char*)d_ws;
  size_t off = 0;
  auto alloc = [&](size_t bytes) -> void* {
    void* p = ws + off;
    off = (off + bytes + 255) & ~(size_t)255;
    return p;
  };
  float*          x    = (float*)alloc((size_t)ROWS * D_ * 4);
  unsigned short* kv0  = (unsigned short*)alloc((size_t)ROWS * 256 * 2);
  unsigned short* kv1  = (unsigned short*)alloc((size_t)ROWS * 256 * 2);
  int*            adj  = (int*)alloc((size_t)S_ * MAXDEG * 4);
  int*            adjc = (int*)alloc((size_t)S_ * 4);
  unsigned short* wbf  = (unsigned short*)alloc((size_t)L_ * WLAYER * 2);
  unsigned*       bcnt = (unsigned*)alloc(8 * 32 * 4);

  adj_kernel<<<S_, 64, 0, stream>>>(pcm, adj, adjc);
  wconv_kernel<<<(L_ * WLAYER + 255) / 256, 256, 0, stream>>>(Wq, Wk, Wv, Wo, W1, W2, wbf);
  xinit_kernel<<<ROWS, 128, 0, stream>>>(r_t, adj, adjc, src_embed, t, time_tab, x, bcnt);

  mega_kernel<<<NBLK, 256, 0, stream>>>(x, kv0, kv1, wbf, g1, b1, g2, b2,
                                        t, time_tab, adj, adjc, fc_w, fc_b, out, bcnt);
}

// Round 13
// 322.482 us; speedup vs baseline: 1.9093x; 1.9093x over previous
//
#include <hip/hip_runtime.h>
#include <cmath>
#include <cstdint>

// Problem constants (from reference)
constexpr int B_ = 8, N_ = 1024, M_ = 512, D_ = 128, S_ = 1536, L_ = 6, DFF_ = 512;
constexpr int ROWS = B_ * S_;    // 12288
constexpr int MAXDEG = 64;       // max attention row degree (actual ~4-20)
constexpr int LKEY = 32;         // LDS-cached keys per row
constexpr int RPB  = 48;         // rows per block
constexpr int NBLK = ROWS / RPB; // 256 persistent blocks (1/CU, all resident)
constexpr int NTILE = 12;        // weight tiles per layer, in stage order
constexpr int TILE  = 128 * 128; // halfwords per tile (LDS image, 32 KB)

typedef __bf16 bf16x8 __attribute__((ext_vector_type(8)));
typedef float  f32x4  __attribute__((ext_vector_type(4)));
typedef unsigned short u16x8 __attribute__((ext_vector_type(8)));

__device__ inline unsigned short f2bf(float f) {  // RNE fp32 -> bf16
  unsigned u = __float_as_uint(f);
  u += 0x7fffu + ((u >> 16) & 1u);
  return (unsigned short)(u >> 16);
}
__device__ inline float bf2f(unsigned short u) {
  return __uint_as_float(((unsigned)u) << 16);
}
__device__ inline void ull2f4(unsigned long long u, float* f) {  // 4 bf16 -> fp32
  f[0] = bf2f((unsigned short)(u));
  f[1] = bf2f((unsigned short)(u >> 16));
  f[2] = bf2f((unsigned short)(u >> 32));
  f[3] = bf2f((unsigned short)(u >> 48));
}

// Direct global->LDS async copy, 16 B/lane (m97's lever). LDS dest is
// wave-uniform base + lane*16; global src per-lane. Generic->AS3 via low-32
// truncation (LDS aperture is in the high half of the generic pointer).
__device__ __forceinline__ void async_ld16(const unsigned short* g, unsigned short* l) {
  __builtin_amdgcn_global_load_lds(
      (const __attribute__((address_space(1))) unsigned int*)(uintptr_t)g,
      (__attribute__((address_space(3))) unsigned int*)(unsigned)(uintptr_t)l,
      16, 0, 0);
}
// Issue one 32 KB tile (pre-swizzled LDS image) into Bs buffer: 32 chunks of
// 1 KB; wave w takes chunks w, w+6, ... No VGPRs held (R9's spill avoided).
__device__ __forceinline__ void issue_tile(const unsigned short* tp, unsigned short* bs,
                                           int w, int lane) {
  for (int c = w; c < 32; c += 6)
    async_ld16(tp + c * 512 + lane * 8, bs + c * 512);
}

// ---------------------------------------------------------------------------
// Adjacency from pcm (one wave per row). exp(-1e9-max) underflows to 0 in
// fp32 => sparse attention over this list == dense masked softmax.
// ---------------------------------------------------------------------------
__global__ void adj_kernel(const int* __restrict__ pcm, int* __restrict__ adj,
                           int* __restrict__ adjcnt) {
  int s = blockIdx.x;
  int lane = threadIdx.x;
  int count = 0;
  for (int base = 0; base < S_; base += 64) {
    int k = base + lane;
    bool allowed;
    if (k == s) allowed = true;
    else if (s < N_ && k >= N_) allowed = pcm[(k - N_) * N_ + s] != 0;
    else if (s >= N_ && k < N_) allowed = pcm[(s - N_) * N_ + k] != 0;
    else allowed = false;
    unsigned long long bal = __ballot(allowed);
    if (allowed) {
      int slot = count + __popcll(bal & ((1ull << lane) - 1ull));
      if (slot < MAXDEG) adj[s * MAXDEG + slot] = k;
    }
    count += __popcll(bal);
  }
  if (lane == 0) adjcnt[s] = count < MAXDEG ? count : MAXDEG;
}

// ---------------------------------------------------------------------------
// x init; also zeroes the grid-barrier counter (ws poisoned 0xAA per call).
// ---------------------------------------------------------------------------
__global__ void xinit_kernel(const float* __restrict__ r_t, const int* __restrict__ adj,
                             const int* __restrict__ adjcnt, const float* __restrict__ se,
                             const int* __restrict__ tt, const float* __restrict__ table,
                             float* __restrict__ x, unsigned* __restrict__ barrier_cnt) {
  int bs = blockIdx.x;
  int b = bs / S_, s = bs % S_;
  int d = threadIdx.x;
  if (bs == 0 && d == 0)
    __hip_atomic_store(barrier_cnt, 0u, __ATOMIC_RELAXED, __HIP_MEMORY_SCOPE_AGENT);
  float node;
  if (s < N_) {
    node = fabsf(r_t[b * N_ + s]);
  } else {
    int cnt = adjcnt[s];
    float sum = 0.f;
    for (int j = 0; j < cnt; ++j) {
      int k = adj[s * MAXDEG + j];
      if (k < N_) {
        float r = r_t[b * N_ + k];
        sum += (r < 0.f) ? 1.f : (r > 0.f ? 0.f : 0.5f);
      }
    }
    node = fmodf(sum, 2.0f);
  }
  x[(size_t)bs * D_ + d] = table[tt[b] * D_ + d] * se[s * D_ + d] * node;
}

// ---------------------------------------------------------------------------
// Weight convert: fp32 -> bf16, emitted as pre-swizzled 128x128 LDS-image
// tiles in per-layer stage order: [0]=Wk^T [1]=Wv^T [2]=Wq^T [3]=Wo^T
// [4+2c]=W1^T chunk c (out cols c*128..) [5+2c]=W2^T k-chunk c.
// LDS image: tile[rr*128 + ((cc^(rr&15))<<3) + e] = W^T[rr][cc*8+e].
// ---------------------------------------------------------------------------
constexpr int WLAYER = NTILE * TILE;  // 196608 halfwords per layer

__global__ void wconv_kernel(const float* __restrict__ Wq, const float* __restrict__ Wk,
                             const float* __restrict__ Wv, const float* __restrict__ Wo,
                             const float* __restrict__ W1, const float* __restrict__ W2,
                             unsigned short* __restrict__ out) {
  int idx = blockIdx.x * blockDim.x + threadIdx.x;
  if (idx >= L_ * WLAYER) return;
  int l = idx / WLAYER, r = idx % WLAYER;
  int tile = r >> 14;        // /16384
  int p = r & 16383;
  int rr = p >> 7;           // output col n (0..127)
  int e  = p & 7;
  int sw = (p >> 3) & 15;
  int cc = sw ^ (rr & 15);
  int kd = cc * 8 + e;       // K element (0..127)
  float v;
  if (tile == 0)      v = Wk[(size_t)l * D_ * D_ + kd * D_ + rr];
  else if (tile == 1) v = Wv[(size_t)l * D_ * D_ + kd * D_ + rr];
  else if (tile == 2) v = Wq[(size_t)l * D_ * D_ + kd * D_ + rr];
  else if (tile == 3) v = Wo[(size_t)l * D_ * D_ + kd * D_ + rr];
  else {
    int c = (tile - 4) >> 1;
    if (((tile - 4) & 1) == 0) v = W1[(size_t)l * D_ * DFF_ + kd * DFF_ + c * 128 + rr];
    else                       v = W2[(size_t)l * DFF_ * D_ + (c * 128 + kd) * D_ + rr];
  }
  out[idx] = f2bf(v);
}

// ---------------------------------------------------------------------------
// MFMA helper: wave tile = 16 rows x 64 cols (4 tiles of 16x16), K=128 in 4
// steps of 32. LDS: 16B chunks XOR-swizzled [row*128 + ((c^(row&15))<<3)].
// ---------------------------------------------------------------------------
__device__ __forceinline__ void mfma4(const unsigned short* As, const unsigned short* Bs,
                                      int rowbase, int colbase, int quad, int l16,
                                      f32x4 (&acc)[4]) {
#pragma unroll
  for (int kk = 0; kk < 4; ++kk) {
    int cb = kk * 4 + quad;
    int row = rowbase + l16;
    bf16x8 a = __builtin_bit_cast(bf16x8, *(const uint4*)&As[row * 128 + ((cb ^ (row & 15)) << 3)]);
    bf16x8 bb[4];
#pragma unroll
    for (int ct = 0; ct < 4; ++ct) {
      int n = colbase + ct * 16 + l16;
      bb[ct] = __builtin_bit_cast(bf16x8, *(const uint4*)&Bs[n * 128 + ((cb ^ (n & 15)) << 3)]);
    }
#pragma unroll
    for (int ct = 0; ct < 4; ++ct)
      acc[ct] = __builtin_amdgcn_mfma_f32_16x16x32_bf16(a, bb[ct], acc[ct], 0, 0, 0);
  }
}

// ---------------------------------------------------------------------------
// Fence-free grid barrier (R10-proven): kv is the only cross-block data and
// all kv traffic is agent-scope atomic (LLC-coherent). __syncthreads drains
// each wave's stores (and async LDS loads) before the counter bump.
// ---------------------------------------------------------------------------
__device__ __forceinline__ void grid_barrier(unsigned* cnt, unsigned target) {
  __syncthreads();
  if (threadIdx.x == 0) {
    __hip_atomic_fetch_add(cnt, 1u, __ATOMIC_RELAXED, __HIP_MEMORY_SCOPE_AGENT);
    while (__hip_atomic_load(cnt, __ATOMIC_RELAXED, __HIP_MEMORY_SCOPE_AGENT) < target)
      __builtin_amdgcn_s_sleep(4);
  }
  __syncthreads();
}

// ---------------------------------------------------------------------------
// Persistent mega-kernel: all 6 layers + fc head.
// grid = 256 blocks x 384 thr (6 waves); block owns 48 rows; 1 block/CU.
// Weight staging fully async: double-buffered Bs, each stage issues the NEXT
// tile via global_load_lds then MFMAs on the current one; one barrier/stage.
// x in registers; Q block-local (Cs); K/V staged in KVs then stored as
// agent-scope atomics (cross-block, dbuffered kv); fence-free grid barrier.
// LDS: As 12K + Bs 64K + Cs 12K + KVs 24K + sKeys 6K + red 1K ~= 122 KB.
// ---------------------------------------------------------------------------
__global__ void __launch_bounds__(384) mega_kernel(
    const float* __restrict__ x0, unsigned short* __restrict__ kv0,
    unsigned short* __restrict__ kv1, const unsigned short* __restrict__ wbf,
    const float* __restrict__ g1, const float* __restrict__ b1,
    const float* __restrict__ g2, const float* __restrict__ b2,
    const int* __restrict__ tt, const float* __restrict__ table,
    const int* __restrict__ adj, const int* __restrict__ adjc,
    const float* __restrict__ fcw, const float* __restrict__ fcb,
    float* __restrict__ out, unsigned* barrier_cnt) {
  __shared__ unsigned short As[RPB * 128];      // 12 KB
  __shared__ unsigned short Bs[2][TILE];        // 64 KB (double buffer)
  __shared__ unsigned short Cs[RPB * 128];      // 12 KB (Q, then FFN hf)
  __shared__ unsigned short KVs[RPB * 256];     // 24 KB (K|V repack)
  __shared__ float red1[2][RPB], red2[2][RPB];
  __shared__ int sKeys[RPB * LKEY];             // 6 KB
  __shared__ int sCnt[RPB];
  const int row0 = blockIdx.x * RPB;
  const int b = row0 / S_;
  const int bS = b * S_;
  const int t = threadIdx.x, w = t >> 6, lane = t & 63, quad = lane >> 4, l16 = lane & 15;
  const int wr = w >> 1, wc = w & 1;
  const int rowbase = wr * 16, colbase = wc * 64;
  const int tbase = tt[b] * D_;

  // prime the pipeline: layer-0 K tile -> Bs[0] (drained by LN1's barrier)
  issue_tile(wbf, Bs[0], w, lane);

  // persistent x in registers (MFMA C-layout)
  f32x4 xreg[4];
#pragma unroll
  for (int ct = 0; ct < 4; ++ct)
#pragma unroll
    for (int i = 0; i < 4; ++i) {
      int row = row0 + rowbase + quad * 4 + i;
      int col = colbase + ct * 16 + l16;
      xreg[ct][i] = x0[(size_t)row * D_ + col];
    }
  if (t < RPB) sCnt[t] = adjc[row0 + t - bS];
  for (int i = t; i < RPB * LKEY; i += 384) {
    int r = i / LKEY, j = i % LKEY;
    sKeys[i] = adj[(row0 + r - bS) * MAXDEG + j];  // tail values unused (clamped)
  }

  for (int l = 0; l < L_; ++l) {
    const unsigned short* wt = wbf + (size_t)l * WLAYER;  // stage s tile = wt + s*TILE
    const float* g1l = g1 + l * D_;
    const float* b1l = b1 + l * D_;
    const float* g2l = g2 + l * D_;
    const float* b2l = b2 + l * D_;
    unsigned short* kv = (l & 1) ? kv1 : kv0;

    // ---------------- LN1 on register x -> bf16 h in As --------------------
    float mu1[4], rs1[4];
#pragma unroll
    for (int i = 0; i < 4; ++i) {
      float s = xreg[0][i] + xreg[1][i] + xreg[2][i] + xreg[3][i];
      for (int off = 1; off < 16; off <<= 1) s += __shfl_xor(s, off);
      if (l16 == 0) red1[wc][rowbase + quad * 4 + i] = s;
    }
    __syncthreads();
#pragma unroll
    for (int i = 0; i < 4; ++i) {
      int r = rowbase + quad * 4 + i;
      mu1[i] = (red1[0][r] + red1[1][r]) * (1.f / 128.f);
      float sq = 0.f;
#pragma unroll
      for (int ct = 0; ct < 4; ++ct) { float d = xreg[ct][i] - mu1[i]; sq += d * d; }
      for (int off = 1; off < 16; off <<= 1) sq += __shfl_xor(sq, off);
      if (l16 == 0) red2[wc][r] = sq;
    }
    __syncthreads();
#pragma unroll
    for (int i = 0; i < 4; ++i) {
      int r = rowbase + quad * 4 + i;
      rs1[i] = rsqrtf((red2[0][r] + red2[1][r]) * (1.f / 128.f) + 1e-5f);
    }
#pragma unroll
    for (int ct = 0; ct < 4; ++ct)
#pragma unroll
      for (int i = 0; i < 4; ++i) {
        int rowL = rowbase + quad * 4 + i;
        int col = colbase + ct * 16 + l16;
        float h = (xreg[ct][i] - mu1[i]) * rs1[i] * g1l[col] + b1l[col];
        As[rowL * 128 + (((col >> 3) ^ (rowL & 15)) << 3) + (col & 7)] = f2bf(h);
      }
    __syncthreads();  // As(h) ready; K tile (issued last stage) drained

    // ---------------- stage 0: K -> KVs[:,0:128) ---------------------------
    issue_tile(wt + 1 * TILE, Bs[1], w, lane);   // V
    {
      f32x4 acc[4];
#pragma unroll
      for (int j = 0; j < 4; ++j) acc[j] = f32x4{0.f, 0.f, 0.f, 0.f};
      mfma4(As, Bs[0], rowbase, colbase, quad, l16, acc);
#pragma unroll
      for (int ct = 0; ct < 4; ++ct)
#pragma unroll
        for (int i = 0; i < 4; ++i) {
          int rowL = rowbase + quad * 4 + i;
          KVs[rowL * 256 + colbase + ct * 16 + l16] = f2bf(acc[ct][i]);
        }
    }
    __syncthreads();
    // ---------------- stage 1: V -> KVs[:,128:256) -------------------------
    issue_tile(wt + 2 * TILE, Bs[0], w, lane);   // Q
    {
      f32x4 acc[4];
#pragma unroll
      for (int j = 0; j < 4; ++j) acc[j] = f32x4{0.f, 0.f, 0.f, 0.f};
      mfma4(As, Bs[1], rowbase, colbase, quad, l16, acc);
#pragma unroll
      for (int ct = 0; ct < 4; ++ct)
#pragma unroll
        for (int i = 0; i < 4; ++i) {
          int rowL = rowbase + quad * 4 + i;
          KVs[rowL * 256 + 128 + colbase + ct * 16 + l16] = f2bf(acc[ct][i]);
        }
    }
    __syncthreads();
    // ---------------- stage 2: Q -> Cs; kv <- KVs (agent atomics) ----------
    issue_tile(wt + 3 * TILE, Bs[1], w, lane);   // Wo
    {
      f32x4 acc[4];
#pragma unroll
      for (int j = 0; j < 4; ++j) acc[j] = f32x4{0.f, 0.f, 0.f, 0.f};
      mfma4(As, Bs[0], rowbase, colbase, quad, l16, acc);
#pragma unroll
      for (int ct = 0; ct < 4; ++ct)
#pragma unroll
        for (int i = 0; i < 4; ++i) {
          int rowL = rowbase + quad * 4 + i;
          int col = colbase + ct * 16 + l16;
          Cs[rowL * 128 + (((col >> 3) ^ (rowL & 15)) << 3) + (col & 7)] = f2bf(acc[ct][i]);
        }
    }
    for (int i = t; i < RPB * 128; i += 384) {  // 128 dwords/row: K|V
      int rL = i >> 7, cw = i & 127;
      unsigned u = *(const unsigned*)&KVs[rL * 256 + cw * 2];
      __hip_atomic_store((unsigned*)&kv[(size_t)(row0 + rL) * 256 + cw * 2],
                         u, __ATOMIC_RELAXED, __HIP_MEMORY_SCOPE_AGENT);
    }

    // -------- fence-free grid barrier: all blocks' kv visible --------------
    grid_barrier(barrier_cnt, (unsigned)(NBLK * (l + 1)));

    // W1c0 loads fly under the whole attention gather
    issue_tile(wt + 4 * TILE, Bs[0], w, lane);

    // ---------------- attention (48 rows x 8 heads, one per thread) --------
    {
      const int rL = t >> 3, h = t & 7;
      const int s = row0 + rL - bS;
      const int cnt = sCnt[rL];
      float q[16];
      {
        u16x8 qa = *(const u16x8*)&Cs[rL * 128 + (((2 * h) ^ (rL & 15)) << 3)];
        u16x8 qb = *(const u16x8*)&Cs[rL * 128 + (((2 * h + 1) ^ (rL & 15)) << 3)];
#pragma unroll
        for (int j = 0; j < 8; ++j) { q[j] = bf2f(qa[j]); q[8 + j] = bf2f(qb[j]); }
      }
      float m = -1e30f, lsum = 0.f;
      float o16[16];
#pragma unroll
      for (int j = 0; j < 16; ++j) o16[j] = 0.f;
      for (int jb = 0; jb < cnt; jb += 4) {  // 4 neighbors in flight
        unsigned long long K[4][4], V[4][4];
#pragma unroll
        for (int u = 0; u < 4; ++u) {
          int j = jb + u;
          int key = 0;
          if (j < cnt) key = (j < LKEY) ? sKeys[rL * LKEY + j] : adj[s * MAXDEG + j];
          const unsigned long long* kp =
              (const unsigned long long*)(kv + (size_t)(bS + key) * 256 + h * 16);
#pragma unroll
          for (int c = 0; c < 4; ++c) {
            K[u][c] = __hip_atomic_load(kp + c, __ATOMIC_RELAXED, __HIP_MEMORY_SCOPE_AGENT);
            V[u][c] = __hip_atomic_load(kp + 32 + c, __ATOMIC_RELAXED, __HIP_MEMORY_SCOPE_AGENT);
          }
        }
#pragma unroll
        for (int u = 0; u < 4; ++u) {
          float kf[16], vf[16];
#pragma unroll
          for (int c = 0; c < 4; ++c) { ull2f4(K[u][c], kf + 4 * c); ull2f4(V[u][c], vf + 4 * c); }
          float dot = 0.f;
#pragma unroll
          for (int j = 0; j < 16; ++j) dot = fmaf(q[j], kf[j], dot);
          dot *= 0.25f;  // 1/sqrt(HD)
          if (jb + u >= cnt) dot = -1e30f;
          const float mn = fmaxf(m, dot);
          const float rescale = __expf(m - mn);
          const float e = __expf(dot - mn);
          lsum = lsum * rescale + e;
#pragma unroll
          for (int j = 0; j < 16; ++j) o16[j] = o16[j] * rescale + e * vf[j];
          m = mn;
        }
      }
      const float inv = 1.f / lsum;
      u16x8 pk0, pk1;
#pragma unroll
      for (int j = 0; j < 8; ++j) {
        pk0[j] = f2bf(o16[j] * inv);
        pk1[j] = f2bf(o16[8 + j] * inv);
      }
      *(u16x8*)&As[rL * 128 + (((2 * h) ^ (rL & 15)) << 3)] = pk0;
      *(u16x8*)&As[rL * 128 + (((2 * h + 1) ^ (rL & 15)) << 3)] = pk1;
    }
    __syncthreads();  // As(o) ready; Wo + W1c0 loads drained

    // ---------------- stage 3: Wo; x'; LN2*te -> As ------------------------
    f32x4 acc1[4];
#pragma unroll
    for (int j = 0; j < 4; ++j) acc1[j] = f32x4{0.f, 0.f, 0.f, 0.f};
    mfma4(As, Bs[1], rowbase, colbase, quad, l16, acc1);
    f32x4 xp[4];
#pragma unroll
    for (int ct = 0; ct < 4; ++ct)
#pragma unroll
      for (int i = 0; i < 4; ++i) xp[ct][i] = xreg[ct][i] + acc1[ct][i];
#pragma unroll
    for (int i = 0; i < 4; ++i) {
      float s = xp[0][i] + xp[1][i] + xp[2][i] + xp[3][i];
      for (int off = 1; off < 16; off <<= 1) s += __shfl_xor(s, off);
      if (l16 == 0) red1[wc][rowbase + quad * 4 + i] = s;
    }
    __syncthreads();  // also: all As(o) reads complete -> safe to rewrite As
    float mu_[4], rs_[4];
#pragma unroll
    for (int i = 0; i < 4; ++i) {
      int r = rowbase + quad * 4 + i;
      mu_[i] = (red1[0][r] + red1[1][r]) * (1.f / 128.f);
      float sq = 0.f;
#pragma unroll
      for (int ct = 0; ct < 4; ++ct) { float d = xp[ct][i] - mu_[i]; sq += d * d; }
      for (int off = 1; off < 16; off <<= 1) sq += __shfl_xor(sq, off);
      if (l16 == 0) red2[wc][r] = sq;
    }
    __syncthreads();
#pragma unroll
    for (int i = 0; i < 4; ++i) {
      int r = rowbase + quad * 4 + i;
      rs_[i] = rsqrtf((red2[0][r] + red2[1][r]) * (1.f / 128.f) + 1e-5f);
    }
#pragma unroll
    for (int ct = 0; ct < 4; ++ct)
#pragma unroll
      for (int i = 0; i < 4; ++i) {
        int rowL = rowbase + quad * 4 + i;
        int col = colbase + ct * 16 + l16;
        float h2 = (xp[ct][i] - mu_[i]) * rs_[i] * g2l[col] + b2l[col];
        h2 *= table[tbase + col];
        As[rowL * 128 + (((col >> 3) ^ (rowL & 15)) << 3) + (col & 7)] = f2bf(h2);
      }
    __syncthreads();  // h2 visible; stage-3 Bs[1] reads done

    // ---------------- FFN: stages 4..11, pipelined -------------------------
    f32x4 acc2[4];
#pragma unroll
    for (int j = 0; j < 4; ++j) acc2[j] = f32x4{0.f, 0.f, 0.f, 0.f};
    for (int c = 0; c < 4; ++c) {
      // stage 4+2c: W1 chunk c (Bs[0])
      issue_tile(wt + (5 + 2 * c) * TILE, Bs[1], w, lane);  // W2 chunk c
      f32x4 accF[4];
#pragma unroll
      for (int j = 0; j < 4; ++j) accF[j] = f32x4{0.f, 0.f, 0.f, 0.f};
      mfma4(As, Bs[0], rowbase, colbase, quad, l16, accF);
#pragma unroll
      for (int ct = 0; ct < 4; ++ct)
#pragma unroll
        for (int i = 0; i < 4; ++i) {
          int rowL = rowbase + quad * 4 + i;
          int col = colbase + ct * 16 + l16;
          Cs[rowL * 128 + (((col >> 3) ^ (rowL & 15)) << 3) + (col & 7)] =
              f2bf(fmaxf(accF[ct][i], 0.f));
        }
      __syncthreads();  // hf visible; W2c loads drained; Bs[0] reads done
      // stage 5+2c: W2 chunk c (Bs[1])
      if (c < 3) issue_tile(wt + (6 + 2 * c) * TILE, Bs[0], w, lane);   // W1 c+1
      else if (l < L_ - 1) issue_tile(wt + WLAYER, Bs[0], w, lane);     // next K
      mfma4(Cs, Bs[1], rowbase, colbase, quad, l16, acc2);
      __syncthreads();  // W1c+1/K loads... drained NEXT barrier; Bs[1] free
    }
    // epilogue: x'' = x' + ffn (registers only)
    if (l < L_ - 1) {
#pragma unroll
      for (int ct = 0; ct < 4; ++ct)
#pragma unroll
        for (int i = 0; i < 4; ++i) xreg[ct][i] = xp[ct][i] + acc2[ct][i];
    } else {
      float pr[4] = {0.f, 0.f, 0.f, 0.f};
#pragma unroll
      for (int ct = 0; ct < 4; ++ct)
#pragma unroll
        for (int i = 0; i < 4; ++i)
          pr[i] += (xp[ct][i] + acc2[ct][i]) * fcw[colbase + ct * 16 + l16];
#pragma unroll
      for (int i = 0; i < 4; ++i) {
        float s = pr[i];
        for (int off = 1; off < 16; off <<= 1) s += __shfl_xor(s, off);
        if (l16 == 0) red1[wc][rowbase + quad * 4 + i] = s;
      }
      __syncthreads();
      if (wc == 0 && l16 == 0)
#pragma unroll
        for (int i = 0; i < 4; ++i) {
          int r = rowbase + quad * 4 + i;
          out[row0 + r] = red1[0][r] + red1[1][r] + fcb[0];
        }
    }
  }
}

// ---------------------------------------------------------------------------
extern "C" void kernel_launch(void* const* d_in, const int* in_sizes, int n_in,
                              void* d_out, int out_size, void* d_ws, size_t ws_size,
                              hipStream_t stream) {
  const float* r_t       = (const float*)d_in[0];
  const int*   t         = (const int*)d_in[1];
  const int*   pcm       = (const int*)d_in[2];
  const float* src_embed = (const float*)d_in[4];
  const float* time_tab  = (const float*)d_in[5];
  const float* Wq = (const float*)d_in[6];
  const float* Wk = (const float*)d_in[7];
  const float* Wv = (const float*)d_in[8];
  const float* Wo = (const float*)d_in[9];
  const float* W1 = (const float*)d_in[10];
  const float* W2 = (const float*)d_in[11];
  const float* g1 = (const float*)d_in[12];
  const float* b1 = (const float*)d_in[13];
  const float* g2 = (const float*)d_in[14];
  const float* b2 = (const float*)d_in[15];
  const float* fc_w = (const float*)d_in[16];
  const float* fc_b = (const float*)d_in[17];
  float* out = (float*)d_out;

  char* ws = (char*)d_ws;
  size_t off = 0;
  auto alloc = [&](size_t bytes) -> void* {
    void* p = ws + off;
    off = (off + bytes + 255) & ~(size_t)255;
    return p;
  };
  float*          x    = (float*)alloc((size_t)ROWS * D_ * 4);
  unsigned short* kv0  = (unsigned short*)alloc((size_t)ROWS * 256 * 2);
  unsigned short* kv1  = (unsigned short*)alloc((size_t)ROWS * 256 * 2);
  int*            adj  = (int*)alloc((size_t)S_ * MAXDEG * 4);
  int*            adjc = (int*)alloc((size_t)S_ * 4);
  unsigned short* wbf  = (unsigned short*)alloc((size_t)L_ * WLAYER * 2);
  unsigned*       bcnt = (unsigned*)alloc(256);

  adj_kernel<<<S_, 64, 0, stream>>>(pcm, adj, adjc);
  wconv_kernel<<<(L_ * WLAYER + 255) / 256, 256, 0, stream>>>(Wq, Wk, Wv, Wo, W1, W2, wbf);
  xinit_kernel<<<ROWS, 128, 0, stream>>>(r_t, adj, adjc, src_embed, t, time_tab, x, bcnt);

  mega_kernel<<<NBLK, 384, 0, stream>>>(x, kv0, kv1, wbf, g1, b1, g2, b2,
                                        t, time_tab, adj, adjc, fc_w, fc_b, out, bcnt);
}

// Round 14
// 290.324 us; speedup vs baseline: 2.1208x; 1.1108x over previous
//
#include <hip/hip_runtime.h>
#include <cmath>
#include <cstdint>

// Problem constants (from reference)
constexpr int B_ = 8, N_ = 1024, M_ = 512, D_ = 128, S_ = 1536, L_ = 6, DFF_ = 512;
constexpr int ROWS = B_ * S_;    // 12288
constexpr int MAXDEG = 64;       // max attention row degree (actual ~4-20)
constexpr int LKEY = 32;         // LDS-cached keys per row
constexpr int RPB  = 48;         // rows per block
constexpr int NBLK = ROWS / RPB; // 256 persistent blocks (1/CU, all resident)
constexpr int BPB  = S_ / RPB;   // 32 blocks per batch (barrier group)
constexpr int NTILE = 12;        // weight tiles per layer, in stage order
constexpr int TILE  = 128 * 128; // halfwords per tile (LDS image, 32 KB)

typedef __bf16 bf16x8 __attribute__((ext_vector_type(8)));
typedef float  f32x4  __attribute__((ext_vector_type(4)));
typedef unsigned short u16x8 __attribute__((ext_vector_type(8)));

__device__ inline unsigned short f2bf(float f) {  // RNE fp32 -> bf16
  unsigned u = __float_as_uint(f);
  u += 0x7fffu + ((u >> 16) & 1u);
  return (unsigned short)(u >> 16);
}
__device__ inline float bf2f(unsigned short u) {
  return __uint_as_float(((unsigned)u) << 16);
}
__device__ inline void ull2f4(unsigned long long u, float* f) {  // 4 bf16 -> fp32
  f[0] = bf2f((unsigned short)(u));
  f[1] = bf2f((unsigned short)(u >> 16));
  f[2] = bf2f((unsigned short)(u >> 32));
  f[3] = bf2f((unsigned short)(u >> 48));
}

// Direct global->LDS async copy, 16 B/lane (m97's lever).
__device__ __forceinline__ void async_ld16(const unsigned short* g, unsigned short* l) {
  __builtin_amdgcn_global_load_lds(
      (const __attribute__((address_space(1))) unsigned int*)(uintptr_t)g,
      (__attribute__((address_space(3))) unsigned int*)(unsigned)(uintptr_t)l,
      16, 0, 0);
}
// Issue one 32 KB tile (pre-swizzled LDS image) into a Bs buffer.
__device__ __forceinline__ void issue_tile(const unsigned short* tp, unsigned short* bs,
                                           int w, int lane) {
  for (int c = w; c < 32; c += 6)
    async_ld16(tp + c * 512 + lane * 8, bs + c * 512);
}

// ---------------------------------------------------------------------------
// Adjacency, built from pcm ROWS (coalesced). Self-edge first, then both
// Tanner directions via atomic append. Order is irrelevant: softmax and mod-2
// syndrome are permutation-invariant. exp(-1e9-max) underflows to 0 in fp32
// => sparse attention over this list == dense masked softmax.
// ---------------------------------------------------------------------------
__global__ void adj_init(int* __restrict__ adj, int* __restrict__ adjcnt) {
  int s = blockIdx.x * blockDim.x + threadIdx.x;
  if (s < S_) { adj[s * MAXDEG] = s; adjcnt[s] = 1; }
}
__global__ void adj_build(const int* __restrict__ pcm, int* __restrict__ adj,
                          int* __restrict__ adjcnt) {
  int c = blockIdx.x;      // check row 0..511
  int lane = threadIdx.x;  // 0..63
  const int* row = pcm + c * N_;
  for (int base = 0; base < N_; base += 64) {
    int k = base + lane;
    if (row[k] != 0) {
      int s1 = atomicAdd(&adjcnt[N_ + c], 1);
      if (s1 < MAXDEG) adj[(N_ + c) * MAXDEG + s1] = k;
      int s2 = atomicAdd(&adjcnt[k], 1);
      if (s2 < MAXDEG) adj[k * MAXDEG + s2] = N_ + c;
    }
  }
}

// ---------------------------------------------------------------------------
// x init; also zeroes the 8 per-batch barrier counters (ws poisoned 0xAA).
// ---------------------------------------------------------------------------
__global__ void xinit_kernel(const float* __restrict__ r_t, const int* __restrict__ adj,
                             const int* __restrict__ adjcnt, const float* __restrict__ se,
                             const int* __restrict__ tt, const float* __restrict__ table,
                             float* __restrict__ x, unsigned* __restrict__ barrier_cnt) {
  int bs = blockIdx.x;
  int b = bs / S_, s = bs % S_;
  int d = threadIdx.x;
  if (bs < 8 && d == 0)
    __hip_atomic_store(barrier_cnt + bs * 32, 0u, __ATOMIC_RELAXED, __HIP_MEMORY_SCOPE_AGENT);
  float node;
  if (s < N_) {
    node = fabsf(r_t[b * N_ + s]);
  } else {
    int cnt = adjcnt[s]; cnt = cnt < MAXDEG ? cnt : MAXDEG;
    float sum = 0.f;
    for (int j = 0; j < cnt; ++j) {
      int k = adj[s * MAXDEG + j];
      if (k < N_) {
        float r = r_t[b * N_ + k];
        sum += (r < 0.f) ? 1.f : (r > 0.f ? 0.f : 0.5f);
      }
    }
    node = fmodf(sum, 2.0f);
  }
  x[(size_t)bs * D_ + d] = table[tt[b] * D_ + d] * se[s * D_ + d] * node;
}

// ---------------------------------------------------------------------------
// Weight convert via LDS transpose staging: coalesced fp32 reads -> bf16 LDS
// tile (padded) -> coalesced pre-swizzled LDS-image writes. Stage order:
// [0]=Wk^T [1]=Wv^T [2]=Wq^T [3]=Wo^T [4+2c]=W1^T chunk c [5+2c]=W2^T chunk c.
// Image: tile[rr*128 + ((cc^(rr&15))<<3) + e] = W^T[rr][cc*8+e] = W[kd][rr].
// grid = L*12 blocks x 256 thr.
// ---------------------------------------------------------------------------
constexpr int WLAYER = NTILE * TILE;  // 196608 halfwords per layer

__global__ void wconv_kernel(const float* __restrict__ Wq, const float* __restrict__ Wk,
                             const float* __restrict__ Wv, const float* __restrict__ Wo,
                             const float* __restrict__ W1, const float* __restrict__ W2,
                             unsigned short* __restrict__ out) {
  __shared__ unsigned short tl[128 * 130];  // +2 pad breaks transpose conflicts
  int bid = blockIdx.x;
  int l = bid / NTILE, tile = bid % NTILE;
  const float* src;
  int rstride, coff = 0;
  if (tile == 0)      { src = Wk + (size_t)l * D_ * D_;  rstride = D_; }
  else if (tile == 1) { src = Wv + (size_t)l * D_ * D_;  rstride = D_; }
  else if (tile == 2) { src = Wq + (size_t)l * D_ * D_;  rstride = D_; }
  else if (tile == 3) { src = Wo + (size_t)l * D_ * D_;  rstride = D_; }
  else {
    int c = (tile - 4) >> 1;
    if (((tile - 4) & 1) == 0) { src = W1 + (size_t)l * D_ * DFF_; rstride = DFF_; coff = c * 128; }
    else                       { src = W2 + (size_t)l * DFF_ * D_ + (size_t)c * 128 * D_; rstride = D_; }
  }
  for (int i = threadIdx.x; i < 16384; i += 256) {  // coalesced row reads
    int kd = i >> 7, rr = i & 127;
    tl[kd * 130 + rr] = f2bf(src[(size_t)kd * rstride + coff + rr]);
  }
  __syncthreads();
  unsigned short* o = out + (size_t)bid * TILE;
  for (int i = threadIdx.x; i < 16384; i += 256) {  // coalesced image writes
    int rr = i >> 7;
    int sw = (i >> 3) & 15, e = i & 7;
    int kd = (sw ^ (rr & 15)) * 8 + e;
    o[i] = tl[kd * 130 + rr];
  }
}

// ---------------------------------------------------------------------------
// MFMA helper: wave tile = 16 rows x 64 cols (4 tiles of 16x16), K=128 in 4
// steps of 32. LDS: 16B chunks XOR-swizzled [row*128 + ((c^(row&15))<<3)].
// ---------------------------------------------------------------------------
__device__ __forceinline__ void mfma4(const unsigned short* As, const unsigned short* Bs,
                                      int rowbase, int colbase, int quad, int l16,
                                      f32x4 (&acc)[4]) {
#pragma unroll
  for (int kk = 0; kk < 4; ++kk) {
    int cb = kk * 4 + quad;
    int row = rowbase + l16;
    bf16x8 a = __builtin_bit_cast(bf16x8, *(const uint4*)&As[row * 128 + ((cb ^ (row & 15)) << 3)]);
    bf16x8 bb[4];
#pragma unroll
    for (int ct = 0; ct < 4; ++ct) {
      int n = colbase + ct * 16 + l16;
      bb[ct] = __builtin_bit_cast(bf16x8, *(const uint4*)&Bs[n * 128 + ((cb ^ (n & 15)) << 3)]);
    }
#pragma unroll
    for (int ct = 0; ct < 4; ++ct)
      acc[ct] = __builtin_amdgcn_mfma_f32_16x16x32_bf16(a, bb[ct], acc[ct], 0, 0, 0);
  }
}

// ---------------------------------------------------------------------------
// Fence-free per-batch barrier (R10-proven mechanism): kv is the only
// cross-block data and all kv traffic is agent-scope atomic (LLC-coherent).
// __syncthreads drains each wave's stores before the counter bump. Only the
// 32 same-batch blocks participate -> less skew, batches desynchronize.
// ---------------------------------------------------------------------------
__device__ __forceinline__ void grid_barrier(unsigned* cnt, unsigned target) {
  __syncthreads();
  if (threadIdx.x == 0) {
    __hip_atomic_fetch_add(cnt, 1u, __ATOMIC_RELAXED, __HIP_MEMORY_SCOPE_AGENT);
    while (__hip_atomic_load(cnt, __ATOMIC_RELAXED, __HIP_MEMORY_SCOPE_AGENT) < target)
      __builtin_amdgcn_s_sleep(4);
  }
  __syncthreads();
}

// ---------------------------------------------------------------------------
// Persistent mega-kernel: all 6 layers + fc head.
// grid = 256 blocks x 384 thr (6 waves); block owns 48 rows; 1 block/CU.
// Async double-buffered weight staging (global_load_lds); x in registers;
// Q block-local (Cs); K/V cross blocks via agent atomics (dbuffered kv);
// per-batch fence-free barrier. LDS ~122 KB.
// ---------------------------------------------------------------------------
__global__ void __launch_bounds__(384) mega_kernel(
    const float* __restrict__ x0, unsigned short* __restrict__ kv0,
    unsigned short* __restrict__ kv1, const unsigned short* __restrict__ wbf,
    const float* __restrict__ g1, const float* __restrict__ b1,
    const float* __restrict__ g2, const float* __restrict__ b2,
    const int* __restrict__ tt, const float* __restrict__ table,
    const int* __restrict__ adj, const int* __restrict__ adjc,
    const float* __restrict__ fcw, const float* __restrict__ fcb,
    float* __restrict__ out, unsigned* barrier_cnt) {
  __shared__ unsigned short As[RPB * 128];      // 12 KB
  __shared__ unsigned short Bs[2][TILE];        // 64 KB (double buffer)
  __shared__ unsigned short Cs[RPB * 128];      // 12 KB (Q, then FFN hf)
  __shared__ unsigned short KVs[RPB * 256];     // 24 KB (K|V repack)
  __shared__ float red1[2][RPB], red2[2][RPB];
  __shared__ int sKeys[RPB * LKEY];             // 6 KB
  __shared__ int sCnt[RPB];
  const int row0 = blockIdx.x * RPB;
  const int b = row0 / S_;
  const int bS = b * S_;
  const int t = threadIdx.x, w = t >> 6, lane = t & 63, quad = lane >> 4, l16 = lane & 15;
  const int wr = w >> 1, wc = w & 1;
  const int rowbase = wr * 16, colbase = wc * 64;
  const int tbase = tt[b] * D_;
  unsigned* bcnt = barrier_cnt + b * 32;  // per-batch counter, 128 B apart

  // prime the pipeline: layer-0 K tile -> Bs[0] (drained by LN1's barrier)
  issue_tile(wbf, Bs[0], w, lane);

  // persistent x in registers (MFMA C-layout)
  f32x4 xreg[4];
#pragma unroll
  for (int ct = 0; ct < 4; ++ct)
#pragma unroll
    for (int i = 0; i < 4; ++i) {
      int row = row0 + rowbase + quad * 4 + i;
      int col = colbase + ct * 16 + l16;
      xreg[ct][i] = x0[(size_t)row * D_ + col];
    }
  if (t < RPB) {
    int c = adjc[row0 + t - bS];
    sCnt[t] = c < MAXDEG ? c : MAXDEG;
  }
  for (int i = t; i < RPB * LKEY; i += 384) {
    int r = i / LKEY, j = i % LKEY;
    sKeys[i] = adj[(row0 + r - bS) * MAXDEG + j];  // tail values unused (clamped)
  }

  for (int l = 0; l < L_; ++l) {
    const unsigned short* wt = wbf + (size_t)l * WLAYER;  // stage s tile = wt + s*TILE
    const float* g1l = g1 + l * D_;
    const float* b1l = b1 + l * D_;
    const float* g2l = g2 + l * D_;
    const float* b2l = b2 + l * D_;
    unsigned short* kv = (l & 1) ? kv1 : kv0;

    // ---------------- LN1 on register x -> bf16 h in As --------------------
    float mu1[4], rs1[4];
#pragma unroll
    for (int i = 0; i < 4; ++i) {
      float s = xreg[0][i] + xreg[1][i] + xreg[2][i] + xreg[3][i];
      for (int off = 1; off < 16; off <<= 1) s += __shfl_xor(s, off);
      if (l16 == 0) red1[wc][rowbase + quad * 4 + i] = s;
    }
    __syncthreads();
#pragma unroll
    for (int i = 0; i < 4; ++i) {
      int r = rowbase + quad * 4 + i;
      mu1[i] = (red1[0][r] + red1[1][r]) * (1.f / 128.f);
      float sq = 0.f;
#pragma unroll
      for (int ct = 0; ct < 4; ++ct) { float d = xreg[ct][i] - mu1[i]; sq += d * d; }
      for (int off = 1; off < 16; off <<= 1) sq += __shfl_xor(sq, off);
      if (l16 == 0) red2[wc][r] = sq;
    }
    __syncthreads();
#pragma unroll
    for (int i = 0; i < 4; ++i) {
      int r = rowbase + quad * 4 + i;
      rs1[i] = rsqrtf((red2[0][r] + red2[1][r]) * (1.f / 128.f) + 1e-5f);
    }
#pragma unroll
    for (int ct = 0; ct < 4; ++ct)
#pragma unroll
      for (int i = 0; i < 4; ++i) {
        int rowL = rowbase + quad * 4 + i;
        int col = colbase + ct * 16 + l16;
        float h = (xreg[ct][i] - mu1[i]) * rs1[i] * g1l[col] + b1l[col];
        As[rowL * 128 + (((col >> 3) ^ (rowL & 15)) << 3) + (col & 7)] = f2bf(h);
      }
    __syncthreads();  // As(h) ready; K tile (issued last stage) drained

    // ---------------- stage 0: K -> KVs[:,0:128) ---------------------------
    issue_tile(wt + 1 * TILE, Bs[1], w, lane);   // V
    {
      f32x4 acc[4];
#pragma unroll
      for (int j = 0; j < 4; ++j) acc[j] = f32x4{0.f, 0.f, 0.f, 0.f};
      mfma4(As, Bs[0], rowbase, colbase, quad, l16, acc);
#pragma unroll
      for (int ct = 0; ct < 4; ++ct)
#pragma unroll
        for (int i = 0; i < 4; ++i) {
          int rowL = rowbase + quad * 4 + i;
          KVs[rowL * 256 + colbase + ct * 16 + l16] = f2bf(acc[ct][i]);
        }
    }
    __syncthreads();
    // ---------------- stage 1: V -> KVs[:,128:256) -------------------------
    issue_tile(wt + 2 * TILE, Bs[0], w, lane);   // Q
    {
      f32x4 acc[4];
#pragma unroll
      for (int j = 0; j < 4; ++j) acc[j] = f32x4{0.f, 0.f, 0.f, 0.f};
      mfma4(As, Bs[1], rowbase, colbase, quad, l16, acc);
#pragma unroll
      for (int ct = 0; ct < 4; ++ct)
#pragma unroll
        for (int i = 0; i < 4; ++i) {
          int rowL = rowbase + quad * 4 + i;
          KVs[rowL * 256 + 128 + colbase + ct * 16 + l16] = f2bf(acc[ct][i]);
        }
    }
    __syncthreads();
    // ---------------- stage 2: Q -> Cs; kv <- KVs (agent atomics) ----------
    issue_tile(wt + 3 * TILE, Bs[1], w, lane);   // Wo
    {
      f32x4 acc[4];
#pragma unroll
      for (int j = 0; j < 4; ++j) acc[j] = f32x4{0.f, 0.f, 0.f, 0.f};
      mfma4(As, Bs[0], rowbase, colbase, quad, l16, acc);
#pragma unroll
      for (int ct = 0; ct < 4; ++ct)
#pragma unroll
        for (int i = 0; i < 4; ++i) {
          int rowL = rowbase + quad * 4 + i;
          int col = colbase + ct * 16 + l16;
          Cs[rowL * 128 + (((col >> 3) ^ (rowL & 15)) << 3) + (col & 7)] = f2bf(acc[ct][i]);
        }
    }
    for (int i = t; i < RPB * 128; i += 384) {  // 128 dwords/row: K|V
      int rL = i >> 7, cw = i & 127;
      unsigned u = *(const unsigned*)&KVs[rL * 256 + cw * 2];
      __hip_atomic_store((unsigned*)&kv[(size_t)(row0 + rL) * 256 + cw * 2],
                         u, __ATOMIC_RELAXED, __HIP_MEMORY_SCOPE_AGENT);
    }

    // -------- per-batch fence-free barrier: batch kv visible ---------------
    grid_barrier(bcnt, (unsigned)(BPB * (l + 1)));

    // W1c0 loads fly under the whole attention gather
    issue_tile(wt + 4 * TILE, Bs[0], w, lane);

    // ---------------- attention (48 rows x 8 heads, one per thread) --------
    {
      const int rL = t >> 3, h = t & 7;
      const int s = row0 + rL - bS;
      const int cnt = sCnt[rL];
      float q[16];
      {
        u16x8 qa = *(const u16x8*)&Cs[rL * 128 + (((2 * h) ^ (rL & 15)) << 3)];
        u16x8 qb = *(const u16x8*)&Cs[rL * 128 + (((2 * h + 1) ^ (rL & 15)) << 3)];
#pragma unroll
        for (int j = 0; j < 8; ++j) { q[j] = bf2f(qa[j]); q[8 + j] = bf2f(qb[j]); }
      }
      float m = -1e30f, lsum = 0.f;
      float o16[16];
#pragma unroll
      for (int j = 0; j < 16; ++j) o16[j] = 0.f;
      for (int jb = 0; jb < cnt; jb += 4) {  // 4 neighbors in flight
        unsigned long long K[4][4], V[4][4];
#pragma unroll
        for (int u = 0; u < 4; ++u) {
          int j = jb + u;
          int key = 0;
          if (j < cnt) key = (j < LKEY) ? sKeys[rL * LKEY + j] : adj[s * MAXDEG + j];
          const unsigned long long* kp =
              (const unsigned long long*)(kv + (size_t)(bS + key) * 256 + h * 16);
#pragma unroll
          for (int c = 0; c < 4; ++c) {
            K[u][c] = __hip_atomic_load(kp + c, __ATOMIC_RELAXED, __HIP_MEMORY_SCOPE_AGENT);
            V[u][c] = __hip_atomic_load(kp + 32 + c, __ATOMIC_RELAXED, __HIP_MEMORY_SCOPE_AGENT);
          }
        }
#pragma unroll
        for (int u = 0; u < 4; ++u) {
          float kf[16], vf[16];
#pragma unroll
          for (int c = 0; c < 4; ++c) { ull2f4(K[u][c], kf + 4 * c); ull2f4(V[u][c], vf + 4 * c); }
          float dot = 0.f;
#pragma unroll
          for (int j = 0; j < 16; ++j) dot = fmaf(q[j], kf[j], dot);
          dot *= 0.25f;  // 1/sqrt(HD)
          if (jb + u >= cnt) dot = -1e30f;
          const float mn = fmaxf(m, dot);
          const float rescale = __expf(m - mn);
          const float e = __expf(dot - mn);
          lsum = lsum * rescale + e;
#pragma unroll
          for (int j = 0; j < 16; ++j) o16[j] = o16[j] * rescale + e * vf[j];
          m = mn;
        }
      }
      const float inv = 1.f / lsum;
      u16x8 pk0, pk1;
#pragma unroll
      for (int j = 0; j < 8; ++j) {
        pk0[j] = f2bf(o16[j] * inv);
        pk1[j] = f2bf(o16[8 + j] * inv);
      }
      *(u16x8*)&As[rL * 128 + (((2 * h) ^ (rL & 15)) << 3)] = pk0;
      *(u16x8*)&As[rL * 128 + (((2 * h + 1) ^ (rL & 15)) << 3)] = pk1;
    }
    __syncthreads();  // As(o) ready; Wo + W1c0 loads drained

    // ---------------- stage 3: Wo; x'; LN2*te -> As ------------------------
    f32x4 acc1[4];
#pragma unroll
    for (int j = 0; j < 4; ++j) acc1[j] = f32x4{0.f, 0.f, 0.f, 0.f};
    mfma4(As, Bs[1], rowbase, colbase, quad, l16, acc1);
    f32x4 xp[4];
#pragma unroll
    for (int ct = 0; ct < 4; ++ct)
#pragma unroll
      for (int i = 0; i < 4; ++i) xp[ct][i] = xreg[ct][i] + acc1[ct][i];
#pragma unroll
    for (int i = 0; i < 4; ++i) {
      float s = xp[0][i] + xp[1][i] + xp[2][i] + xp[3][i];
      for (int off = 1; off < 16; off <<= 1) s += __shfl_xor(s, off);
      if (l16 == 0) red1[wc][rowbase + quad * 4 + i] = s;
    }
    __syncthreads();  // also: all As(o) reads complete -> safe to rewrite As
    float mu_[4], rs_[4];
#pragma unroll
    for (int i = 0; i < 4; ++i) {
      int r = rowbase + quad * 4 + i;
      mu_[i] = (red1[0][r] + red1[1][r]) * (1.f / 128.f);
      float sq = 0.f;
#pragma unroll
      for (int ct = 0; ct < 4; ++ct) { float d = xp[ct][i] - mu_[i]; sq += d * d; }
      for (int off = 1; off < 16; off <<= 1) sq += __shfl_xor(sq, off);
      if (l16 == 0) red2[wc][r] = sq;
    }
    __syncthreads();
#pragma unroll
    for (int i = 0; i < 4; ++i) {
      int r = rowbase + quad * 4 + i;
      rs_[i] = rsqrtf((red2[0][r] + red2[1][r]) * (1.f / 128.f) + 1e-5f);
    }
#pragma unroll
    for (int ct = 0; ct < 4; ++ct)
#pragma unroll
      for (int i = 0; i < 4; ++i) {
        int rowL = rowbase + quad * 4 + i;
        int col = colbase + ct * 16 + l16;
        float h2 = (xp[ct][i] - mu_[i]) * rs_[i] * g2l[col] + b2l[col];
        h2 *= table[tbase + col];
        As[rowL * 128 + (((col >> 3) ^ (rowL & 15)) << 3) + (col & 7)] = f2bf(h2);
      }
    __syncthreads();  // h2 visible; stage-3 Bs[1] reads done

    // ---------------- FFN: stages 4..11, pipelined -------------------------
    f32x4 acc2[4];
#pragma unroll
    for (int j = 0; j < 4; ++j) acc2[j] = f32x4{0.f, 0.f, 0.f, 0.f};
    for (int c = 0; c < 4; ++c) {
      issue_tile(wt + (5 + 2 * c) * TILE, Bs[1], w, lane);  // W2 chunk c
      f32x4 accF[4];
#pragma unroll
      for (int j = 0; j < 4; ++j) accF[j] = f32x4{0.f, 0.f, 0.f, 0.f};
      mfma4(As, Bs[0], rowbase, colbase, quad, l16, accF);
#pragma unroll
      for (int ct = 0; ct < 4; ++ct)
#pragma unroll
        for (int i = 0; i < 4; ++i) {
          int rowL = rowbase + quad * 4 + i;
          int col = colbase + ct * 16 + l16;
          Cs[rowL * 128 + (((col >> 3) ^ (rowL & 15)) << 3) + (col & 7)] =
              f2bf(fmaxf(accF[ct][i], 0.f));
        }
      __syncthreads();  // hf visible; W2c loads drained; Bs[0] reads done
      if (c < 3) issue_tile(wt + (6 + 2 * c) * TILE, Bs[0], w, lane);   // W1 c+1
      else if (l < L_ - 1) issue_tile(wt + WLAYER, Bs[0], w, lane);     // next K
      mfma4(Cs, Bs[1], rowbase, colbase, quad, l16, acc2);
      __syncthreads();  // Bs[1] free for next c
    }
    // epilogue: x'' = x' + ffn (registers only)
    if (l < L_ - 1) {
#pragma unroll
      for (int ct = 0; ct < 4; ++ct)
#pragma unroll
        for (int i = 0; i < 4; ++i) xreg[ct][i] = xp[ct][i] + acc2[ct][i];
    } else {
      float pr[4] = {0.f, 0.f, 0.f, 0.f};
#pragma unroll
      for (int ct = 0; ct < 4; ++ct)
#pragma unroll
        for (int i = 0; i < 4; ++i)
          pr[i] += (xp[ct][i] + acc2[ct][i]) * fcw[colbase + ct * 16 + l16];
#pragma unroll
      for (int i = 0; i < 4; ++i) {
        float s = pr[i];
        for (int off = 1; off < 16; off <<= 1) s += __shfl_xor(s, off);
        if (l16 == 0) red1[wc][rowbase + quad * 4 + i] = s;
      }
      __syncthreads();
      if (wc == 0 && l16 == 0)
#pragma unroll
        for (int i = 0; i < 4; ++i) {
          int r = rowbase + quad * 4 + i;
          out[row0 + r] = red1[0][r] + red1[1][r] + fcb[0];
        }
    }
  }
}

// ---------------------------------------------------------------------------
extern "C" void kernel_launch(void* const* d_in, const int* in_sizes, int n_in,
                              void* d_out, int out_size, void* d_ws, size_t ws_size,
                              hipStream_t stream) {
  const float* r_t       = (const float*)d_in[0];
  const int*   t         = (const int*)d_in[1];
  const int*   pcm       = (const int*)d_in[2];
  const float* src_embed = (const float*)d_in[4];
  const float* time_tab  = (const float*)d_in[5];
  const float* Wq = (const float*)d_in[6];
  const float* Wk = (const float*)d_in[7];
  const float* Wv = (const float*)d_in[8];
  const float* Wo = (const float*)d_in[9];
  const float* W1 = (const float*)d_in[10];
  const float* W2 = (const float*)d_in[11];
  const float* g1 = (const float*)d_in[12];
  const float* b1 = (const float*)d_in[13];
  const float* g2 = (const float*)d_in[14];
  const float* b2 = (const float*)d_in[15];
  const float* fc_w = (const float*)d_in[16];
  const float* fc_b = (const float*)d_in[17];
  float* out = (float*)d_out;

  char* ws = (char*)d_ws;
  size_t off = 0;
  auto alloc = [&](size_t bytes) -> void* {
    void* p = ws + off;
    off = (off + bytes + 255) & ~(size_t)255;
    return p;
  };
  float*          x    = (float*)alloc((size_t)ROWS * D_ * 4);
  unsigned short* kv0  = (unsigned short*)alloc((size_t)ROWS * 256 * 2);
  unsigned short* kv1  = (unsigned short*)alloc((size_t)ROWS * 256 * 2);
  int*            adj  = (int*)alloc((size_t)S_ * MAXDEG * 4);
  int*            adjc = (int*)alloc((size_t)S_ * 4);
  unsigned short* wbf  = (unsigned short*)alloc((size_t)L_ * WLAYER * 2);
  unsigned*       bcnt = (unsigned*)alloc(8 * 32 * 4);

  adj_init<<<(S_ + 255) / 256, 256, 0, stream>>>(adj, adjc);
  adj_build<<<M_, 64, 0, stream>>>(pcm, adj, adjc);
  wconv_kernel<<<L_ * NTILE, 256, 0, stream>>>(Wq, Wk, Wv, Wo, W1, W2, wbf);
  xinit_kernel<<<ROWS, 128, 0, stream>>>(r_t, adj, adjc, src_embed, t, time_tab, x, bcnt);

  mega_kernel<<<NBLK, 384, 0, stream>>>(x, kv0, kv1, wbf, g1, b1, g2, b2,
                                        t, time_tab, adj, adjc, fc_w, fc_b, out, bcnt);
}

// Round 15
// 286.551 us; speedup vs baseline: 2.1487x; 1.0132x over previous
//
#include <hip/hip_runtime.h>
#include <cmath>
#include <cstdint>

// Problem constants (from reference)
constexpr int B_ = 8, N_ = 1024, M_ = 512, D_ = 128, S_ = 1536, L_ = 6, DFF_ = 512;
constexpr int ROWS = B_ * S_;    // 12288
constexpr int MAXDEG = 64;       // max attention row degree (actual ~4-25)
constexpr int LKEY = 32;         // LDS-cached keys per row
constexpr int RPB  = 48;         // rows per block
constexpr int NBLK = ROWS / RPB; // 256 persistent blocks (1/CU, all resident)
constexpr int BPB  = S_ / RPB;   // 32 blocks per batch (barrier group)
constexpr int NTILE = 12;        // weight tiles per layer, in stage order
constexpr int TILE  = 128 * 128; // halfwords per tile (LDS image, 32 KB)

typedef __bf16 bf16x8 __attribute__((ext_vector_type(8)));
typedef float  f32x4  __attribute__((ext_vector_type(4)));
typedef unsigned short u16x8 __attribute__((ext_vector_type(8)));

__device__ inline unsigned short f2bf(float f) {  // RNE fp32 -> bf16
  unsigned u = __float_as_uint(f);
  u += 0x7fffu + ((u >> 16) & 1u);
  return (unsigned short)(u >> 16);
}
__device__ inline float bf2f(unsigned short u) {
  return __uint_as_float(((unsigned)u) << 16);
}
__device__ inline void ull2f4(unsigned long long u, float* f) {  // 4 bf16 -> fp32
  f[0] = bf2f((unsigned short)(u));
  f[1] = bf2f((unsigned short)(u >> 16));
  f[2] = bf2f((unsigned short)(u >> 32));
  f[3] = bf2f((unsigned short)(u >> 48));
}

// Direct global->LDS async copy, 16 B/lane (m97's lever).
__device__ __forceinline__ void async_ld16(const unsigned short* g, unsigned short* l) {
  __builtin_amdgcn_global_load_lds(
      (const __attribute__((address_space(1))) unsigned int*)(uintptr_t)g,
      (__attribute__((address_space(3))) unsigned int*)(unsigned)(uintptr_t)l,
      16, 0, 0);
}
// Issue one 32 KB tile (pre-swizzled LDS image) into a Bs buffer.
__device__ __forceinline__ void issue_tile(const unsigned short* tp, unsigned short* bs,
                                           int w, int lane) {
  for (int c = w; c < 32; c += 6)
    async_ld16(tp + c * 512 + lane * 8, bs + c * 512);
}

// ---------------------------------------------------------------------------
// Adjacency, built from pcm ROWS (coalesced). Self-edge first, then both
// Tanner directions via atomic append. Order is irrelevant: softmax and mod-2
// syndrome are permutation-invariant. exp(-1e9-max) underflows to 0 in fp32
// => sparse attention over this list == dense masked softmax.
// ---------------------------------------------------------------------------
__global__ void adj_init(int* __restrict__ adj, int* __restrict__ adjcnt) {
  int s = blockIdx.x * blockDim.x + threadIdx.x;
  if (s < S_) { adj[s * MAXDEG] = s; adjcnt[s] = 1; }
}
__global__ void adj_build(const int* __restrict__ pcm, int* __restrict__ adj,
                          int* __restrict__ adjcnt) {
  int c = blockIdx.x;      // check row 0..511
  int lane = threadIdx.x;  // 0..63
  const int* row = pcm + c * N_;
  for (int base = 0; base < N_; base += 64) {
    int k = base + lane;
    if (row[k] != 0) {
      int s1 = atomicAdd(&adjcnt[N_ + c], 1);
      if (s1 < MAXDEG) adj[(N_ + c) * MAXDEG + s1] = k;
      int s2 = atomicAdd(&adjcnt[k], 1);
      if (s2 < MAXDEG) adj[k * MAXDEG + s2] = N_ + c;
    }
  }
}

// ---------------------------------------------------------------------------
// x init; also zeroes the 8 per-batch barrier counters (ws poisoned 0xAA).
// ---------------------------------------------------------------------------
__global__ void xinit_kernel(const float* __restrict__ r_t, const int* __restrict__ adj,
                             const int* __restrict__ adjcnt, const float* __restrict__ se,
                             const int* __restrict__ tt, const float* __restrict__ table,
                             float* __restrict__ x, unsigned* __restrict__ barrier_cnt) {
  int bs = blockIdx.x;
  int b = bs / S_, s = bs % S_;
  int d = threadIdx.x;
  if (bs < 8 && d == 0)
    __hip_atomic_store(barrier_cnt + bs * 32, 0u, __ATOMIC_RELAXED, __HIP_MEMORY_SCOPE_AGENT);
  float node;
  if (s < N_) {
    node = fabsf(r_t[b * N_ + s]);
  } else {
    int cnt = adjcnt[s]; cnt = cnt < MAXDEG ? cnt : MAXDEG;
    float sum = 0.f;
    for (int j = 0; j < cnt; ++j) {
      int k = adj[s * MAXDEG + j];
      if (k < N_) {
        float r = r_t[b * N_ + k];
        sum += (r < 0.f) ? 1.f : (r > 0.f ? 0.f : 0.5f);
      }
    }
    node = fmodf(sum, 2.0f);
  }
  x[(size_t)bs * D_ + d] = table[tt[b] * D_ + d] * se[s * D_ + d] * node;
}

// ---------------------------------------------------------------------------
// Weight convert via LDS transpose staging: coalesced fp32 reads -> bf16 LDS
// tile (padded) -> coalesced pre-swizzled LDS-image writes. Stage order:
// [0]=Wk^T [1]=Wv^T [2]=Wq^T [3]=Wo^T [4+2c]=W1^T chunk c [5+2c]=W2^T chunk c.
// Image: tile[rr*128 + ((cc^(rr&15))<<3) + e] = W^T[rr][cc*8+e] = W[kd][rr].
// ---------------------------------------------------------------------------
constexpr int WLAYER = NTILE * TILE;  // 196608 halfwords per layer

__global__ void wconv_kernel(const float* __restrict__ Wq, const float* __restrict__ Wk,
                             const float* __restrict__ Wv, const float* __restrict__ Wo,
                             const float* __restrict__ W1, const float* __restrict__ W2,
                             unsigned short* __restrict__ out) {
  __shared__ unsigned short tl[128 * 130];  // +2 pad breaks transpose conflicts
  int bid = blockIdx.x;
  int l = bid / NTILE, tile = bid % NTILE;
  const float* src;
  int rstride, coff = 0;
  if (tile == 0)      { src = Wk + (size_t)l * D_ * D_;  rstride = D_; }
  else if (tile == 1) { src = Wv + (size_t)l * D_ * D_;  rstride = D_; }
  else if (tile == 2) { src = Wq + (size_t)l * D_ * D_;  rstride = D_; }
  else if (tile == 3) { src = Wo + (size_t)l * D_ * D_;  rstride = D_; }
  else {
    int c = (tile - 4) >> 1;
    if (((tile - 4) & 1) == 0) { src = W1 + (size_t)l * D_ * DFF_; rstride = DFF_; coff = c * 128; }
    else                       { src = W2 + (size_t)l * DFF_ * D_ + (size_t)c * 128 * D_; rstride = D_; }
  }
  for (int i = threadIdx.x; i < 16384; i += 256) {  // coalesced row reads
    int kd = i >> 7, rr = i & 127;
    tl[kd * 130 + rr] = f2bf(src[(size_t)kd * rstride + coff + rr]);
  }
  __syncthreads();
  unsigned short* o = out + (size_t)bid * TILE;
  for (int i = threadIdx.x; i < 16384; i += 256) {  // coalesced image writes
    int rr = i >> 7;
    int sw = (i >> 3) & 15, e = i & 7;
    int kd = (sw ^ (rr & 15)) * 8 + e;
    o[i] = tl[kd * 130 + rr];
  }
}

// ---------------------------------------------------------------------------
// MFMA helper: wave tile = 16 rows x 64 cols (4 tiles of 16x16), K=128 in 4
// steps of 32. LDS: 16B chunks XOR-swizzled [row*128 + ((c^(row&15))<<3)].
// ---------------------------------------------------------------------------
__device__ __forceinline__ void mfma4(const unsigned short* As, const unsigned short* Bs,
                                      int rowbase, int colbase, int quad, int l16,
                                      f32x4 (&acc)[4]) {
#pragma unroll
  for (int kk = 0; kk < 4; ++kk) {
    int cb = kk * 4 + quad;
    int row = rowbase + l16;
    bf16x8 a = __builtin_bit_cast(bf16x8, *(const uint4*)&As[row * 128 + ((cb ^ (row & 15)) << 3)]);
    bf16x8 bb[4];
#pragma unroll
    for (int ct = 0; ct < 4; ++ct) {
      int n = colbase + ct * 16 + l16;
      bb[ct] = __builtin_bit_cast(bf16x8, *(const uint4*)&Bs[n * 128 + ((cb ^ (n & 15)) << 3)]);
    }
#pragma unroll
    for (int ct = 0; ct < 4; ++ct)
      acc[ct] = __builtin_amdgcn_mfma_f32_16x16x32_bf16(a, bb[ct], acc[ct], 0, 0, 0);
  }
}

// ---------------------------------------------------------------------------
// Fence-free per-batch barrier (R10-proven): kv is the only cross-block data
// and all kv traffic is agent-scope atomic (LLC-coherent). __syncthreads
// drains each wave's stores before the counter bump. 32 blocks per group.
// ---------------------------------------------------------------------------
__device__ __forceinline__ void grid_barrier(unsigned* cnt, unsigned target) {
  __syncthreads();
  if (threadIdx.x == 0) {
    __hip_atomic_fetch_add(cnt, 1u, __ATOMIC_RELAXED, __HIP_MEMORY_SCOPE_AGENT);
    while (__hip_atomic_load(cnt, __ATOMIC_RELAXED, __HIP_MEMORY_SCOPE_AGENT) < target)
      __builtin_amdgcn_s_sleep(4);
  }
  __syncthreads();
}

// ---------------------------------------------------------------------------
// Persistent mega-kernel: all 6 layers + fc head.
// grid = 256 blocks x 384 thr (6 waves); block owns 48 rows; 1 block/CU.
// Bs = 3-buffer ring (96 KB): K,V,Q co-resident at layer start (zero
// barriers between the 3 QKV MFMA stages — wave-private outputs); Wo+W1c0+
// W2c0 all land under the attention phase; FFN ring keeps 1-stage cover.
// One-pass LN (var = E[x^2]-mu^2). x in registers; Q block-local (Cs);
// K/V cross blocks via agent atomics (dbuffered kv); per-batch barrier.
// LDS: As 12K + Bs 96K + Cs 12K + KVs 24K + sKeys 6K + red 0.8K ~= 151 KB.
// ---------------------------------------------------------------------------
__global__ void __launch_bounds__(384) mega_kernel(
    const float* __restrict__ x0, unsigned short* __restrict__ kv0,
    unsigned short* __restrict__ kv1, const unsigned short* __restrict__ wbf,
    const float* __restrict__ g1, const float* __restrict__ b1,
    const float* __restrict__ g2, const float* __restrict__ b2,
    const int* __restrict__ tt, const float* __restrict__ table,
    const int* __restrict__ adj, const int* __restrict__ adjc,
    const float* __restrict__ fcw, const float* __restrict__ fcb,
    float* __restrict__ out, unsigned* barrier_cnt) {
  __shared__ unsigned short As[RPB * 128];      // 12 KB
  __shared__ unsigned short Bs[3][TILE];        // 96 KB (ring)
  __shared__ unsigned short Cs[RPB * 128];      // 12 KB (Q, then FFN hf)
  __shared__ unsigned short KVs[RPB * 256];     // 24 KB (K|V repack)
  __shared__ float red1[2][RPB], red2[2][RPB];
  __shared__ int sKeys[RPB * LKEY];             // 6 KB
  __shared__ int sCnt[RPB];
  const int row0 = blockIdx.x * RPB;
  const int b = row0 / S_;
  const int bS = b * S_;
  const int t = threadIdx.x, w = t >> 6, lane = t & 63, quad = lane >> 4, l16 = lane & 15;
  const int wr = w >> 1, wc = w & 1;
  const int rowbase = wr * 16, colbase = wc * 64;
  const int tbase = tt[b] * D_;
  unsigned* bcnt = barrier_cnt + b * 32;  // per-batch counter, 128 B apart

  // prime the pipeline: layer-0 K,V,Q tiles -> Bs[0..2]
  issue_tile(wbf + 0 * TILE, Bs[0], w, lane);
  issue_tile(wbf + 1 * TILE, Bs[1], w, lane);
  issue_tile(wbf + 2 * TILE, Bs[2], w, lane);

  // persistent x in registers (MFMA C-layout)
  f32x4 xreg[4];
#pragma unroll
  for (int ct = 0; ct < 4; ++ct)
#pragma unroll
    for (int i = 0; i < 4; ++i) {
      int row = row0 + rowbase + quad * 4 + i;
      int col = colbase + ct * 16 + l16;
      xreg[ct][i] = x0[(size_t)row * D_ + col];
    }
  if (t < RPB) {
    int c = adjc[row0 + t - bS];
    sCnt[t] = c < MAXDEG ? c : MAXDEG;
  }
  for (int i = t; i < RPB * LKEY; i += 384) {
    int r = i / LKEY, j = i % LKEY;
    sKeys[i] = adj[(row0 + r - bS) * MAXDEG + j];  // tail values unused (clamped)
  }

  for (int l = 0; l < L_; ++l) {
    const unsigned short* wt = wbf + (size_t)l * WLAYER;
    const float* g1l = g1 + l * D_;
    const float* b1l = b1 + l * D_;
    const float* g2l = g2 + l * D_;
    const float* b2l = b2 + l * D_;
    unsigned short* kv = (l & 1) ? kv1 : kv0;

    // ------------- LN1 (one-pass var) on register x -> bf16 h in As --------
    float mu1[4], rs1[4];
#pragma unroll
    for (int i = 0; i < 4; ++i) {
      float s = 0.f, sq = 0.f;
#pragma unroll
      for (int ct = 0; ct < 4; ++ct) { s += xreg[ct][i]; sq += xreg[ct][i] * xreg[ct][i]; }
      for (int off = 1; off < 16; off <<= 1) { s += __shfl_xor(s, off); sq += __shfl_xor(sq, off); }
      if (l16 == 0) { red1[wc][rowbase + quad * 4 + i] = s; red2[wc][rowbase + quad * 4 + i] = sq; }
    }
    __syncthreads();
#pragma unroll
    for (int i = 0; i < 4; ++i) {
      int r = rowbase + quad * 4 + i;
      float mu = (red1[0][r] + red1[1][r]) * (1.f / 128.f);
      float var = (red2[0][r] + red2[1][r]) * (1.f / 128.f) - mu * mu;
      mu1[i] = mu;
      rs1[i] = rsqrtf(var + 1e-5f);
    }
#pragma unroll
    for (int ct = 0; ct < 4; ++ct)
#pragma unroll
      for (int i = 0; i < 4; ++i) {
        int rowL = rowbase + quad * 4 + i;
        int col = colbase + ct * 16 + l16;
        float h = (xreg[ct][i] - mu1[i]) * rs1[i] * g1l[col] + b1l[col];
        As[rowL * 128 + (((col >> 3) ^ (rowL & 15)) << 3) + (col & 7)] = f2bf(h);
      }
    __syncthreads();  // As(h) visible; K,V,Q tiles drained

    // ------------- QKV: three barrier-free MFMA stages ---------------------
    {  // K -> KVs[:,0:128)  (wave-private region)
      f32x4 acc[4];
#pragma unroll
      for (int j = 0; j < 4; ++j) acc[j] = f32x4{0.f, 0.f, 0.f, 0.f};
      mfma4(As, Bs[0], rowbase, colbase, quad, l16, acc);
#pragma unroll
      for (int ct = 0; ct < 4; ++ct)
#pragma unroll
        for (int i = 0; i < 4; ++i) {
          int rowL = rowbase + quad * 4 + i;
          KVs[rowL * 256 + colbase + ct * 16 + l16] = f2bf(acc[ct][i]);
        }
    }
    {  // V -> KVs[:,128:256)
      f32x4 acc[4];
#pragma unroll
      for (int j = 0; j < 4; ++j) acc[j] = f32x4{0.f, 0.f, 0.f, 0.f};
      mfma4(As, Bs[1], rowbase, colbase, quad, l16, acc);
#pragma unroll
      for (int ct = 0; ct < 4; ++ct)
#pragma unroll
        for (int i = 0; i < 4; ++i) {
          int rowL = rowbase + quad * 4 + i;
          KVs[rowL * 256 + 128 + colbase + ct * 16 + l16] = f2bf(acc[ct][i]);
        }
    }
    {  // Q -> Cs (swizzled A-layout, kept for attention)
      f32x4 acc[4];
#pragma unroll
      for (int j = 0; j < 4; ++j) acc[j] = f32x4{0.f, 0.f, 0.f, 0.f};
      mfma4(As, Bs[2], rowbase, colbase, quad, l16, acc);
#pragma unroll
      for (int ct = 0; ct < 4; ++ct)
#pragma unroll
        for (int i = 0; i < 4; ++i) {
          int rowL = rowbase + quad * 4 + i;
          int col = colbase + ct * 16 + l16;
          Cs[rowL * 128 + (((col >> 3) ^ (rowL & 15)) << 3) + (col & 7)] = f2bf(acc[ct][i]);
        }
    }
    __syncthreads();  // KVs complete block-wide
    for (int i = t; i < RPB * 128; i += 384) {  // 128 dwords/row: K|V
      int rL = i >> 7, cw = i & 127;
      unsigned u = *(const unsigned*)&KVs[rL * 256 + cw * 2];
      __hip_atomic_store((unsigned*)&kv[(size_t)(row0 + rL) * 256 + cw * 2],
                         u, __ATOMIC_RELAXED, __HIP_MEMORY_SCOPE_AGENT);
    }

    // -------- per-batch fence-free barrier: batch kv visible ---------------
    grid_barrier(bcnt, (unsigned)(BPB * (l + 1)));

    // Wo + W1c0 + W2c0 (96 KB) all land under the attention gather
    issue_tile(wt + 3 * TILE, Bs[0], w, lane);
    issue_tile(wt + 4 * TILE, Bs[1], w, lane);
    issue_tile(wt + 5 * TILE, Bs[2], w, lane);

    // ---------------- attention (48 rows x 8 heads, one per thread) --------
    {
      const int rL = t >> 3, h = t & 7;
      const int s = row0 + rL - bS;
      const int cnt = sCnt[rL];
      float q[16];
      {
        u16x8 qa = *(const u16x8*)&Cs[rL * 128 + (((2 * h) ^ (rL & 15)) << 3)];
        u16x8 qb = *(const u16x8*)&Cs[rL * 128 + (((2 * h + 1) ^ (rL & 15)) << 3)];
#pragma unroll
        for (int j = 0; j < 8; ++j) { q[j] = bf2f(qa[j]); q[8 + j] = bf2f(qb[j]); }
      }
      float m = -1e30f, lsum = 0.f;
      float o16[16];
#pragma unroll
      for (int j = 0; j < 16; ++j) o16[j] = 0.f;
      for (int jb = 0; jb < cnt; jb += 4) {  // 4 neighbors in flight
        unsigned long long K[4][4], V[4][4];
#pragma unroll
        for (int u = 0; u < 4; ++u) {
          int j = jb + u;
          int key = 0;
          if (j < cnt) key = (j < LKEY) ? sKeys[rL * LKEY + j] : adj[s * MAXDEG + j];
          const unsigned long long* kp =
              (const unsigned long long*)(kv + (size_t)(bS + key) * 256 + h * 16);
#pragma unroll
          for (int c = 0; c < 4; ++c) {
            K[u][c] = __hip_atomic_load(kp + c, __ATOMIC_RELAXED, __HIP_MEMORY_SCOPE_AGENT);
            V[u][c] = __hip_atomic_load(kp + 32 + c, __ATOMIC_RELAXED, __HIP_MEMORY_SCOPE_AGENT);
          }
        }
#pragma unroll
        for (int u = 0; u < 4; ++u) {
          float kf[16], vf[16];
#pragma unroll
          for (int c = 0; c < 4; ++c) { ull2f4(K[u][c], kf + 4 * c); ull2f4(V[u][c], vf + 4 * c); }
          float dot = 0.f;
#pragma unroll
          for (int j = 0; j < 16; ++j) dot = fmaf(q[j], kf[j], dot);
          dot *= 0.25f;  // 1/sqrt(HD)
          if (jb + u >= cnt) dot = -1e30f;
          const float mn = fmaxf(m, dot);
          const float rescale = __expf(m - mn);
          const float e = __expf(dot - mn);
          lsum = lsum * rescale + e;
#pragma unroll
          for (int j = 0; j < 16; ++j) o16[j] = o16[j] * rescale + e * vf[j];
          m = mn;
        }
      }
      const float inv = 1.f / lsum;
      u16x8 pk0, pk1;
#pragma unroll
      for (int j = 0; j < 8; ++j) {
        pk0[j] = f2bf(o16[j] * inv);
        pk1[j] = f2bf(o16[8 + j] * inv);
      }
      *(u16x8*)&As[rL * 128 + (((2 * h) ^ (rL & 15)) << 3)] = pk0;
      *(u16x8*)&As[rL * 128 + (((2 * h + 1) ^ (rL & 15)) << 3)] = pk1;
    }
    __syncthreads();  // As(o) visible; Wo/W1c0/W2c0 drained

    // ---------------- Wo; x'; LN2*te -> As ---------------------------------
    f32x4 acc1[4];
#pragma unroll
    for (int j = 0; j < 4; ++j) acc1[j] = f32x4{0.f, 0.f, 0.f, 0.f};
    mfma4(As, Bs[0], rowbase, colbase, quad, l16, acc1);
    f32x4 xp[4];
#pragma unroll
    for (int ct = 0; ct < 4; ++ct)
#pragma unroll
      for (int i = 0; i < 4; ++i) xp[ct][i] = xreg[ct][i] + acc1[ct][i];
    float mu_[4], rs_[4];
#pragma unroll
    for (int i = 0; i < 4; ++i) {
      float s = 0.f, sq = 0.f;
#pragma unroll
      for (int ct = 0; ct < 4; ++ct) { s += xp[ct][i]; sq += xp[ct][i] * xp[ct][i]; }
      for (int off = 1; off < 16; off <<= 1) { s += __shfl_xor(s, off); sq += __shfl_xor(sq, off); }
      if (l16 == 0) { red1[wc][rowbase + quad * 4 + i] = s; red2[wc][rowbase + quad * 4 + i] = sq; }
    }
    __syncthreads();  // red visible; also all As(o) reads done
#pragma unroll
    for (int i = 0; i < 4; ++i) {
      int r = rowbase + quad * 4 + i;
      float mu = (red1[0][r] + red1[1][r]) * (1.f / 128.f);
      float var = (red2[0][r] + red2[1][r]) * (1.f / 128.f) - mu * mu;
      mu_[i] = mu;
      rs_[i] = rsqrtf(var + 1e-5f);
    }
#pragma unroll
    for (int ct = 0; ct < 4; ++ct)
#pragma unroll
      for (int i = 0; i < 4; ++i) {
        int rowL = rowbase + quad * 4 + i;
        int col = colbase + ct * 16 + l16;
        float h2 = (xp[ct][i] - mu_[i]) * rs_[i] * g2l[col] + b2l[col];
        h2 *= table[tbase + col];
        As[rowL * 128 + (((col >> 3) ^ (rowL & 15)) << 3) + (col & 7)] = f2bf(h2);
      }
    __syncthreads();  // h2 visible

    // ---------------- FFN: ring-scheduled stages ---------------------------
    // buffer ring: c0 W1@1 W2@2; c1 W1@0 W2@1; c2 W1@2 W2@0; c3 W1@1 W2@2.
    f32x4 acc2[4];
#pragma unroll
    for (int j = 0; j < 4; ++j) acc2[j] = f32x4{0.f, 0.f, 0.f, 0.f};
    const int bufW1[4] = {1, 0, 2, 1};
    const int bufW2[4] = {2, 1, 0, 2};
#pragma unroll
    for (int c = 0; c < 4; ++c) {
      f32x4 accF[4];
#pragma unroll
      for (int j = 0; j < 4; ++j) accF[j] = f32x4{0.f, 0.f, 0.f, 0.f};
      mfma4(As, Bs[bufW1[c]], rowbase, colbase, quad, l16, accF);
#pragma unroll
      for (int ct = 0; ct < 4; ++ct)
#pragma unroll
        for (int i = 0; i < 4; ++i) {
          int rowL = rowbase + quad * 4 + i;
          int col = colbase + ct * 16 + l16;
          Cs[rowL * 128 + (((col >> 3) ^ (rowL & 15)) << 3) + (col & 7)] =
              f2bf(fmaxf(accF[ct][i], 0.f));
        }
      __syncthreads();  // hf visible; W1c reads done; prior issues drained
      if (c < 3) issue_tile(wt + (4 + 2 * (c + 1)) * TILE, Bs[bufW1[c + 1]], w, lane);
      else if (l < L_ - 1) issue_tile(wt + WLAYER + 0 * TILE, Bs[0], w, lane);  // next K
      mfma4(Cs, Bs[bufW2[c]], rowbase, colbase, quad, l16, acc2);
      __syncthreads();  // Cs reads done (safe rewrite); W2c reads done
      if (c < 3) issue_tile(wt + (5 + 2 * (c + 1)) * TILE, Bs[bufW2[c + 1]], w, lane);
      else if (l < L_ - 1) {
        issue_tile(wt + WLAYER + 1 * TILE, Bs[1], w, lane);  // next V
        issue_tile(wt + WLAYER + 2 * TILE, Bs[2], w, lane);  // next Q
      }
    }
    // epilogue: x'' = x' + ffn (registers only)
    if (l < L_ - 1) {
#pragma unroll
      for (int ct = 0; ct < 4; ++ct)
#pragma unroll
        for (int i = 0; i < 4; ++i) xreg[ct][i] = xp[ct][i] + acc2[ct][i];
    } else {
      float pr[4] = {0.f, 0.f, 0.f, 0.f};
#pragma unroll
      for (int ct = 0; ct < 4; ++ct)
#pragma unroll
        for (int i = 0; i < 4; ++i)
          pr[i] += (xp[ct][i] + acc2[ct][i]) * fcw[colbase + ct * 16 + l16];
#pragma unroll
      for (int i = 0; i < 4; ++i) {
        float s = pr[i];
        for (int off = 1; off < 16; off <<= 1) s += __shfl_xor(s, off);
        if (l16 == 0) red1[wc][rowbase + quad * 4 + i] = s;
      }
      __syncthreads();
      if (wc == 0 && l16 == 0)
#pragma unroll
        for (int i = 0; i < 4; ++i) {
          int r = rowbase + quad * 4 + i;
          out[row0 + r] = red1[0][r] + red1[1][r] + fcb[0];
        }
    }
  }
}

// ---------------------------------------------------------------------------
extern "C" void kernel_launch(void* const* d_in, const int* in_sizes, int n_in,
                              void* d_out, int out_size, void* d_ws, size_t ws_size,
                              hipStream_t stream) {
  const float* r_t       = (const float*)d_in[0];
  const int*   t         = (const int*)d_in[1];
  const int*   pcm       = (const int*)d_in[2];
  const float* src_embed = (const float*)d_in[4];
  const float* time_tab  = (const float*)d_in[5];
  const float* Wq = (const float*)d_in[6];
  const float* Wk = (const float*)d_in[7];
  const float* Wv = (const float*)d_in[8];
  const float* Wo = (const float*)d_in[9];
  const float* W1 = (const float*)d_in[10];
  const float* W2 = (const float*)d_in[11];
  const float* g1 = (const float*)d_in[12];
  const float* b1 = (const float*)d_in[13];
  const float* g2 = (const float*)d_in[14];
  const float* b2 = (const float*)d_in[15];
  const float* fc_w = (const float*)d_in[16];
  const float* fc_b = (const float*)d_in[17];
  float* out = (float*)d_out;

  char* ws = (char*)d_ws;
  size_t off = 0;
  auto alloc = [&](size_t bytes) -> void* {
    void* p = ws + off;
    off = (off + bytes + 255) & ~(size_t)255;
    return p;
  };
  float*          x    = (float*)alloc((size_t)ROWS * D_ * 4);
  unsigned short* kv0  = (unsigned short*)alloc((size_t)ROWS * 256 * 2);
  unsigned short* kv1  = (unsigned short*)alloc((size_t)ROWS * 256 * 2);
  int*            adj  = (int*)alloc((size_t)S_ * MAXDEG * 4);
  int*            adjc = (int*)alloc((size_t)S_ * 4);
  unsigned short* wbf  = (unsigned short*)alloc((size_t)L_ * WLAYER * 2);
  unsigned*       bcnt = (unsigned*)alloc(8 * 32 * 4);

  adj_init<<<(S_ + 255) / 256, 256, 0, stream>>>(adj, adjc);
  adj_build<<<M_, 64, 0, stream>>>(pcm, adj, adjc);
  wconv_kernel<<<L_ * NTILE, 256, 0, stream>>>(Wq, Wk, Wv, Wo, W1, W2, wbf);
  xinit_kernel<<<ROWS, 128, 0, stream>>>(r_t, adj, adjc, src_embed, t, time_tab, x, bcnt);

  mega_kernel<<<NBLK, 384, 0, stream>>>(x, kv0, kv1, wbf, g1, b1, g2, b2,
                                        t, time_tab, adj, adjc, fc_w, fc_b, out, bcnt);
}

// Round 16
// 259.988 us; speedup vs baseline: 2.3683x; 1.1022x over previous
//
#include <hip/hip_runtime.h>
#include <cmath>
#include <cstdint>

// Problem constants (from reference)
constexpr int B_ = 8, N_ = 1024, M_ = 512, D_ = 128, S_ = 1536, L_ = 6, DFF_ = 512;
constexpr int ROWS = B_ * S_;    // 12288
constexpr int MAXDEG = 64;       // max attention row degree (actual ~4-25)
constexpr int LKEY = 32;         // LDS-cached keys per row
constexpr int RPB  = 48;         // rows per block
constexpr int NBLK = ROWS / RPB; // 256 persistent blocks (1/CU, all resident)
constexpr int BPB  = S_ / RPB;   // 32 blocks per batch (barrier group)
constexpr int NTILE = 12;        // weight tiles per layer, in stage order
constexpr int TILE  = 128 * 128; // halfwords per tile (LDS image, 32 KB)
constexpr int KVSZ  = ROWS * 256;// halfwords per kv layer-buffer

typedef __bf16 bf16x8 __attribute__((ext_vector_type(8)));
typedef float  f32x4  __attribute__((ext_vector_type(4)));
typedef unsigned short u16x8 __attribute__((ext_vector_type(8)));

__device__ inline unsigned short f2bf(float f) {  // RNE fp32 -> bf16
  unsigned u = __float_as_uint(f);
  u += 0x7fffu + ((u >> 16) & 1u);
  return (unsigned short)(u >> 16);
}
__device__ inline float bf2f(unsigned short u) {
  return __uint_as_float(((unsigned)u) << 16);
}

// Direct global->LDS async copy, 16 B/lane (m97's lever).
__device__ __forceinline__ void async_ld16(const unsigned short* g, unsigned short* l) {
  __builtin_amdgcn_global_load_lds(
      (const __attribute__((address_space(1))) unsigned int*)(uintptr_t)g,
      (__attribute__((address_space(3))) unsigned int*)(unsigned)(uintptr_t)l,
      16, 0, 0);
}
// Issue one 32 KB tile (pre-swizzled LDS image) into a Bs buffer.
__device__ __forceinline__ void issue_tile(const unsigned short* tp, unsigned short* bs,
                                           int w, int lane) {
  for (int c = w; c < 32; c += 6)
    async_ld16(tp + c * 512 + lane * 8, bs + c * 512);
}

// ---------------------------------------------------------------------------
// Adjacency, built from pcm ROWS (coalesced). Self-edge first, then both
// Tanner directions via atomic append. Order is irrelevant: softmax and mod-2
// syndrome are permutation-invariant. exp(-1e9-max) underflows to 0 in fp32
// => sparse attention over this list == dense masked softmax.
// ---------------------------------------------------------------------------
__global__ void adj_init(int* __restrict__ adj, int* __restrict__ adjcnt) {
  int s = blockIdx.x * blockDim.x + threadIdx.x;
  if (s < S_) { adj[s * MAXDEG] = s; adjcnt[s] = 1; }
}
__global__ void adj_build(const int* __restrict__ pcm, int* __restrict__ adj,
                          int* __restrict__ adjcnt) {
  int c = blockIdx.x;      // check row 0..511
  int lane = threadIdx.x;  // 0..63
  const int* row = pcm + c * N_;
  for (int base = 0; base < N_; base += 64) {
    int k = base + lane;
    if (row[k] != 0) {
      int s1 = atomicAdd(&adjcnt[N_ + c], 1);
      if (s1 < MAXDEG) adj[(N_ + c) * MAXDEG + s1] = k;
      int s2 = atomicAdd(&adjcnt[k], 1);
      if (s2 < MAXDEG) adj[k * MAXDEG + s2] = N_ + c;
    }
  }
}

// ---------------------------------------------------------------------------
// x init; also zeroes the 8 per-batch barrier counters (ws poisoned 0xAA).
// ---------------------------------------------------------------------------
__global__ void xinit_kernel(const float* __restrict__ r_t, const int* __restrict__ adj,
                             const int* __restrict__ adjcnt, const float* __restrict__ se,
                             const int* __restrict__ tt, const float* __restrict__ table,
                             float* __restrict__ x, unsigned* __restrict__ barrier_cnt) {
  int bs = blockIdx.x;
  int b = bs / S_, s = bs % S_;
  int d = threadIdx.x;
  if (bs < 8 && d == 0)
    __hip_atomic_store(barrier_cnt + bs * 32, 0u, __ATOMIC_RELAXED, __HIP_MEMORY_SCOPE_AGENT);
  float node;
  if (s < N_) {
    node = fabsf(r_t[b * N_ + s]);
  } else {
    int cnt = adjcnt[s]; cnt = cnt < MAXDEG ? cnt : MAXDEG;
    float sum = 0.f;
    for (int j = 0; j < cnt; ++j) {
      int k = adj[s * MAXDEG + j];
      if (k < N_) {
        float r = r_t[b * N_ + k];
        sum += (r < 0.f) ? 1.f : (r > 0.f ? 0.f : 0.5f);
      }
    }
    node = fmodf(sum, 2.0f);
  }
  x[(size_t)bs * D_ + d] = table[tt[b] * D_ + d] * se[s * D_ + d] * node;
}

// ---------------------------------------------------------------------------
// Weight convert via LDS transpose staging: coalesced fp32 reads -> bf16 LDS
// tile (padded) -> coalesced pre-swizzled LDS-image writes. Stage order:
// [0]=Wk^T [1]=Wv^T [2]=Wq^T [3]=Wo^T [4+2c]=W1^T chunk c [5+2c]=W2^T chunk c.
// Image: tile[rr*128 + ((cc^(rr&15))<<3) + e] = W^T[rr][cc*8+e] = W[kd][rr].
// ---------------------------------------------------------------------------
constexpr int WLAYER = NTILE * TILE;  // 196608 halfwords per layer

__global__ void wconv_kernel(const float* __restrict__ Wq, const float* __restrict__ Wk,
                             const float* __restrict__ Wv, const float* __restrict__ Wo,
                             const float* __restrict__ W1, const float* __restrict__ W2,
                             unsigned short* __restrict__ out) {
  __shared__ unsigned short tl[128 * 130];  // +2 pad breaks transpose conflicts
  int bid = blockIdx.x;
  int l = bid / NTILE, tile = bid % NTILE;
  const float* src;
  int rstride, coff = 0;
  if (tile == 0)      { src = Wk + (size_t)l * D_ * D_;  rstride = D_; }
  else if (tile == 1) { src = Wv + (size_t)l * D_ * D_;  rstride = D_; }
  else if (tile == 2) { src = Wq + (size_t)l * D_ * D_;  rstride = D_; }
  else if (tile == 3) { src = Wo + (size_t)l * D_ * D_;  rstride = D_; }
  else {
    int c = (tile - 4) >> 1;
    if (((tile - 4) & 1) == 0) { src = W1 + (size_t)l * D_ * DFF_; rstride = DFF_; coff = c * 128; }
    else                       { src = W2 + (size_t)l * DFF_ * D_ + (size_t)c * 128 * D_; rstride = D_; }
  }
  for (int i = threadIdx.x; i < 16384; i += 256) {  // coalesced row reads
    int kd = i >> 7, rr = i & 127;
    tl[kd * 130 + rr] = f2bf(src[(size_t)kd * rstride + coff + rr]);
  }
  __syncthreads();
  unsigned short* o = out + (size_t)bid * TILE;
  for (int i = threadIdx.x; i < 16384; i += 256) {  // coalesced image writes
    int rr = i >> 7;
    int sw = (i >> 3) & 15, e = i & 7;
    int kd = (sw ^ (rr & 15)) * 8 + e;
    o[i] = tl[kd * 130 + rr];
  }
}

// ---------------------------------------------------------------------------
// MFMA helper: wave tile = 16 rows x 64 cols (4 tiles of 16x16), K=128 in 4
// steps of 32. LDS: 16B chunks XOR-swizzled [row*128 + ((c^(row&15))<<3)].
// ---------------------------------------------------------------------------
__device__ __forceinline__ void mfma4(const unsigned short* As, const unsigned short* Bs,
                                      int rowbase, int colbase, int quad, int l16,
                                      f32x4 (&acc)[4]) {
#pragma unroll
  for (int kk = 0; kk < 4; ++kk) {
    int cb = kk * 4 + quad;
    int row = rowbase + l16;
    bf16x8 a = __builtin_bit_cast(bf16x8, *(const uint4*)&As[row * 128 + ((cb ^ (row & 15)) << 3)]);
    bf16x8 bb[4];
#pragma unroll
    for (int ct = 0; ct < 4; ++ct) {
      int n = colbase + ct * 16 + l16;
      bb[ct] = __builtin_bit_cast(bf16x8, *(const uint4*)&Bs[n * 128 + ((cb ^ (n & 15)) << 3)]);
    }
#pragma unroll
    for (int ct = 0; ct < 4; ++ct)
      acc[ct] = __builtin_amdgcn_mfma_f32_16x16x32_bf16(a, bb[ct], acc[ct], 0, 0, 0);
  }
}

// ---------------------------------------------------------------------------
// Fence-free per-batch barrier (R10-proven): kv stores are agent-scope
// atomics (write through to LLC); __syncthreads drains each wave's stores
// before the counter bump. 32 blocks per group.
// ---------------------------------------------------------------------------
__device__ __forceinline__ void grid_barrier(unsigned* cnt, unsigned target) {
  __syncthreads();
  if (threadIdx.x == 0) {
    __hip_atomic_fetch_add(cnt, 1u, __ATOMIC_RELAXED, __HIP_MEMORY_SCOPE_AGENT);
    while (__hip_atomic_load(cnt, __ATOMIC_RELAXED, __HIP_MEMORY_SCOPE_AGENT) < target)
      __builtin_amdgcn_s_sleep(4);
  }
  __syncthreads();
}

// ---------------------------------------------------------------------------
// Persistent mega-kernel: all 6 layers + fc head.
// grid = 256 blocks x 384 thr (6 waves); block owns 48 rows; 1 block/CU.
// Bs = 3-buffer ring (96 KB). kv: ONE BUFFER PER LAYER -> every kv address
// is written exactly once per launch (agent-scope store -> LLC; no XCD ever
// cached it pre-write since dispatch-acquire invalidated caches), so the
// attention gather uses NORMAL cached vector loads: first touch = LLC,
// neighbor reuse hits L2 (~3x lower latency than the old agent-scope
// atomic-load path which always bypassed to LLC).
// LDS: As 12K + Bs 96K + Cs 12K + KVs 24K + sKeys 6K + red 0.8K ~= 151 KB.
// ---------------------------------------------------------------------------
__global__ void __launch_bounds__(384) mega_kernel(
    const float* __restrict__ x0, unsigned short* __restrict__ kvbase,
    const unsigned short* __restrict__ wbf,
    const float* __restrict__ g1, const float* __restrict__ b1,
    const float* __restrict__ g2, const float* __restrict__ b2,
    const int* __restrict__ tt, const float* __restrict__ table,
    const int* __restrict__ adj, const int* __restrict__ adjc,
    const float* __restrict__ fcw, const float* __restrict__ fcb,
    float* __restrict__ out, unsigned* barrier_cnt) {
  __shared__ unsigned short As[RPB * 128];      // 12 KB
  __shared__ unsigned short Bs[3][TILE];        // 96 KB (ring)
  __shared__ unsigned short Cs[RPB * 128];      // 12 KB (Q, then FFN hf)
  __shared__ unsigned short KVs[RPB * 256];     // 24 KB (K|V repack)
  __shared__ float red1[2][RPB], red2[2][RPB];
  __shared__ int sKeys[RPB * LKEY];             // 6 KB
  __shared__ int sCnt[RPB];
  const int row0 = blockIdx.x * RPB;
  const int b = row0 / S_;
  const int bS = b * S_;
  const int t = threadIdx.x, w = t >> 6, lane = t & 63, quad = lane >> 4, l16 = lane & 15;
  const int wr = w >> 1, wc = w & 1;
  const int rowbase = wr * 16, colbase = wc * 64;
  const int tbase = tt[b] * D_;
  unsigned* bcnt = barrier_cnt + b * 32;  // per-batch counter, 128 B apart

  // prime the pipeline: layer-0 K,V,Q tiles -> Bs[0..2]
  issue_tile(wbf + 0 * TILE, Bs[0], w, lane);
  issue_tile(wbf + 1 * TILE, Bs[1], w, lane);
  issue_tile(wbf + 2 * TILE, Bs[2], w, lane);

  // persistent x in registers (MFMA C-layout)
  f32x4 xreg[4];
#pragma unroll
  for (int ct = 0; ct < 4; ++ct)
#pragma unroll
    for (int i = 0; i < 4; ++i) {
      int row = row0 + rowbase + quad * 4 + i;
      int col = colbase + ct * 16 + l16;
      xreg[ct][i] = x0[(size_t)row * D_ + col];
    }
  if (t < RPB) {
    int c = adjc[row0 + t - bS];
    sCnt[t] = c < MAXDEG ? c : MAXDEG;
  }
  for (int i = t; i < RPB * LKEY; i += 384) {
    int r = i / LKEY, j = i % LKEY;
    sKeys[i] = adj[(row0 + r - bS) * MAXDEG + j];  // tail values unused (clamped)
  }

  for (int l = 0; l < L_; ++l) {
    const unsigned short* wt = wbf + (size_t)l * WLAYER;
    const float* g1l = g1 + l * D_;
    const float* b1l = b1 + l * D_;
    const float* g2l = g2 + l * D_;
    const float* b2l = b2 + l * D_;
    unsigned short* kv = kvbase + (size_t)l * KVSZ;  // per-layer buffer

    // ------------- LN1 (one-pass var) on register x -> bf16 h in As --------
    float mu1[4], rs1[4];
#pragma unroll
    for (int i = 0; i < 4; ++i) {
      float s = 0.f, sq = 0.f;
#pragma unroll
      for (int ct = 0; ct < 4; ++ct) { s += xreg[ct][i]; sq += xreg[ct][i] * xreg[ct][i]; }
      for (int off = 1; off < 16; off <<= 1) { s += __shfl_xor(s, off); sq += __shfl_xor(sq, off); }
      if (l16 == 0) { red1[wc][rowbase + quad * 4 + i] = s; red2[wc][rowbase + quad * 4 + i] = sq; }
    }
    __syncthreads();
#pragma unroll
    for (int i = 0; i < 4; ++i) {
      int r = rowbase + quad * 4 + i;
      float mu = (red1[0][r] + red1[1][r]) * (1.f / 128.f);
      float var = (red2[0][r] + red2[1][r]) * (1.f / 128.f) - mu * mu;
      mu1[i] = mu;
      rs1[i] = rsqrtf(var + 1e-5f);
    }
#pragma unroll
    for (int ct = 0; ct < 4; ++ct)
#pragma unroll
      for (int i = 0; i < 4; ++i) {
        int rowL = rowbase + quad * 4 + i;
        int col = colbase + ct * 16 + l16;
        float h = (xreg[ct][i] - mu1[i]) * rs1[i] * g1l[col] + b1l[col];
        As[rowL * 128 + (((col >> 3) ^ (rowL & 15)) << 3) + (col & 7)] = f2bf(h);
      }
    __syncthreads();  // As(h) visible; K,V,Q tiles drained

    // ------------- QKV: three barrier-free MFMA stages ---------------------
    {  // K -> KVs[:,0:128)  (wave-private region)
      f32x4 acc[4];
#pragma unroll
      for (int j = 0; j < 4; ++j) acc[j] = f32x4{0.f, 0.f, 0.f, 0.f};
      mfma4(As, Bs[0], rowbase, colbase, quad, l16, acc);
#pragma unroll
      for (int ct = 0; ct < 4; ++ct)
#pragma unroll
        for (int i = 0; i < 4; ++i) {
          int rowL = rowbase + quad * 4 + i;
          KVs[rowL * 256 + colbase + ct * 16 + l16] = f2bf(acc[ct][i]);
        }
    }
    {  // V -> KVs[:,128:256)
      f32x4 acc[4];
#pragma unroll
      for (int j = 0; j < 4; ++j) acc[j] = f32x4{0.f, 0.f, 0.f, 0.f};
      mfma4(As, Bs[1], rowbase, colbase, quad, l16, acc);
#pragma unroll
      for (int ct = 0; ct < 4; ++ct)
#pragma unroll
        for (int i = 0; i < 4; ++i) {
          int rowL = rowbase + quad * 4 + i;
          KVs[rowL * 256 + 128 + colbase + ct * 16 + l16] = f2bf(acc[ct][i]);
        }
    }
    {  // Q -> Cs (swizzled A-layout, kept for attention)
      f32x4 acc[4];
#pragma unroll
      for (int j = 0; j < 4; ++j) acc[j] = f32x4{0.f, 0.f, 0.f, 0.f};
      mfma4(As, Bs[2], rowbase, colbase, quad, l16, acc);
#pragma unroll
      for (int ct = 0; ct < 4; ++ct)
#pragma unroll
        for (int i = 0; i < 4; ++i) {
          int rowL = rowbase + quad * 4 + i;
          int col = colbase + ct * 16 + l16;
          Cs[rowL * 128 + (((col >> 3) ^ (rowL & 15)) << 3) + (col & 7)] = f2bf(acc[ct][i]);
        }
    }
    __syncthreads();  // KVs complete block-wide
    for (int i = t; i < RPB * 128; i += 384) {  // 128 dwords/row: K|V
      int rL = i >> 7, cw = i & 127;
      unsigned u = *(const unsigned*)&KVs[rL * 256 + cw * 2];
      __hip_atomic_store((unsigned*)&kv[(size_t)(row0 + rL) * 256 + cw * 2],
                         u, __ATOMIC_RELAXED, __HIP_MEMORY_SCOPE_AGENT);
    }

    // -------- per-batch fence-free barrier: batch kv visible ---------------
    grid_barrier(bcnt, (unsigned)(BPB * (l + 1)));

    // Wo + W1c0 + W2c0 (96 KB) all land under the attention gather
    issue_tile(wt + 3 * TILE, Bs[0], w, lane);
    issue_tile(wt + 4 * TILE, Bs[1], w, lane);
    issue_tile(wt + 5 * TILE, Bs[2], w, lane);

    // ------- attention (48 rows x 8 heads, one per thread; cached loads) ---
    {
      const int rL = t >> 3, h = t & 7;
      const int s = row0 + rL - bS;
      const int cnt = sCnt[rL];
      float q[16];
      {
        u16x8 qa = *(const u16x8*)&Cs[rL * 128 + (((2 * h) ^ (rL & 15)) << 3)];
        u16x8 qb = *(const u16x8*)&Cs[rL * 128 + (((2 * h + 1) ^ (rL & 15)) << 3)];
#pragma unroll
        for (int j = 0; j < 8; ++j) { q[j] = bf2f(qa[j]); q[8 + j] = bf2f(qb[j]); }
      }
      float m = -1e30f, lsum = 0.f;
      float o16[16];
#pragma unroll
      for (int j = 0; j < 16; ++j) o16[j] = 0.f;
      for (int jb = 0; jb < cnt; jb += 4) {  // 4 neighbors in flight
        u16x8 K[4][2], V[4][2];
#pragma unroll
        for (int u = 0; u < 4; ++u) {
          int j = jb + u;
          int key = 0;
          if (j < cnt) key = (j < LKEY) ? sKeys[rL * LKEY + j] : adj[s * MAXDEG + j];
          const u16x8* kp = (const u16x8*)(kv + (size_t)(bS + key) * 256 + h * 16);
          K[u][0] = kp[0];  K[u][1] = kp[1];    // K: 16 halves
          V[u][0] = kp[16]; V[u][1] = kp[17];   // V: +128 halves
        }
#pragma unroll
        for (int u = 0; u < 4; ++u) {
          float dot = 0.f;
#pragma unroll
          for (int j = 0; j < 8; ++j) {
            dot = fmaf(q[j], bf2f(K[u][0][j]), dot);
            dot = fmaf(q[8 + j], bf2f(K[u][1][j]), dot);
          }
          dot *= 0.25f;  // 1/sqrt(HD)
          if (jb + u >= cnt) dot = -1e30f;
          const float mn = fmaxf(m, dot);
          const float rescale = __expf(m - mn);
          const float e = __expf(dot - mn);
          lsum = lsum * rescale + e;
#pragma unroll
          for (int j = 0; j < 8; ++j) {
            o16[j]     = o16[j]     * rescale + e * bf2f(V[u][0][j]);
            o16[8 + j] = o16[8 + j] * rescale + e * bf2f(V[u][1][j]);
          }
          m = mn;
        }
      }
      const float inv = 1.f / lsum;
      u16x8 pk0, pk1;
#pragma unroll
      for (int j = 0; j < 8; ++j) {
        pk0[j] = f2bf(o16[j] * inv);
        pk1[j] = f2bf(o16[8 + j] * inv);
      }
      *(u16x8*)&As[rL * 128 + (((2 * h) ^ (rL & 15)) << 3)] = pk0;
      *(u16x8*)&As[rL * 128 + (((2 * h + 1) ^ (rL & 15)) << 3)] = pk1;
    }
    __syncthreads();  // As(o) visible; Wo/W1c0/W2c0 drained

    // ---------------- Wo; x'; LN2*te -> As ---------------------------------
    f32x4 acc1[4];
#pragma unroll
    for (int j = 0; j < 4; ++j) acc1[j] = f32x4{0.f, 0.f, 0.f, 0.f};
    mfma4(As, Bs[0], rowbase, colbase, quad, l16, acc1);
    f32x4 xp[4];
#pragma unroll
    for (int ct = 0; ct < 4; ++ct)
#pragma unroll
      for (int i = 0; i < 4; ++i) xp[ct][i] = xreg[ct][i] + acc1[ct][i];
    float mu_[4], rs_[4];
#pragma unroll
    for (int i = 0; i < 4; ++i) {
      float s = 0.f, sq = 0.f;
#pragma unroll
      for (int ct = 0; ct < 4; ++ct) { s += xp[ct][i]; sq += xp[ct][i] * xp[ct][i]; }
      for (int off = 1; off < 16; off <<= 1) { s += __shfl_xor(s, off); sq += __shfl_xor(sq, off); }
      if (l16 == 0) { red1[wc][rowbase + quad * 4 + i] = s; red2[wc][rowbase + quad * 4 + i] = sq; }
    }
    __syncthreads();  // red visible; also all As(o) reads done
#pragma unroll
    for (int i = 0; i < 4; ++i) {
      int r = rowbase + quad * 4 + i;
      float mu = (red1[0][r] + red1[1][r]) * (1.f / 128.f);
      float var = (red2[0][r] + red2[1][r]) * (1.f / 128.f) - mu * mu;
      mu_[i] = mu;
      rs_[i] = rsqrtf(var + 1e-5f);
    }
#pragma unroll
    for (int ct = 0; ct < 4; ++ct)
#pragma unroll
      for (int i = 0; i < 4; ++i) {
        int rowL = rowbase + quad * 4 + i;
        int col = colbase + ct * 16 + l16;
        float h2 = (xp[ct][i] - mu_[i]) * rs_[i] * g2l[col] + b2l[col];
        h2 *= table[tbase + col];
        As[rowL * 128 + (((col >> 3) ^ (rowL & 15)) << 3) + (col & 7)] = f2bf(h2);
      }
    __syncthreads();  // h2 visible

    // ---------------- FFN: ring-scheduled stages ---------------------------
    // buffer ring: c0 W1@1 W2@2; c1 W1@0 W2@1; c2 W1@2 W2@0; c3 W1@1 W2@2.
    f32x4 acc2[4];
#pragma unroll
    for (int j = 0; j < 4; ++j) acc2[j] = f32x4{0.f, 0.f, 0.f, 0.f};
    const int bufW1[4] = {1, 0, 2, 1};
    const int bufW2[4] = {2, 1, 0, 2};
#pragma unroll
    for (int c = 0; c < 4; ++c) {
      f32x4 accF[4];
#pragma unroll
      for (int j = 0; j < 4; ++j) accF[j] = f32x4{0.f, 0.f, 0.f, 0.f};
      mfma4(As, Bs[bufW1[c]], rowbase, colbase, quad, l16, accF);
#pragma unroll
      for (int ct = 0; ct < 4; ++ct)
#pragma unroll
        for (int i = 0; i < 4; ++i) {
          int rowL = rowbase + quad * 4 + i;
          int col = colbase + ct * 16 + l16;
          Cs[rowL * 128 + (((col >> 3) ^ (rowL & 15)) << 3) + (col & 7)] =
              f2bf(fmaxf(accF[ct][i], 0.f));
        }
      __syncthreads();  // hf visible; W1c reads done; prior issues drained
      if (c < 3) issue_tile(wt + (4 + 2 * (c + 1)) * TILE, Bs[bufW1[c + 1]], w, lane);
      else if (l < L_ - 1) issue_tile(wt + WLAYER + 0 * TILE, Bs[0], w, lane);  // next K
      mfma4(Cs, Bs[bufW2[c]], rowbase, colbase, quad, l16, acc2);
      __syncthreads();  // Cs reads done (safe rewrite); W2c reads done
      if (c < 3) issue_tile(wt + (5 + 2 * (c + 1)) * TILE, Bs[bufW2[c + 1]], w, lane);
      else if (l < L_ - 1) {
        issue_tile(wt + WLAYER + 1 * TILE, Bs[1], w, lane);  // next V
        issue_tile(wt + WLAYER + 2 * TILE, Bs[2], w, lane);  // next Q
      }
    }
    // epilogue: x'' = x' + ffn (registers only)
    if (l < L_ - 1) {
#pragma unroll
      for (int ct = 0; ct < 4; ++ct)
#pragma unroll
        for (int i = 0; i < 4; ++i) xreg[ct][i] = xp[ct][i] + acc2[ct][i];
    } else {
      float pr[4] = {0.f, 0.f, 0.f, 0.f};
#pragma unroll
      for (int ct = 0; ct < 4; ++ct)
#pragma unroll
        for (int i = 0; i < 4; ++i)
          pr[i] += (xp[ct][i] + acc2[ct][i]) * fcw[colbase + ct * 16 + l16];
#pragma unroll
      for (int i = 0; i < 4; ++i) {
        float s = pr[i];
        for (int off = 1; off < 16; off <<= 1) s += __shfl_xor(s, off);
        if (l16 == 0) red1[wc][rowbase + quad * 4 + i] = s;
      }
      __syncthreads();
      if (wc == 0 && l16 == 0)
#pragma unroll
        for (int i = 0; i < 4; ++i) {
          int r = rowbase + quad * 4 + i;
          out[row0 + r] = red1[0][r] + red1[1][r] + fcb[0];
        }
    }
  }
}

// ---------------------------------------------------------------------------
extern "C" void kernel_launch(void* const* d_in, const int* in_sizes, int n_in,
                              void* d_out, int out_size, void* d_ws, size_t ws_size,
                              hipStream_t stream) {
  const float* r_t       = (const float*)d_in[0];
  const int*   t         = (const int*)d_in[1];
  const int*   pcm       = (const int*)d_in[2];
  const float* src_embed = (const float*)d_in[4];
  const float* time_tab  = (const float*)d_in[5];
  const float* Wq = (const float*)d_in[6];
  const float* Wk = (const float*)d_in[7];
  const float* Wv = (const float*)d_in[8];
  const float* Wo = (const float*)d_in[9];
  const float* W1 = (const float*)d_in[10];
  const float* W2 = (const float*)d_in[11];
  const float* g1 = (const float*)d_in[12];
  const float* b1 = (const float*)d_in[13];
  const float* g2 = (const float*)d_in[14];
  const float* b2 = (const float*)d_in[15];
  const float* fc_w = (const float*)d_in[16];
  const float* fc_b = (const float*)d_in[17];
  float* out = (float*)d_out;

  char* ws = (char*)d_ws;
  size_t off = 0;
  auto alloc = [&](size_t bytes) -> void* {
    void* p = ws + off;
    off = (off + bytes + 255) & ~(size_t)255;
    return p;
  };
  float*          x    = (float*)alloc((size_t)ROWS * D_ * 4);
  unsigned short* kv   = (unsigned short*)alloc((size_t)L_ * KVSZ * 2);  // per-layer
  int*            adj  = (int*)alloc((size_t)S_ * MAXDEG * 4);
  int*            adjc = (int*)alloc((size_t)S_ * 4);
  unsigned short* wbf  = (unsigned short*)alloc((size_t)L_ * WLAYER * 2);
  unsigned*       bcnt = (unsigned*)alloc(8 * 32 * 4);

  adj_init<<<(S_ + 255) / 256, 256, 0, stream>>>(adj, adjc);
  adj_build<<<M_, 64, 0, stream>>>(pcm, adj, adjc);
  wconv_kernel<<<L_ * NTILE, 256, 0, stream>>>(Wq, Wk, Wv, Wo, W1, W2, wbf);
  xinit_kernel<<<ROWS, 128, 0, stream>>>(r_t, adj, adjc, src_embed, t, time_tab, x, bcnt);

  mega_kernel<<<NBLK, 384, 0, stream>>>(x, kv, wbf, g1, b1, g2, b2,
                                        t, time_tab, adj, adjc, fc_w, fc_b, out, bcnt);
}

// Round 17
// 255.306 us; speedup vs baseline: 2.4117x; 1.0183x over previous
//
#include <hip/hip_runtime.h>
#include <cmath>
#include <cstdint>

// Problem constants (from reference)
constexpr int B_ = 8, N_ = 1024, M_ = 512, D_ = 128, S_ = 1536, L_ = 6, DFF_ = 512;
constexpr int ROWS = B_ * S_;    // 12288
constexpr int MAXDEG = 64;       // max attention row degree (actual ~4-25)
constexpr int LKEY = 32;         // LDS-cached keys per row
constexpr int RPB  = 48;         // rows per block
constexpr int NBLK = ROWS / RPB; // 256 persistent blocks (1/CU, all resident)
constexpr int BPB  = S_ / RPB;   // 32 blocks per batch (barrier group)
constexpr int NTILE = 12;        // weight tiles per layer, in stage order
constexpr int TILE  = 128 * 128; // halfwords per tile (LDS image, 32 KB)
constexpr int KVSZ  = ROWS * 256;// halfwords per kv layer-buffer

typedef __bf16 bf16x8 __attribute__((ext_vector_type(8)));
typedef float  f32x4  __attribute__((ext_vector_type(4)));
typedef unsigned short u16x8 __attribute__((ext_vector_type(8)));

__device__ inline unsigned short f2bf(float f) {  // RNE fp32 -> bf16
  unsigned u = __float_as_uint(f);
  u += 0x7fffu + ((u >> 16) & 1u);
  return (unsigned short)(u >> 16);
}
__device__ inline float bf2f(unsigned short u) {
  return __uint_as_float(((unsigned)u) << 16);
}

// Direct global->LDS async copy, 16 B/lane (m97's lever).
__device__ __forceinline__ void async_ld16(const unsigned short* g, unsigned short* l) {
  __builtin_amdgcn_global_load_lds(
      (const __attribute__((address_space(1))) unsigned int*)(uintptr_t)g,
      (__attribute__((address_space(3))) unsigned int*)(unsigned)(uintptr_t)l,
      16, 0, 0);
}
// Issue one 32 KB tile (pre-swizzled LDS image) into a Bs buffer.
__device__ __forceinline__ void issue_tile(const unsigned short* tp, unsigned short* bs,
                                           int w, int lane) {
  for (int c = w; c < 32; c += 6)
    async_ld16(tp + c * 512 + lane * 8, bs + c * 512);
}

// ---------------------------------------------------------------------------
// Adjacency built from pcm ROWS (coalesced), both Tanner directions via
// atomic append (order irrelevant: softmax and mod-2 syndrome are
// permutation-invariant). Self-edges + counters pre-initialized by wconv
// (launched before this on the same stream). exp(-1e9-max) underflows to 0
// in fp32 => sparse attention over this list == dense masked softmax.
// ---------------------------------------------------------------------------
__global__ void adj_build(const int* __restrict__ pcm, int* __restrict__ adj,
                          int* __restrict__ adjcnt) {
  int c = blockIdx.x;      // check row 0..511
  int lane = threadIdx.x;  // 0..63
  const int* row = pcm + c * N_;
  for (int base = 0; base < N_; base += 64) {
    int k = base + lane;
    if (row[k] != 0) {
      int s1 = atomicAdd(&adjcnt[N_ + c], 1);
      if (s1 < MAXDEG) adj[(N_ + c) * MAXDEG + s1] = k;
      int s2 = atomicAdd(&adjcnt[k], 1);
      if (s2 < MAXDEG) adj[k * MAXDEG + s2] = N_ + c;
    }
  }
}

// ---------------------------------------------------------------------------
// Weight convert via LDS transpose staging: coalesced fp32 reads -> bf16 LDS
// tile (padded) -> coalesced pre-swizzled LDS-image writes. Stage order:
// [0]=Wk^T [1]=Wv^T [2]=Wq^T [3]=Wo^T [4+2c]=W1^T chunk c [5+2c]=W2^T chunk c.
// Image: tile[rr*128 + ((cc^(rr&15))<<3) + e] = W^T[rr][cc*8+e] = W[kd][rr].
// Spare duty (runs before adj_build on the stream): blocks 0..5 init the
// adjacency self-edges/counters; block 6 zeroes the 8 barrier counters.
// ---------------------------------------------------------------------------
constexpr int WLAYER = NTILE * TILE;  // 196608 halfwords per layer

__global__ void wconv_kernel(const float* __restrict__ Wq, const float* __restrict__ Wk,
                             const float* __restrict__ Wv, const float* __restrict__ Wo,
                             const float* __restrict__ W1, const float* __restrict__ W2,
                             unsigned short* __restrict__ out, int* __restrict__ adj,
                             int* __restrict__ adjcnt, unsigned* __restrict__ barrier_cnt) {
  __shared__ unsigned short tl[128 * 130];  // +2 pad breaks transpose conflicts
  int bid = blockIdx.x;
  if (bid < 6) {  // adjacency init (ws poisoned 0xAA each call)
    int s = bid * 256 + threadIdx.x;
    if (s < S_) { adj[s * MAXDEG] = s; adjcnt[s] = 1; }
  }
  if (bid == 6 && threadIdx.x < 8)
    __hip_atomic_store(barrier_cnt + threadIdx.x * 32, 0u,
                       __ATOMIC_RELAXED, __HIP_MEMORY_SCOPE_AGENT);
  int l = bid / NTILE, tile = bid % NTILE;
  const float* src;
  int rstride, coff = 0;
  if (tile == 0)      { src = Wk + (size_t)l * D_ * D_;  rstride = D_; }
  else if (tile == 1) { src = Wv + (size_t)l * D_ * D_;  rstride = D_; }
  else if (tile == 2) { src = Wq + (size_t)l * D_ * D_;  rstride = D_; }
  else if (tile == 3) { src = Wo + (size_t)l * D_ * D_;  rstride = D_; }
  else {
    int c = (tile - 4) >> 1;
    if (((tile - 4) & 1) == 0) { src = W1 + (size_t)l * D_ * DFF_; rstride = DFF_; coff = c * 128; }
    else                       { src = W2 + (size_t)l * DFF_ * D_ + (size_t)c * 128 * D_; rstride = D_; }
  }
  for (int i = threadIdx.x; i < 16384; i += 256) {  // coalesced row reads
    int kd = i >> 7, rr = i & 127;
    tl[kd * 130 + rr] = f2bf(src[(size_t)kd * rstride + coff + rr]);
  }
  __syncthreads();
  unsigned short* o = out + (size_t)bid * TILE;
  for (int i = threadIdx.x; i < 16384; i += 256) {  // coalesced image writes
    int rr = i >> 7;
    int sw = (i >> 3) & 15, e = i & 7;
    int kd = (sw ^ (rr & 15)) * 8 + e;
    o[i] = tl[kd * 130 + rr];
  }
}

// ---------------------------------------------------------------------------
// MFMA helper: wave tile = 16 rows x 64 cols (4 tiles of 16x16), K=128 in 4
// steps of 32. LDS: 16B chunks XOR-swizzled [row*128 + ((c^(row&15))<<3)].
// ---------------------------------------------------------------------------
__device__ __forceinline__ void mfma4(const unsigned short* As, const unsigned short* Bs,
                                      int rowbase, int colbase, int quad, int l16,
                                      f32x4 (&acc)[4]) {
#pragma unroll
  for (int kk = 0; kk < 4; ++kk) {
    int cb = kk * 4 + quad;
    int row = rowbase + l16;
    bf16x8 a = __builtin_bit_cast(bf16x8, *(const uint4*)&As[row * 128 + ((cb ^ (row & 15)) << 3)]);
    bf16x8 bb[4];
#pragma unroll
    for (int ct = 0; ct < 4; ++ct) {
      int n = colbase + ct * 16 + l16;
      bb[ct] = __builtin_bit_cast(bf16x8, *(const uint4*)&Bs[n * 128 + ((cb ^ (n & 15)) << 3)]);
    }
#pragma unroll
    for (int ct = 0; ct < 4; ++ct)
      acc[ct] = __builtin_amdgcn_mfma_f32_16x16x32_bf16(a, bb[ct], acc[ct], 0, 0, 0);
  }
}

// ---------------------------------------------------------------------------
// Fence-free per-batch barrier (R10-proven): kv stores are agent-scope
// atomics (write through to LLC); __syncthreads drains each wave's stores
// before the counter bump. 32 blocks per group.
// ---------------------------------------------------------------------------
__device__ __forceinline__ void grid_barrier(unsigned* cnt, unsigned target) {
  __syncthreads();
  if (threadIdx.x == 0) {
    __hip_atomic_fetch_add(cnt, 1u, __ATOMIC_RELAXED, __HIP_MEMORY_SCOPE_AGENT);
    while (__hip_atomic_load(cnt, __ATOMIC_RELAXED, __HIP_MEMORY_SCOPE_AGENT) < target)
      __builtin_amdgcn_s_sleep(4);
  }
  __syncthreads();
}

// ---------------------------------------------------------------------------
// Persistent mega-kernel: x-init + all 6 layers + fc head.
// grid = 256 blocks x 384 thr (6 waves); block owns 48 rows; 1 block/CU.
// Prologue computes x in-block (node from LDS-cached adjacency) straight
// into registers — no x global buffer. Bs = 3-buffer ring (96 KB). kv: one
// buffer per layer -> attention gather uses normal cached vector loads
// (neighbor reuse hits L2). K/V cross blocks via agent-scope atomic stores;
// per-batch fence-free barrier.
// LDS: As 12K + Bs 96K + Cs 12K + KVs 24K + sKeys 6K + red 0.8K ~= 151 KB.
// ---------------------------------------------------------------------------
__global__ void __launch_bounds__(384) mega_kernel(
    const float* __restrict__ r_t, const float* __restrict__ se,
    unsigned short* __restrict__ kvbase, const unsigned short* __restrict__ wbf,
    const float* __restrict__ g1, const float* __restrict__ b1,
    const float* __restrict__ g2, const float* __restrict__ b2,
    const int* __restrict__ tt, const float* __restrict__ table,
    const int* __restrict__ adj, const int* __restrict__ adjc,
    const float* __restrict__ fcw, const float* __restrict__ fcb,
    float* __restrict__ out, unsigned* barrier_cnt) {
  __shared__ unsigned short As[RPB * 128];      // 12 KB
  __shared__ unsigned short Bs[3][TILE];        // 96 KB (ring)
  __shared__ unsigned short Cs[RPB * 128];      // 12 KB (Q, then FFN hf)
  __shared__ unsigned short KVs[RPB * 256];     // 24 KB (K|V repack)
  __shared__ float red1[2][RPB], red2[2][RPB];
  __shared__ float nodeS[RPB];
  __shared__ int sKeys[RPB * LKEY];             // 6 KB
  __shared__ int sCnt[RPB];
  const int row0 = blockIdx.x * RPB;
  const int b = row0 / S_;
  const int bS = b * S_;
  const int t = threadIdx.x, w = t >> 6, lane = t & 63, quad = lane >> 4, l16 = lane & 15;
  const int wr = w >> 1, wc = w & 1;
  const int rowbase = wr * 16, colbase = wc * 64;
  const int tbase = tt[b] * D_;
  unsigned* bcnt = barrier_cnt + b * 32;  // per-batch counter, 128 B apart

  // prime the pipeline: layer-0 K,V,Q tiles -> Bs[0..2]
  issue_tile(wbf + 0 * TILE, Bs[0], w, lane);
  issue_tile(wbf + 1 * TILE, Bs[1], w, lane);
  issue_tile(wbf + 2 * TILE, Bs[2], w, lane);

  // ---- prologue: adjacency cache, node values, x straight into registers --
  if (t < RPB) {
    int c = adjc[row0 + t - bS];
    sCnt[t] = c < MAXDEG ? c : MAXDEG;
  }
  for (int i = t; i < RPB * LKEY; i += 384) {
    int r = i / LKEY, j = i % LKEY;
    sKeys[i] = adj[(row0 + r - bS) * MAXDEG + j];  // tail values unused (clamped)
  }
  __syncthreads();
  if (t < RPB) {
    int s = row0 + t - bS;
    float node;
    if (s < N_) {
      node = fabsf(r_t[b * N_ + s]);
    } else {
      int cnt = sCnt[t];
      float sum = 0.f;
      for (int j = 0; j < cnt; ++j) {
        int k = (j < LKEY) ? sKeys[t * LKEY + j] : adj[s * MAXDEG + j];
        if (k < N_) {
          float r = r_t[b * N_ + k];
          sum += (r < 0.f) ? 1.f : (r > 0.f ? 0.f : 0.5f);  // bits = 0.5*(1-sign)
        }
      }
      node = fmodf(sum, 2.0f);
    }
    nodeS[t] = node;
  }
  __syncthreads();
  // persistent x in registers (MFMA C-layout): x = te * se * node
  f32x4 xreg[4];
#pragma unroll
  for (int ct = 0; ct < 4; ++ct)
#pragma unroll
    for (int i = 0; i < 4; ++i) {
      int rowL = rowbase + quad * 4 + i;
      int s = row0 + rowL - bS;
      int col = colbase + ct * 16 + l16;
      xreg[ct][i] = table[tbase + col] * se[(size_t)s * D_ + col] * nodeS[rowL];
    }

  for (int l = 0; l < L_; ++l) {
    const unsigned short* wt = wbf + (size_t)l * WLAYER;
    const float* g1l = g1 + l * D_;
    const float* b1l = b1 + l * D_;
    const float* g2l = g2 + l * D_;
    const float* b2l = b2 + l * D_;
    unsigned short* kv = kvbase + (size_t)l * KVSZ;  // per-layer buffer

    // ------------- LN1 (one-pass var) on register x -> bf16 h in As --------
    float mu1[4], rs1[4];
#pragma unroll
    for (int i = 0; i < 4; ++i) {
      float s = 0.f, sq = 0.f;
#pragma unroll
      for (int ct = 0; ct < 4; ++ct) { s += xreg[ct][i]; sq += xreg[ct][i] * xreg[ct][i]; }
      for (int off = 1; off < 16; off <<= 1) { s += __shfl_xor(s, off); sq += __shfl_xor(sq, off); }
      if (l16 == 0) { red1[wc][rowbase + quad * 4 + i] = s; red2[wc][rowbase + quad * 4 + i] = sq; }
    }
    __syncthreads();
#pragma unroll
    for (int i = 0; i < 4; ++i) {
      int r = rowbase + quad * 4 + i;
      float mu = (red1[0][r] + red1[1][r]) * (1.f / 128.f);
      float var = (red2[0][r] + red2[1][r]) * (1.f / 128.f) - mu * mu;
      mu1[i] = mu;
      rs1[i] = rsqrtf(var + 1e-5f);
    }
#pragma unroll
    for (int ct = 0; ct < 4; ++ct)
#pragma unroll
      for (int i = 0; i < 4; ++i) {
        int rowL = rowbase + quad * 4 + i;
        int col = colbase + ct * 16 + l16;
        float h = (xreg[ct][i] - mu1[i]) * rs1[i] * g1l[col] + b1l[col];
        As[rowL * 128 + (((col >> 3) ^ (rowL & 15)) << 3) + (col & 7)] = f2bf(h);
      }
    __syncthreads();  // As(h) visible; K,V,Q tiles drained

    // ------------- QKV: three barrier-free MFMA stages ---------------------
    {  // K -> KVs[:,0:128)  (wave-private region)
      f32x4 acc[4];
#pragma unroll
      for (int j = 0; j < 4; ++j) acc[j] = f32x4{0.f, 0.f, 0.f, 0.f};
      mfma4(As, Bs[0], rowbase, colbase, quad, l16, acc);
#pragma unroll
      for (int ct = 0; ct < 4; ++ct)
#pragma unroll
        for (int i = 0; i < 4; ++i) {
          int rowL = rowbase + quad * 4 + i;
          KVs[rowL * 256 + colbase + ct * 16 + l16] = f2bf(acc[ct][i]);
        }
    }
    {  // V -> KVs[:,128:256)
      f32x4 acc[4];
#pragma unroll
      for (int j = 0; j < 4; ++j) acc[j] = f32x4{0.f, 0.f, 0.f, 0.f};
      mfma4(As, Bs[1], rowbase, colbase, quad, l16, acc);
#pragma unroll
      for (int ct = 0; ct < 4; ++ct)
#pragma unroll
        for (int i = 0; i < 4; ++i) {
          int rowL = rowbase + quad * 4 + i;
          KVs[rowL * 256 + 128 + colbase + ct * 16 + l16] = f2bf(acc[ct][i]);
        }
    }
    {  // Q -> Cs (swizzled A-layout, kept for attention)
      f32x4 acc[4];
#pragma unroll
      for (int j = 0; j < 4; ++j) acc[j] = f32x4{0.f, 0.f, 0.f, 0.f};
      mfma4(As, Bs[2], rowbase, colbase, quad, l16, acc);
#pragma unroll
      for (int ct = 0; ct < 4; ++ct)
#pragma unroll
        for (int i = 0; i < 4; ++i) {
          int rowL = rowbase + quad * 4 + i;
          int col = colbase + ct * 16 + l16;
          Cs[rowL * 128 + (((col >> 3) ^ (rowL & 15)) << 3) + (col & 7)] = f2bf(acc[ct][i]);
        }
    }
    __syncthreads();  // KVs complete block-wide
    for (int i = t; i < RPB * 128; i += 384) {  // 128 dwords/row: K|V
      int rL = i >> 7, cw = i & 127;
      unsigned u = *(const unsigned*)&KVs[rL * 256 + cw * 2];
      __hip_atomic_store((unsigned*)&kv[(size_t)(row0 + rL) * 256 + cw * 2],
                         u, __ATOMIC_RELAXED, __HIP_MEMORY_SCOPE_AGENT);
    }

    // -------- per-batch fence-free barrier: batch kv visible ---------------
    grid_barrier(bcnt, (unsigned)(BPB * (l + 1)));

    // Wo + W1c0 + W2c0 (96 KB) all land under the attention gather
    issue_tile(wt + 3 * TILE, Bs[0], w, lane);
    issue_tile(wt + 4 * TILE, Bs[1], w, lane);
    issue_tile(wt + 5 * TILE, Bs[2], w, lane);

    // ------- attention (48 rows x 8 heads, one per thread; cached loads) ---
    {
      const int rL = t >> 3, h = t & 7;
      const int s = row0 + rL - bS;
      const int cnt = sCnt[rL];
      float q[16];
      {
        u16x8 qa = *(const u16x8*)&Cs[rL * 128 + (((2 * h) ^ (rL & 15)) << 3)];
        u16x8 qb = *(const u16x8*)&Cs[rL * 128 + (((2 * h + 1) ^ (rL & 15)) << 3)];
#pragma unroll
        for (int j = 0; j < 8; ++j) { q[j] = bf2f(qa[j]); q[8 + j] = bf2f(qb[j]); }
      }
      float m = -1e30f, lsum = 0.f;
      float o16[16];
#pragma unroll
      for (int j = 0; j < 16; ++j) o16[j] = 0.f;
      for (int jb = 0; jb < cnt; jb += 4) {  // 4 neighbors in flight
        u16x8 K[4][2], V[4][2];
#pragma unroll
        for (int u = 0; u < 4; ++u) {
          int j = jb + u;
          int key = 0;
          if (j < cnt) key = (j < LKEY) ? sKeys[rL * LKEY + j] : adj[s * MAXDEG + j];
          const u16x8* kp = (const u16x8*)(kv + (size_t)(bS + key) * 256 + h * 16);
          K[u][0] = kp[0];  K[u][1] = kp[1];    // K: 16 halves
          V[u][0] = kp[16]; V[u][1] = kp[17];   // V: +128 halves
        }
#pragma unroll
        for (int u = 0; u < 4; ++u) {
          float dot = 0.f;
#pragma unroll
          for (int j = 0; j < 8; ++j) {
            dot = fmaf(q[j], bf2f(K[u][0][j]), dot);
            dot = fmaf(q[8 + j], bf2f(K[u][1][j]), dot);
          }
          dot *= 0.25f;  // 1/sqrt(HD)
          if (jb + u >= cnt) dot = -1e30f;
          const float mn = fmaxf(m, dot);
          const float rescale = __expf(m - mn);
          const float e = __expf(dot - mn);
          lsum = lsum * rescale + e;
#pragma unroll
          for (int j = 0; j < 8; ++j) {
            o16[j]     = o16[j]     * rescale + e * bf2f(V[u][0][j]);
            o16[8 + j] = o16[8 + j] * rescale + e * bf2f(V[u][1][j]);
          }
          m = mn;
        }
      }
      const float inv = 1.f / lsum;
      u16x8 pk0, pk1;
#pragma unroll
      for (int j = 0; j < 8; ++j) {
        pk0[j] = f2bf(o16[j] * inv);
        pk1[j] = f2bf(o16[8 + j] * inv);
      }
      *(u16x8*)&As[rL * 128 + (((2 * h) ^ (rL & 15)) << 3)] = pk0;
      *(u16x8*)&As[rL * 128 + (((2 * h + 1) ^ (rL & 15)) << 3)] = pk1;
    }
    __syncthreads();  // As(o) visible; Wo/W1c0/W2c0 drained

    // ---------------- Wo; x'; LN2*te -> As ---------------------------------
    f32x4 acc1[4];
#pragma unroll
    for (int j = 0; j < 4; ++j) acc1[j] = f32x4{0.f, 0.f, 0.f, 0.f};
    mfma4(As, Bs[0], rowbase, colbase, quad, l16, acc1);
    f32x4 xp[4];
#pragma unroll
    for (int ct = 0; ct < 4; ++ct)
#pragma unroll
      for (int i = 0; i < 4; ++i) xp[ct][i] = xreg[ct][i] + acc1[ct][i];
    float mu_[4], rs_[4];
#pragma unroll
    for (int i = 0; i < 4; ++i) {
      float s = 0.f, sq = 0.f;
#pragma unroll
      for (int ct = 0; ct < 4; ++ct) { s += xp[ct][i]; sq += xp[ct][i] * xp[ct][i]; }
      for (int off = 1; off < 16; off <<= 1) { s += __shfl_xor(s, off); sq += __shfl_xor(sq, off); }
      if (l16 == 0) { red1[wc][rowbase + quad * 4 + i] = s; red2[wc][rowbase + quad * 4 + i] = sq; }
    }
    __syncthreads();  // red visible; also all As(o) reads done
#pragma unroll
    for (int i = 0; i < 4; ++i) {
      int r = rowbase + quad * 4 + i;
      float mu = (red1[0][r] + red1[1][r]) * (1.f / 128.f);
      float var = (red2[0][r] + red2[1][r]) * (1.f / 128.f) - mu * mu;
      mu_[i] = mu;
      rs_[i] = rsqrtf(var + 1e-5f);
    }
#pragma unroll
    for (int ct = 0; ct < 4; ++ct)
#pragma unroll
      for (int i = 0; i < 4; ++i) {
        int rowL = rowbase + quad * 4 + i;
        int col = colbase + ct * 16 + l16;
        float h2 = (xp[ct][i] - mu_[i]) * rs_[i] * g2l[col] + b2l[col];
        h2 *= table[tbase + col];
        As[rowL * 128 + (((col >> 3) ^ (rowL & 15)) << 3) + (col & 7)] = f2bf(h2);
      }
    __syncthreads();  // h2 visible

    // ---------------- FFN: ring-scheduled stages ---------------------------
    // buffer ring: c0 W1@1 W2@2; c1 W1@0 W2@1; c2 W1@2 W2@0; c3 W1@1 W2@2.
    f32x4 acc2[4];
#pragma unroll
    for (int j = 0; j < 4; ++j) acc2[j] = f32x4{0.f, 0.f, 0.f, 0.f};
    const int bufW1[4] = {1, 0, 2, 1};
    const int bufW2[4] = {2, 1, 0, 2};
#pragma unroll
    for (int c = 0; c < 4; ++c) {
      f32x4 accF[4];
#pragma unroll
      for (int j = 0; j < 4; ++j) accF[j] = f32x4{0.f, 0.f, 0.f, 0.f};
      mfma4(As, Bs[bufW1[c]], rowbase, colbase, quad, l16, accF);
#pragma unroll
      for (int ct = 0; ct < 4; ++ct)
#pragma unroll
        for (int i = 0; i < 4; ++i) {
          int rowL = rowbase + quad * 4 + i;
          int col = colbase + ct * 16 + l16;
          Cs[rowL * 128 + (((col >> 3) ^ (rowL & 15)) << 3) + (col & 7)] =
              f2bf(fmaxf(accF[ct][i], 0.f));
        }
      __syncthreads();  // hf visible; W1c reads done; prior issues drained
      if (c < 3) issue_tile(wt + (4 + 2 * (c + 1)) * TILE, Bs[bufW1[c + 1]], w, lane);
      else if (l < L_ - 1) issue_tile(wt + WLAYER + 0 * TILE, Bs[0], w, lane);  // next K
      mfma4(Cs, Bs[bufW2[c]], rowbase, colbase, quad, l16, acc2);
      __syncthreads();  // Cs reads done (safe rewrite); W2c reads done
      if (c < 3) issue_tile(wt + (5 + 2 * (c + 1)) * TILE, Bs[bufW2[c + 1]], w, lane);
      else if (l < L_ - 1) {
        issue_tile(wt + WLAYER + 1 * TILE, Bs[1], w, lane);  // next V
        issue_tile(wt + WLAYER + 2 * TILE, Bs[2], w, lane);  // next Q
      }
    }
    // epilogue: x'' = x' + ffn (registers only)
    if (l < L_ - 1) {
#pragma unroll
      for (int ct = 0; ct < 4; ++ct)
#pragma unroll
        for (int i = 0; i < 4; ++i) xreg[ct][i] = xp[ct][i] + acc2[ct][i];
    } else {
      float pr[4] = {0.f, 0.f, 0.f, 0.f};
#pragma unroll
      for (int ct = 0; ct < 4; ++ct)
#pragma unroll
        for (int i = 0; i < 4; ++i)
          pr[i] += (xp[ct][i] + acc2[ct][i]) * fcw[colbase + ct * 16 + l16];
#pragma unroll
      for (int i = 0; i < 4; ++i) {
        float s = pr[i];
        for (int off = 1; off < 16; off <<= 1) s += __shfl_xor(s, off);
        if (l16 == 0) red1[wc][rowbase + quad * 4 + i] = s;
      }
      __syncthreads();
      if (wc == 0 && l16 == 0)
#pragma unroll
        for (int i = 0; i < 4; ++i) {
          int r = rowbase + quad * 4 + i;
          out[row0 + r] = red1[0][r] + red1[1][r] + fcb[0];
        }
    }
  }
}

// ---------------------------------------------------------------------------
extern "C" void kernel_launch(void* const* d_in, const int* in_sizes, int n_in,
                              void* d_out, int out_size, void* d_ws, size_t ws_size,
                              hipStream_t stream) {
  const float* r_t       = (const float*)d_in[0];
  const int*   t         = (const int*)d_in[1];
  const int*   pcm       = (const int*)d_in[2];
  const float* src_embed = (const float*)d_in[4];
  const float* time_tab  = (const float*)d_in[5];
  const float* Wq = (const float*)d_in[6];
  const float* Wk = (const float*)d_in[7];
  const float* Wv = (const float*)d_in[8];
  const float* Wo = (const float*)d_in[9];
  const float* W1 = (const float*)d_in[10];
  const float* W2 = (const float*)d_in[11];
  const float* g1 = (const float*)d_in[12];
  const float* b1 = (const float*)d_in[13];
  const float* g2 = (const float*)d_in[14];
  const float* b2 = (const float*)d_in[15];
  const float* fc_w = (const float*)d_in[16];
  const float* fc_b = (const float*)d_in[17];
  float* out = (float*)d_out;

  char* ws = (char*)d_ws;
  size_t off = 0;
  auto alloc = [&](size_t bytes) -> void* {
    void* p = ws + off;
    off = (off + bytes + 255) & ~(size_t)255;
    return p;
  };
  unsigned short* kv   = (unsigned short*)alloc((size_t)L_ * KVSZ * 2);  // per-layer
  int*            adj  = (int*)alloc((size_t)S_ * MAXDEG * 4);
  int*            adjc = (int*)alloc((size_t)S_ * 4);
  unsigned short* wbf  = (unsigned short*)alloc((size_t)L_ * WLAYER * 2);
  unsigned*       bcnt = (unsigned*)alloc(8 * 32 * 4);

  wconv_kernel<<<L_ * NTILE, 256, 0, stream>>>(Wq, Wk, Wv, Wo, W1, W2, wbf, adj, adjc, bcnt);
  adj_build<<<M_, 64, 0, stream>>>(pcm, adj, adjc);
  mega_kernel<<<NBLK, 384, 0, stream>>>(r_t, src_embed, kv, wbf, g1, b1, g2, b2,
                                        t, time_tab, adj, adjc, fc_w, fc_b, out, bcnt);
}

// Round 18
// 248.761 us; speedup vs baseline: 2.4751x; 1.0263x over previous
//
#include <hip/hip_runtime.h>
#include <cmath>
#include <cstdint>

// Problem constants (from reference)
constexpr int B_ = 8, N_ = 1024, M_ = 512, D_ = 128, S_ = 1536, L_ = 6, DFF_ = 512;
constexpr int ROWS = B_ * S_;    // 12288
constexpr int MAXDEG = 64;       // max attention row degree (actual ~4-25)
constexpr int LKEY = 32;         // LDS-cached keys per row
constexpr int RPB  = 48;         // rows per block
constexpr int NBLK = ROWS / RPB; // 256 persistent blocks (1/CU, all resident)
constexpr int BPB  = S_ / RPB;   // 32 blocks per batch (barrier group)
constexpr int NTILE = 12;        // weight tiles per layer, in stage order
constexpr int TILE  = 128 * 128; // halfwords per tile (LDS image, 32 KB)
constexpr int KVSZ  = ROWS * 256;// halfwords per kv layer-buffer

typedef __bf16 bf16x8 __attribute__((ext_vector_type(8)));
typedef float  f32x4  __attribute__((ext_vector_type(4)));
typedef unsigned short u16x8 __attribute__((ext_vector_type(8)));

__device__ inline unsigned short f2bf(float f) {  // RNE fp32 -> bf16
  unsigned u = __float_as_uint(f);
  u += 0x7fffu + ((u >> 16) & 1u);
  return (unsigned short)(u >> 16);
}
__device__ inline float bf2f(unsigned short u) {
  return __uint_as_float(((unsigned)u) << 16);
}

// Direct global->LDS async copy, 16 B/lane (m97's lever).
__device__ __forceinline__ void async_ld16(const unsigned short* g, unsigned short* l) {
  __builtin_amdgcn_global_load_lds(
      (const __attribute__((address_space(1))) unsigned int*)(uintptr_t)g,
      (__attribute__((address_space(3))) unsigned int*)(unsigned)(uintptr_t)l,
      16, 0, 0);
}
// Issue one 32 KB tile (pre-swizzled LDS image) into a Bs buffer.
__device__ __forceinline__ void issue_tile(const unsigned short* tp, unsigned short* bs,
                                           int w, int lane) {
  for (int c = w; c < 32; c += 6)
    async_ld16(tp + c * 512 + lane * 8, bs + c * 512);
}

// ---------------------------------------------------------------------------
// Adjacency built from pcm ROWS (coalesced), both Tanner directions via
// atomic append (order irrelevant: softmax and mod-2 syndrome are
// permutation-invariant). Self-edges + counters pre-initialized by wconv
// (launched before this on the same stream). exp(-1e9-max) underflows to 0
// in fp32 => sparse attention over this list == dense masked softmax.
// ---------------------------------------------------------------------------
__global__ void adj_build(const int* __restrict__ pcm, int* __restrict__ adj,
                          int* __restrict__ adjcnt) {
  int c = blockIdx.x;      // check row 0..511
  int lane = threadIdx.x;  // 0..63
  const int* row = pcm + c * N_;
  for (int base = 0; base < N_; base += 64) {
    int k = base + lane;
    if (row[k] != 0) {
      int s1 = atomicAdd(&adjcnt[N_ + c], 1);
      if (s1 < MAXDEG) adj[(N_ + c) * MAXDEG + s1] = k;
      int s2 = atomicAdd(&adjcnt[k], 1);
      if (s2 < MAXDEG) adj[k * MAXDEG + s2] = N_ + c;
    }
  }
}

// ---------------------------------------------------------------------------
// Weight convert via LDS transpose staging: coalesced fp32 reads -> bf16 LDS
// half-tile (padded) -> coalesced pre-swizzled LDS-image writes. Tile/stage
// order: [0]=Wk^T [1]=Wv^T [2]=Wq^T [3]=Wo^T [4+2c]=W1^T chk c [5+2c]=W2^T c.
// Image: tile[rr*128 + ((cc^(rr&15))<<3) + e] = W^T[rr][cc*8+e] = W[kd][rr].
// grid = 144 blocks (2 per tile: half = kd range [h*64, h*64+64)).
// Spare duty (runs before adj_build): blocks 0..5 init adjacency self-edges;
// block 6 zeroes the 8 barrier counters.
// ---------------------------------------------------------------------------
constexpr int WLAYER = NTILE * TILE;  // 196608 halfwords per layer

__global__ void wconv_kernel(const float* __restrict__ Wq, const float* __restrict__ Wk,
                             const float* __restrict__ Wv, const float* __restrict__ Wo,
                             const float* __restrict__ W1, const float* __restrict__ W2,
                             unsigned short* __restrict__ out, int* __restrict__ adj,
                             int* __restrict__ adjcnt, unsigned* __restrict__ barrier_cnt) {
  __shared__ unsigned short tl[64 * 130];  // +2 pad breaks transpose conflicts
  int bid = blockIdx.x;
  if (bid < 6) {  // adjacency init (ws poisoned 0xAA each call)
    int s = bid * 256 + threadIdx.x;
    if (s < S_) { adj[s * MAXDEG] = s; adjcnt[s] = 1; }
  }
  if (bid == 6 && threadIdx.x < 8)
    __hip_atomic_store(barrier_cnt + threadIdx.x * 32, 0u,
                       __ATOMIC_RELAXED, __HIP_MEMORY_SCOPE_AGENT);
  int tb = bid >> 1, half = bid & 1;       // tile block, kd-half
  int l = tb / NTILE, tile = tb % NTILE;
  const int kd0 = half * 64;
  const float* src;
  int rstride, coff = 0;
  if (tile == 0)      { src = Wk + (size_t)l * D_ * D_;  rstride = D_; }
  else if (tile == 1) { src = Wv + (size_t)l * D_ * D_;  rstride = D_; }
  else if (tile == 2) { src = Wq + (size_t)l * D_ * D_;  rstride = D_; }
  else if (tile == 3) { src = Wo + (size_t)l * D_ * D_;  rstride = D_; }
  else {
    int c = (tile - 4) >> 1;
    if (((tile - 4) & 1) == 0) { src = W1 + (size_t)l * D_ * DFF_; rstride = DFF_; coff = c * 128; }
    else                       { src = W2 + (size_t)l * DFF_ * D_ + (size_t)c * 128 * D_; rstride = D_; }
  }
  for (int i = threadIdx.x; i < 8192; i += 256) {  // coalesced row reads
    int kd = i >> 7, rr = i & 127;
    tl[kd * 130 + rr] = f2bf(src[(size_t)(kd0 + kd) * rstride + coff + rr]);
  }
  __syncthreads();
  unsigned short* o = out + (size_t)tb * TILE;
  // image positions whose kd lies in [kd0, kd0+64): cc*8+e = kd, cc = sw^(rr&15)
  for (int i = threadIdx.x; i < 8192; i += 256) {
    int rr = i >> 6;                 // 0..127
    int kloc = i & 63;               // kd - kd0
    int kd = kd0 + kloc;
    int cc = kd >> 3, e = kd & 7;
    int sw = cc ^ (rr & 15);
    o[rr * 128 + (sw << 3) + e] = tl[kloc * 130 + rr];
  }
}

// ---------------------------------------------------------------------------
// MFMA helper: wave tile = 16 rows x 64 cols (4 tiles of 16x16), K=128 in 4
// steps of 32. LDS: 16B chunks XOR-swizzled [row*128 + ((c^(row&15))<<3)].
// ---------------------------------------------------------------------------
__device__ __forceinline__ void mfma4(const unsigned short* As, const unsigned short* Bs,
                                      int rowbase, int colbase, int quad, int l16,
                                      f32x4 (&acc)[4]) {
#pragma unroll
  for (int kk = 0; kk < 4; ++kk) {
    int cb = kk * 4 + quad;
    int row = rowbase + l16;
    bf16x8 a = __builtin_bit_cast(bf16x8, *(const uint4*)&As[row * 128 + ((cb ^ (row & 15)) << 3)]);
    bf16x8 bb[4];
#pragma unroll
    for (int ct = 0; ct < 4; ++ct) {
      int n = colbase + ct * 16 + l16;
      bb[ct] = __builtin_bit_cast(bf16x8, *(const uint4*)&Bs[n * 128 + ((cb ^ (n & 15)) << 3)]);
    }
#pragma unroll
    for (int ct = 0; ct < 4; ++ct)
      acc[ct] = __builtin_amdgcn_mfma_f32_16x16x32_bf16(a, bb[ct], acc[ct], 0, 0, 0);
  }
}

// ---------------------------------------------------------------------------
// Fence-free per-batch barrier (R10-proven): kv stores are agent-scope
// atomics (write through to LLC); __syncthreads drains each wave's stores
// before the counter bump. 32 blocks per group.
// ---------------------------------------------------------------------------
__device__ __forceinline__ void grid_barrier(unsigned* cnt, unsigned target) {
  __syncthreads();
  if (threadIdx.x == 0) {
    __hip_atomic_fetch_add(cnt, 1u, __ATOMIC_RELAXED, __HIP_MEMORY_SCOPE_AGENT);
    while (__hip_atomic_load(cnt, __ATOMIC_RELAXED, __HIP_MEMORY_SCOPE_AGENT) < target)
      __builtin_amdgcn_s_sleep(4);
  }
  __syncthreads();
}

// ---------------------------------------------------------------------------
// Persistent mega-kernel: x-init + all 6 layers + fc head.
// grid = 256 blocks x 384 thr (6 waves); block owns 48 rows; 1 block/CU.
// Prologue computes x in-block with 8 threads/row (parallel syndrome, shfl
// reduce) straight into registers. Bs = 3-buffer ring (96 KB). kv: one
// buffer per layer -> attention gather uses normal cached vector loads.
// K/V cross blocks via agent-scope atomic stores; per-batch barrier.
// LDS: As 12K + Bs 96K + Cs 12K + KVs 24K + sKeys 6K + red 0.8K ~= 151 KB.
// ---------------------------------------------------------------------------
__global__ void __launch_bounds__(384) mega_kernel(
    const float* __restrict__ r_t, const float* __restrict__ se,
    unsigned short* __restrict__ kvbase, const unsigned short* __restrict__ wbf,
    const float* __restrict__ g1, const float* __restrict__ b1,
    const float* __restrict__ g2, const float* __restrict__ b2,
    const int* __restrict__ tt, const float* __restrict__ table,
    const int* __restrict__ adj, const int* __restrict__ adjc,
    const float* __restrict__ fcw, const float* __restrict__ fcb,
    float* __restrict__ out, unsigned* barrier_cnt) {
  __shared__ unsigned short As[RPB * 128];      // 12 KB
  __shared__ unsigned short Bs[3][TILE];        // 96 KB (ring)
  __shared__ unsigned short Cs[RPB * 128];      // 12 KB (Q, then FFN hf)
  __shared__ unsigned short KVs[RPB * 256];     // 24 KB (K|V repack)
  __shared__ float red1[2][RPB], red2[2][RPB];
  __shared__ float nodeS[RPB];
  __shared__ int sKeys[RPB * LKEY];             // 6 KB
  __shared__ int sCnt[RPB];
  const int row0 = blockIdx.x * RPB;
  const int b = row0 / S_;
  const int bS = b * S_;
  const int t = threadIdx.x, w = t >> 6, lane = t & 63, quad = lane >> 4, l16 = lane & 15;
  const int wr = w >> 1, wc = w & 1;
  const int rowbase = wr * 16, colbase = wc * 64;
  const int tbase = tt[b] * D_;
  unsigned* bcnt = barrier_cnt + b * 32;  // per-batch counter, 128 B apart

  // prime the pipeline: layer-0 K,V,Q tiles -> Bs[0..2]
  issue_tile(wbf + 0 * TILE, Bs[0], w, lane);
  issue_tile(wbf + 1 * TILE, Bs[1], w, lane);
  issue_tile(wbf + 2 * TILE, Bs[2], w, lane);

  // ---- prologue: adjacency cache, node values (8 thr/row), x -> registers -
  if (t < RPB) {
    int c = adjc[row0 + t - bS];
    sCnt[t] = c < MAXDEG ? c : MAXDEG;
  }
  for (int i = t; i < RPB * LKEY; i += 384) {
    int r = i / LKEY, j = i % LKEY;
    sKeys[i] = adj[(row0 + r - bS) * MAXDEG + j];  // tail values unused (clamped)
  }
  __syncthreads();
  {  // task = (row rL, slot p): 48 x 8 = 384
    const int rL = t >> 3, p = t & 7;
    const int s = row0 + rL - bS;
    float node;
    if (s < N_) {
      node = fabsf(r_t[b * N_ + s]);
    } else {
      const int cnt = sCnt[rL];
      float sum = 0.f;
      for (int j = p; j < cnt; j += 8) {
        int k = (j < LKEY) ? sKeys[rL * LKEY + j] : adj[s * MAXDEG + j];
        if (k < N_) {
          float r = r_t[b * N_ + k];
          sum += (r < 0.f) ? 1.f : (r > 0.f ? 0.f : 0.5f);  // bits = 0.5*(1-sign)
        }
      }
      sum += __shfl_xor(sum, 1, 16);  // reduce over the 8 slots (within 16-grp)
      sum += __shfl_xor(sum, 2, 16);
      sum += __shfl_xor(sum, 4, 16);
      node = fmodf(sum, 2.0f);
    }
    if (p == 0) nodeS[rL] = node;
  }
  __syncthreads();
  // persistent x in registers (MFMA C-layout): x = te * se * node
  f32x4 xreg[4];
#pragma unroll
  for (int ct = 0; ct < 4; ++ct)
#pragma unroll
    for (int i = 0; i < 4; ++i) {
      int rowL = rowbase + quad * 4 + i;
      int s = row0 + rowL - bS;
      int col = colbase + ct * 16 + l16;
      xreg[ct][i] = table[tbase + col] * se[(size_t)s * D_ + col] * nodeS[rowL];
    }

  for (int l = 0; l < L_; ++l) {
    const unsigned short* wt = wbf + (size_t)l * WLAYER;
    const float* g1l = g1 + l * D_;
    const float* b1l = b1 + l * D_;
    const float* g2l = g2 + l * D_;
    const float* b2l = b2 + l * D_;
    unsigned short* kv = kvbase + (size_t)l * KVSZ;  // per-layer buffer

    // ------------- LN1 (one-pass var) on register x -> bf16 h in As --------
    float mu1[4], rs1[4];
#pragma unroll
    for (int i = 0; i < 4; ++i) {
      float s = 0.f, sq = 0.f;
#pragma unroll
      for (int ct = 0; ct < 4; ++ct) { s += xreg[ct][i]; sq += xreg[ct][i] * xreg[ct][i]; }
      for (int off = 1; off < 16; off <<= 1) { s += __shfl_xor(s, off); sq += __shfl_xor(sq, off); }
      if (l16 == 0) { red1[wc][rowbase + quad * 4 + i] = s; red2[wc][rowbase + quad * 4 + i] = sq; }
    }
    __syncthreads();
#pragma unroll
    for (int i = 0; i < 4; ++i) {
      int r = rowbase + quad * 4 + i;
      float mu = (red1[0][r] + red1[1][r]) * (1.f / 128.f);
      float var = (red2[0][r] + red2[1][r]) * (1.f / 128.f) - mu * mu;
      mu1[i] = mu;
      rs1[i] = rsqrtf(var + 1e-5f);
    }
#pragma unroll
    for (int ct = 0; ct < 4; ++ct)
#pragma unroll
      for (int i = 0; i < 4; ++i) {
        int rowL = rowbase + quad * 4 + i;
        int col = colbase + ct * 16 + l16;
        float h = (xreg[ct][i] - mu1[i]) * rs1[i] * g1l[col] + b1l[col];
        As[rowL * 128 + (((col >> 3) ^ (rowL & 15)) << 3) + (col & 7)] = f2bf(h);
      }
    __syncthreads();  // As(h) visible; K,V,Q tiles drained

    // ------------- QKV: three barrier-free MFMA stages ---------------------
    {  // K -> KVs[:,0:128)  (wave-private region)
      f32x4 acc[4];
#pragma unroll
      for (int j = 0; j < 4; ++j) acc[j] = f32x4{0.f, 0.f, 0.f, 0.f};
      mfma4(As, Bs[0], rowbase, colbase, quad, l16, acc);
#pragma unroll
      for (int ct = 0; ct < 4; ++ct)
#pragma unroll
        for (int i = 0; i < 4; ++i) {
          int rowL = rowbase + quad * 4 + i;
          KVs[rowL * 256 + colbase + ct * 16 + l16] = f2bf(acc[ct][i]);
        }
    }
    {  // V -> KVs[:,128:256)
      f32x4 acc[4];
#pragma unroll
      for (int j = 0; j < 4; ++j) acc[j] = f32x4{0.f, 0.f, 0.f, 0.f};
      mfma4(As, Bs[1], rowbase, colbase, quad, l16, acc);
#pragma unroll
      for (int ct = 0; ct < 4; ++ct)
#pragma unroll
        for (int i = 0; i < 4; ++i) {
          int rowL = rowbase + quad * 4 + i;
          KVs[rowL * 256 + 128 + colbase + ct * 16 + l16] = f2bf(acc[ct][i]);
        }
    }
    {  // Q -> Cs (swizzled A-layout, kept for attention)
      f32x4 acc[4];
#pragma unroll
      for (int j = 0; j < 4; ++j) acc[j] = f32x4{0.f, 0.f, 0.f, 0.f};
      mfma4(As, Bs[2], rowbase, colbase, quad, l16, acc);
#pragma unroll
      for (int ct = 0; ct < 4; ++ct)
#pragma unroll
        for (int i = 0; i < 4; ++i) {
          int rowL = rowbase + quad * 4 + i;
          int col = colbase + ct * 16 + l16;
          Cs[rowL * 128 + (((col >> 3) ^ (rowL & 15)) << 3) + (col & 7)] = f2bf(acc[ct][i]);
        }
    }
    __syncthreads();  // KVs complete block-wide
    for (int i = t; i < RPB * 128; i += 384) {  // 128 dwords/row: K|V
      int rL = i >> 7, cw = i & 127;
      unsigned u = *(const unsigned*)&KVs[rL * 256 + cw * 2];
      __hip_atomic_store((unsigned*)&kv[(size_t)(row0 + rL) * 256 + cw * 2],
                         u, __ATOMIC_RELAXED, __HIP_MEMORY_SCOPE_AGENT);
    }

    // -------- per-batch fence-free barrier: batch kv visible ---------------
    grid_barrier(bcnt, (unsigned)(BPB * (l + 1)));

    // Wo + W1c0 + W2c0 (96 KB) all land under the attention gather
    issue_tile(wt + 3 * TILE, Bs[0], w, lane);
    issue_tile(wt + 4 * TILE, Bs[1], w, lane);
    issue_tile(wt + 5 * TILE, Bs[2], w, lane);

    // ------- attention (48 rows x 8 heads, one per thread; cached loads) ---
    {
      const int rL = t >> 3, h = t & 7;
      const int s = row0 + rL - bS;
      const int cnt = sCnt[rL];
      float q[16];
      {
        u16x8 qa = *(const u16x8*)&Cs[rL * 128 + (((2 * h) ^ (rL & 15)) << 3)];
        u16x8 qb = *(const u16x8*)&Cs[rL * 128 + (((2 * h + 1) ^ (rL & 15)) << 3)];
#pragma unroll
        for (int j = 0; j < 8; ++j) { q[j] = bf2f(qa[j]); q[8 + j] = bf2f(qb[j]); }
      }
      float m = -1e30f, lsum = 0.f;
      float o16[16];
#pragma unroll
      for (int j = 0; j < 16; ++j) o16[j] = 0.f;
      for (int jb = 0; jb < cnt; jb += 4) {  // 4 neighbors in flight
        u16x8 K[4][2], V[4][2];
#pragma unroll
        for (int u = 0; u < 4; ++u) {
          int j = jb + u;
          int key = 0;
          if (j < cnt) key = (j < LKEY) ? sKeys[rL * LKEY + j] : adj[s * MAXDEG + j];
          const u16x8* kp = (const u16x8*)(kv + (size_t)(bS + key) * 256 + h * 16);
          K[u][0] = kp[0];  K[u][1] = kp[1];    // K: 16 halves
          V[u][0] = kp[16]; V[u][1] = kp[17];   // V: +128 halves
        }
#pragma unroll
        for (int u = 0; u < 4; ++u) {
          float dot = 0.f;
#pragma unroll
          for (int j = 0; j < 8; ++j) {
            dot = fmaf(q[j], bf2f(K[u][0][j]), dot);
            dot = fmaf(q[8 + j], bf2f(K[u][1][j]), dot);
          }
          dot *= 0.25f;  // 1/sqrt(HD)
          if (jb + u >= cnt) dot = -1e30f;
          const float mn = fmaxf(m, dot);
          const float rescale = __expf(m - mn);
          const float e = __expf(dot - mn);
          lsum = lsum * rescale + e;
#pragma unroll
          for (int j = 0; j < 8; ++j) {
            o16[j]     = o16[j]     * rescale + e * bf2f(V[u][0][j]);
            o16[8 + j] = o16[8 + j] * rescale + e * bf2f(V[u][1][j]);
          }
          m = mn;
        }
      }
      const float inv = 1.f / lsum;
      u16x8 pk0, pk1;
#pragma unroll
      for (int j = 0; j < 8; ++j) {
        pk0[j] = f2bf(o16[j] * inv);
        pk1[j] = f2bf(o16[8 + j] * inv);
      }
      *(u16x8*)&As[rL * 128 + (((2 * h) ^ (rL & 15)) << 3)] = pk0;
      *(u16x8*)&As[rL * 128 + (((2 * h + 1) ^ (rL & 15)) << 3)] = pk1;
    }
    __syncthreads();  // As(o) visible; Wo/W1c0/W2c0 drained

    // ---------------- Wo; x'; LN2*te -> As ---------------------------------
    f32x4 acc1[4];
#pragma unroll
    for (int j = 0; j < 4; ++j) acc1[j] = f32x4{0.f, 0.f, 0.f, 0.f};
    mfma4(As, Bs[0], rowbase, colbase, quad, l16, acc1);
    f32x4 xp[4];
#pragma unroll
    for (int ct = 0; ct < 4; ++ct)
#pragma unroll
      for (int i = 0; i < 4; ++i) xp[ct][i] = xreg[ct][i] + acc1[ct][i];
    float mu_[4], rs_[4];
#pragma unroll
    for (int i = 0; i < 4; ++i) {
      float s = 0.f, sq = 0.f;
#pragma unroll
      for (int ct = 0; ct < 4; ++ct) { s += xp[ct][i]; sq += xp[ct][i] * xp[ct][i]; }
      for (int off = 1; off < 16; off <<= 1) { s += __shfl_xor(s, off); sq += __shfl_xor(sq, off); }
      if (l16 == 0) { red1[wc][rowbase + quad * 4 + i] = s; red2[wc][rowbase + quad * 4 + i] = sq; }
    }
    __syncthreads();  // red visible; also all As(o) reads done
#pragma unroll
    for (int i = 0; i < 4; ++i) {
      int r = rowbase + quad * 4 + i;
      float mu = (red1[0][r] + red1[1][r]) * (1.f / 128.f);
      float var = (red2[0][r] + red2[1][r]) * (1.f / 128.f) - mu * mu;
      mu_[i] = mu;
      rs_[i] = rsqrtf(var + 1e-5f);
    }
#pragma unroll
    for (int ct = 0; ct < 4; ++ct)
#pragma unroll
      for (int i = 0; i < 4; ++i) {
        int rowL = rowbase + quad * 4 + i;
        int col = colbase + ct * 16 + l16;
        float h2 = (xp[ct][i] - mu_[i]) * rs_[i] * g2l[col] + b2l[col];
        h2 *= table[tbase + col];
        As[rowL * 128 + (((col >> 3) ^ (rowL & 15)) << 3) + (col & 7)] = f2bf(h2);
      }
    __syncthreads();  // h2 visible

    // ---------------- FFN: ring-scheduled stages ---------------------------
    // buffer ring: c0 W1@1 W2@2; c1 W1@0 W2@1; c2 W1@2 W2@0; c3 W1@1 W2@2.
    f32x4 acc2[4];
#pragma unroll
    for (int j = 0; j < 4; ++j) acc2[j] = f32x4{0.f, 0.f, 0.f, 0.f};
    const int bufW1[4] = {1, 0, 2, 1};
    const int bufW2[4] = {2, 1, 0, 2};
#pragma unroll
    for (int c = 0; c < 4; ++c) {
      f32x4 accF[4];
#pragma unroll
      for (int j = 0; j < 4; ++j) accF[j] = f32x4{0.f, 0.f, 0.f, 0.f};
      mfma4(As, Bs[bufW1[c]], rowbase, colbase, quad, l16, accF);
#pragma unroll
      for (int ct = 0; ct < 4; ++ct)
#pragma unroll
        for (int i = 0; i < 4; ++i) {
          int rowL = rowbase + quad * 4 + i;
          int col = colbase + ct * 16 + l16;
          Cs[rowL * 128 + (((col >> 3) ^ (rowL & 15)) << 3) + (col & 7)] =
              f2bf(fmaxf(accF[ct][i], 0.f));
        }
      __syncthreads();  // hf visible; W1c reads done; prior issues drained
      if (c < 3) issue_tile(wt + (4 + 2 * (c + 1)) * TILE, Bs[bufW1[c + 1]], w, lane);
      else if (l < L_ - 1) issue_tile(wt + WLAYER + 0 * TILE, Bs[0], w, lane);  // next K
      mfma4(Cs, Bs[bufW2[c]], rowbase, colbase, quad, l16, acc2);
      __syncthreads();  // Cs reads done (safe rewrite); W2c reads done
      if (c < 3) issue_tile(wt + (5 + 2 * (c + 1)) * TILE, Bs[bufW2[c + 1]], w, lane);
      else if (l < L_ - 1) {
        issue_tile(wt + WLAYER + 1 * TILE, Bs[1], w, lane);  // next V
        issue_tile(wt + WLAYER + 2 * TILE, Bs[2], w, lane);  // next Q
      }
    }
    // epilogue: x'' = x' + ffn (registers only)
    if (l < L_ - 1) {
#pragma unroll
      for (int ct = 0; ct < 4; ++ct)
#pragma unroll
        for (int i = 0; i < 4; ++i) xreg[ct][i] = xp[ct][i] + acc2[ct][i];
    } else {
      float pr[4] = {0.f, 0.f, 0.f, 0.f};
#pragma unroll
      for (int ct = 0; ct < 4; ++ct)
#pragma unroll
        for (int i = 0; i < 4; ++i)
          pr[i] += (xp[ct][i] + acc2[ct][i]) * fcw[colbase + ct * 16 + l16];
#pragma unroll
      for (int i = 0; i < 4; ++i) {
        float s = pr[i];
        for (int off = 1; off < 16; off <<= 1) s += __shfl_xor(s, off);
        if (l16 == 0) red1[wc][rowbase + quad * 4 + i] = s;
      }
      __syncthreads();
      if (wc == 0 && l16 == 0)
#pragma unroll
        for (int i = 0; i < 4; ++i) {
          int r = rowbase + quad * 4 + i;
          out[row0 + r] = red1[0][r] + red1[1][r] + fcb[0];
        }
    }
  }
}

// ---------------------------------------------------------------------------
extern "C" void kernel_launch(void* const* d_in, const int* in_sizes, int n_in,
                              void* d_out, int out_size, void* d_ws, size_t ws_size,
                              hipStream_t stream) {
  const float* r_t       = (const float*)d_in[0];
  const int*   t         = (const int*)d_in[1];
  const int*   pcm       = (const int*)d_in[2];
  const float* src_embed = (const float*)d_in[4];
  const float* time_tab  = (const float*)d_in[5];
  const float* Wq = (const float*)d_in[6];
  const float* Wk = (const float*)d_in[7];
  const float* Wv = (const float*)d_in[8];
  const float* Wo = (const float*)d_in[9];
  const float* W1 = (const float*)d_in[10];
  const float* W2 = (const float*)d_in[11];
  const float* g1 = (const float*)d_in[12];
  const float* b1 = (const float*)d_in[13];
  const float* g2 = (const float*)d_in[14];
  const float* b2 = (const float*)d_in[15];
  const float* fc_w = (const float*)d_in[16];
  const float* fc_b = (const float*)d_in[17];
  float* out = (float*)d_out;

  char* ws = (char*)d_ws;
  size_t off = 0;
  auto alloc = [&](size_t bytes) -> void* {
    void* p = ws + off;
    off = (off + bytes + 255) & ~(size_t)255;
    return p;
  };
  unsigned short* kv   = (unsigned short*)alloc((size_t)L_ * KVSZ * 2);  // per-layer
  int*            adj  = (int*)alloc((size_t)S_ * MAXDEG * 4);
  int*            adjc = (int*)alloc((size_t)S_ * 4);
  unsigned short* wbf  = (unsigned short*)alloc((size_t)L_ * WLAYER * 2);
  unsigned*       bcnt = (unsigned*)alloc(8 * 32 * 4);

  wconv_kernel<<<L_ * NTILE * 2, 256, 0, stream>>>(Wq, Wk, Wv, Wo, W1, W2, wbf, adj, adjc, bcnt);
  adj_build<<<M_, 64, 0, stream>>>(pcm, adj, adjc);
  mega_kernel<<<NBLK, 384, 0, stream>>>(r_t, src_embed, kv, wbf, g1, b1, g2, b2,
                                        t, time_tab, adj, adjc, fc_w, fc_b, out, bcnt);
}

// Round 19
// 242.928 us; speedup vs baseline: 2.5346x; 1.0240x over previous
//
#include <hip/hip_runtime.h>
#include <cmath>
#include <cstdint>

// Problem constants (from reference)
constexpr int B_ = 8, N_ = 1024, M_ = 512, D_ = 128, S_ = 1536, L_ = 6, DFF_ = 512;
constexpr int ROWS = B_ * S_;    // 12288
constexpr int MAXDEG = 64;       // max attention row degree (actual ~4-25)
constexpr int LKEY = 32;         // LDS-cached keys per row
constexpr int RPB  = 48;         // rows per block
constexpr int NBLK = ROWS / RPB; // 256 persistent blocks (1/CU, all resident)
constexpr int BPB  = S_ / RPB;   // 32 blocks per batch (barrier group)
constexpr int NTILE = 12;        // weight tiles per layer, in stage order
constexpr int TILE  = 128 * 128; // halfwords per tile (LDS image, 32 KB)
constexpr int KVSZ  = ROWS * 256;// halfwords per kv layer-buffer
constexpr int WBLK  = L_ * NTILE * 2;  // 144 wconv half-tile blocks
constexpr int ABLK  = 128;             // adj blocks (4 check rows each)

typedef __bf16 bf16x8 __attribute__((ext_vector_type(8)));
typedef float  f32x4  __attribute__((ext_vector_type(4)));
typedef unsigned short u16x8 __attribute__((ext_vector_type(8)));

__device__ inline unsigned short f2bf(float f) {  // RNE fp32 -> bf16
  unsigned u = __float_as_uint(f);
  u += 0x7fffu + ((u >> 16) & 1u);
  return (unsigned short)(u >> 16);
}
__device__ inline float bf2f(unsigned short u) {
  return __uint_as_float(((unsigned)u) << 16);
}

// Direct global->LDS async copy, 16 B/lane (m97's lever).
__device__ __forceinline__ void async_ld16(const unsigned short* g, unsigned short* l) {
  __builtin_amdgcn_global_load_lds(
      (const __attribute__((address_space(1))) unsigned int*)(uintptr_t)g,
      (__attribute__((address_space(3))) unsigned int*)(unsigned)(uintptr_t)l,
      16, 0, 0);
}
// Issue one 32 KB tile (pre-swizzled LDS image) into a Bs buffer.
__device__ __forceinline__ void issue_tile(const unsigned short* tp, unsigned short* bs,
                                           int w, int lane) {
  for (int c = w; c < 32; c += 6)
    async_ld16(tp + c * 512 + lane * 8, bs + c * 512);
}

// ---------------------------------------------------------------------------
// Combined setup kernel (adjcnt/bcnt pre-zeroed via hipMemsetAsync):
//  blocks [0, WBLK): weight convert, one 64-kd half-tile each, via LDS
//    transpose staging (coalesced fp32 reads -> bf16 -> coalesced swizzled-
//    image writes). Tile/stage order: [0]=Wk^T [1]=Wv^T [2]=Wq^T [3]=Wo^T
//    [4+2c]=W1^T chunk c [5+2c]=W2^T chunk c.
//    Image: tile[rr*128 + ((cc^(rr&15))<<3) + e] = W^T[rr][cc*8+e].
//  blocks [WBLK, WBLK+ABLK): adjacency from pcm ROWS (coalesced), both
//    Tanner directions + self-edges via atomic append (order irrelevant:
//    softmax and mod-2 syndrome are permutation-invariant). exp(-1e9-max)
//    underflows to 0 in fp32 => sparse attention == dense masked softmax.
// ---------------------------------------------------------------------------
constexpr int WLAYER = NTILE * TILE;  // 196608 halfwords per layer

__global__ void setup_kernel(const float* __restrict__ Wq, const float* __restrict__ Wk,
                             const float* __restrict__ Wv, const float* __restrict__ Wo,
                             const float* __restrict__ W1, const float* __restrict__ W2,
                             unsigned short* __restrict__ out, const int* __restrict__ pcm,
                             int* __restrict__ adj, int* __restrict__ adjcnt) {
  int bid = blockIdx.x;
  if (bid >= WBLK) {  // ---- adjacency blocks: 4 check rows + 12 self-rows ----
    int ab = bid - WBLK;
    int c0 = ab * 4, lane = threadIdx.x & 63, sub = threadIdx.x >> 6;  // 4 subrows
    // self edges: rows [ab*12, ab*12+12)
    if (threadIdx.x < 12) {
      int s = ab * 12 + threadIdx.x;
      int slot = atomicAdd(&adjcnt[s], 1);
      if (slot < MAXDEG) adj[s * MAXDEG + slot] = s;
    }
    int c = c0 + sub;  // this thread-group's check row
    const int* row = pcm + c * N_;
    for (int base = 0; base < N_; base += 64) {
      int k = base + lane;
      if (row[k] != 0) {
        int s1 = atomicAdd(&adjcnt[N_ + c], 1);
        if (s1 < MAXDEG) adj[(N_ + c) * MAXDEG + s1] = k;
        int s2 = atomicAdd(&adjcnt[k], 1);
        if (s2 < MAXDEG) adj[k * MAXDEG + s2] = N_ + c;
      }
    }
    return;
  }
  // ---- weight-convert blocks ----
  __shared__ unsigned short tl[64 * 130];  // +2 pad breaks transpose conflicts
  int tb = bid >> 1, half = bid & 1;       // tile block, kd-half
  int l = tb / NTILE, tile = tb % NTILE;
  const int kd0 = half * 64;
  const float* src;
  int rstride, coff = 0;
  if (tile == 0)      { src = Wk + (size_t)l * D_ * D_;  rstride = D_; }
  else if (tile == 1) { src = Wv + (size_t)l * D_ * D_;  rstride = D_; }
  else if (tile == 2) { src = Wq + (size_t)l * D_ * D_;  rstride = D_; }
  else if (tile == 3) { src = Wo + (size_t)l * D_ * D_;  rstride = D_; }
  else {
    int c = (tile - 4) >> 1;
    if (((tile - 4) & 1) == 0) { src = W1 + (size_t)l * D_ * DFF_; rstride = DFF_; coff = c * 128; }
    else                       { src = W2 + (size_t)l * DFF_ * D_ + (size_t)c * 128 * D_; rstride = D_; }
  }
  for (int i = threadIdx.x; i < 8192; i += 256) {  // coalesced row reads
    int kd = i >> 7, rr = i & 127;
    tl[kd * 130 + rr] = f2bf(src[(size_t)(kd0 + kd) * rstride + coff + rr]);
  }
  __syncthreads();
  unsigned short* o = out + (size_t)tb * TILE;
  for (int i = threadIdx.x; i < 8192; i += 256) {
    int rr = i >> 6;                 // 0..127
    int kloc = i & 63;               // kd - kd0
    int kd = kd0 + kloc;
    int cc = kd >> 3, e = kd & 7;
    int sw = cc ^ (rr & 15);
    o[rr * 128 + (sw << 3) + e] = tl[kloc * 130 + rr];
  }
}

// ---------------------------------------------------------------------------
// MFMA helper: wave tile = 16 rows x 64 cols (4 tiles of 16x16), K=128 in 4
// steps of 32. LDS: 16B chunks XOR-swizzled [row*128 + ((c^(row&15))<<3)].
// ---------------------------------------------------------------------------
__device__ __forceinline__ void mfma4(const unsigned short* As, const unsigned short* Bs,
                                      int rowbase, int colbase, int quad, int l16,
                                      f32x4 (&acc)[4]) {
#pragma unroll
  for (int kk = 0; kk < 4; ++kk) {
    int cb = kk * 4 + quad;
    int row = rowbase + l16;
    bf16x8 a = __builtin_bit_cast(bf16x8, *(const uint4*)&As[row * 128 + ((cb ^ (row & 15)) << 3)]);
    bf16x8 bb[4];
#pragma unroll
    for (int ct = 0; ct < 4; ++ct) {
      int n = colbase + ct * 16 + l16;
      bb[ct] = __builtin_bit_cast(bf16x8, *(const uint4*)&Bs[n * 128 + ((cb ^ (n & 15)) << 3)]);
    }
#pragma unroll
    for (int ct = 0; ct < 4; ++ct)
      acc[ct] = __builtin_amdgcn_mfma_f32_16x16x32_bf16(a, bb[ct], acc[ct], 0, 0, 0);
  }
}

// ---------------------------------------------------------------------------
// Fence-free per-batch barrier (R10-proven): kv stores are agent-scope
// atomics (write through to LLC); __syncthreads drains each wave's stores
// before the counter bump. 32 blocks per group.
// ---------------------------------------------------------------------------
__device__ __forceinline__ void grid_barrier(unsigned* cnt, unsigned target) {
  __syncthreads();
  if (threadIdx.x == 0) {
    __hip_atomic_fetch_add(cnt, 1u, __ATOMIC_RELAXED, __HIP_MEMORY_SCOPE_AGENT);
    while (__hip_atomic_load(cnt, __ATOMIC_RELAXED, __HIP_MEMORY_SCOPE_AGENT) < target)
      __builtin_amdgcn_s_sleep(4);
  }
  __syncthreads();
}

// ---------------------------------------------------------------------------
// Persistent mega-kernel: x-init + all 6 layers + fc head.
// grid = 256 blocks x 384 thr (6 waves); block owns 48 rows; 1 block/CU.
// Prologue computes x in-block with 8 threads/row straight into registers.
// Bs = 3-buffer ring (96 KB). kv: one buffer per layer -> attention gather
// uses normal cached vector loads (neighbor reuse hits L2). K/V cross
// blocks via agent-scope atomic stores; per-batch fence-free barrier.
// LDS: As 12K + Bs 96K + Cs 12K + KVs 24K + sKeys 6K + red 0.8K ~= 151 KB.
// ---------------------------------------------------------------------------
__global__ void __launch_bounds__(384) mega_kernel(
    const float* __restrict__ r_t, const float* __restrict__ se,
    unsigned short* __restrict__ kvbase, const unsigned short* __restrict__ wbf,
    const float* __restrict__ g1, const float* __restrict__ b1,
    const float* __restrict__ g2, const float* __restrict__ b2,
    const int* __restrict__ tt, const float* __restrict__ table,
    const int* __restrict__ adj, const int* __restrict__ adjc,
    const float* __restrict__ fcw, const float* __restrict__ fcb,
    float* __restrict__ out, unsigned* barrier_cnt) {
  __shared__ unsigned short As[RPB * 128];      // 12 KB
  __shared__ unsigned short Bs[3][TILE];        // 96 KB (ring)
  __shared__ unsigned short Cs[RPB * 128];      // 12 KB (Q, then FFN hf)
  __shared__ unsigned short KVs[RPB * 256];     // 24 KB (K|V repack)
  __shared__ float red1[2][RPB], red2[2][RPB];
  __shared__ float nodeS[RPB];
  __shared__ int sKeys[RPB * LKEY];             // 6 KB
  __shared__ int sCnt[RPB];
  const int row0 = blockIdx.x * RPB;
  const int b = row0 / S_;
  const int bS = b * S_;
  const int t = threadIdx.x, w = t >> 6, lane = t & 63, quad = lane >> 4, l16 = lane & 15;
  const int wr = w >> 1, wc = w & 1;
  const int rowbase = wr * 16, colbase = wc * 64;
  const int tbase = tt[b] * D_;
  unsigned* bcnt = barrier_cnt + b * 32;  // per-batch counter, 128 B apart

  // prime the pipeline: layer-0 K,V,Q tiles -> Bs[0..2]
  issue_tile(wbf + 0 * TILE, Bs[0], w, lane);
  issue_tile(wbf + 1 * TILE, Bs[1], w, lane);
  issue_tile(wbf + 2 * TILE, Bs[2], w, lane);

  // ---- prologue: adjacency cache, node values (8 thr/row), x -> registers -
  if (t < RPB) {
    int c = adjc[row0 + t - bS];
    sCnt[t] = c < MAXDEG ? c : MAXDEG;
  }
  for (int i = t; i < RPB * LKEY; i += 384) {
    int r = i / LKEY, j = i % LKEY;
    sKeys[i] = adj[(row0 + r - bS) * MAXDEG + j];  // tail values unused (clamped)
  }
  __syncthreads();
  {  // task = (row rL, slot p): 48 x 8 = 384
    const int rL = t >> 3, p = t & 7;
    const int s = row0 + rL - bS;
    float node;
    if (s < N_) {
      node = fabsf(r_t[b * N_ + s]);
    } else {
      const int cnt = sCnt[rL];
      float sum = 0.f;
      for (int j = p; j < cnt; j += 8) {
        int k = (j < LKEY) ? sKeys[rL * LKEY + j] : adj[s * MAXDEG + j];
        if (k < N_) {
          float r = r_t[b * N_ + k];
          sum += (r < 0.f) ? 1.f : (r > 0.f ? 0.f : 0.5f);  // bits = 0.5*(1-sign)
        }
      }
      sum += __shfl_xor(sum, 1, 16);  // reduce over the 8 slots (within 16-grp)
      sum += __shfl_xor(sum, 2, 16);
      sum += __shfl_xor(sum, 4, 16);
      node = fmodf(sum, 2.0f);
    }
    if (p == 0) nodeS[rL] = node;
  }
  __syncthreads();
  // persistent x in registers (MFMA C-layout): x = te * se * node
  f32x4 xreg[4];
#pragma unroll
  for (int ct = 0; ct < 4; ++ct)
#pragma unroll
    for (int i = 0; i < 4; ++i) {
      int rowL = rowbase + quad * 4 + i;
      int s = row0 + rowL - bS;
      int col = colbase + ct * 16 + l16;
      xreg[ct][i] = table[tbase + col] * se[(size_t)s * D_ + col] * nodeS[rowL];
    }

  for (int l = 0; l < L_; ++l) {
    const unsigned short* wt = wbf + (size_t)l * WLAYER;
    const float* g1l = g1 + l * D_;
    const float* b1l = b1 + l * D_;
    const float* g2l = g2 + l * D_;
    const float* b2l = b2 + l * D_;
    unsigned short* kv = kvbase + (size_t)l * KVSZ;  // per-layer buffer

    // ------------- LN1 (one-pass var) on register x -> bf16 h in As --------
    float mu1[4], rs1[4];
#pragma unroll
    for (int i = 0; i < 4; ++i) {
      float s = 0.f, sq = 0.f;
#pragma unroll
      for (int ct = 0; ct < 4; ++ct) { s += xreg[ct][i]; sq += xreg[ct][i] * xreg[ct][i]; }
      for (int off = 1; off < 16; off <<= 1) { s += __shfl_xor(s, off); sq += __shfl_xor(sq, off); }
      if (l16 == 0) { red1[wc][rowbase + quad * 4 + i] = s; red2[wc][rowbase + quad * 4 + i] = sq; }
    }
    __syncthreads();
#pragma unroll
    for (int i = 0; i < 4; ++i) {
      int r = rowbase + quad * 4 + i;
      float mu = (red1[0][r] + red1[1][r]) * (1.f / 128.f);
      float var = (red2[0][r] + red2[1][r]) * (1.f / 128.f) - mu * mu;
      mu1[i] = mu;
      rs1[i] = rsqrtf(var + 1e-5f);
    }
#pragma unroll
    for (int ct = 0; ct < 4; ++ct)
#pragma unroll
      for (int i = 0; i < 4; ++i) {
        int rowL = rowbase + quad * 4 + i;
        int col = colbase + ct * 16 + l16;
        float h = (xreg[ct][i] - mu1[i]) * rs1[i] * g1l[col] + b1l[col];
        As[rowL * 128 + (((col >> 3) ^ (rowL & 15)) << 3) + (col & 7)] = f2bf(h);
      }
    __syncthreads();  // As(h) visible; K,V,Q tiles drained

    // ------------- QKV: three barrier-free MFMA stages ---------------------
    {  // K -> KVs[:,0:128)  (wave-private region)
      f32x4 acc[4];
#pragma unroll
      for (int j = 0; j < 4; ++j) acc[j] = f32x4{0.f, 0.f, 0.f, 0.f};
      mfma4(As, Bs[0], rowbase, colbase, quad, l16, acc);
#pragma unroll
      for (int ct = 0; ct < 4; ++ct)
#pragma unroll
        for (int i = 0; i < 4; ++i) {
          int rowL = rowbase + quad * 4 + i;
          KVs[rowL * 256 + colbase + ct * 16 + l16] = f2bf(acc[ct][i]);
        }
    }
    {  // V -> KVs[:,128:256)
      f32x4 acc[4];
#pragma unroll
      for (int j = 0; j < 4; ++j) acc[j] = f32x4{0.f, 0.f, 0.f, 0.f};
      mfma4(As, Bs[1], rowbase, colbase, quad, l16, acc);
#pragma unroll
      for (int ct = 0; ct < 4; ++ct)
#pragma unroll
        for (int i = 0; i < 4; ++i) {
          int rowL = rowbase + quad * 4 + i;
          KVs[rowL * 256 + 128 + colbase + ct * 16 + l16] = f2bf(acc[ct][i]);
        }
    }
    {  // Q -> Cs (swizzled A-layout, kept for attention)
      f32x4 acc[4];
#pragma unroll
      for (int j = 0; j < 4; ++j) acc[j] = f32x4{0.f, 0.f, 0.f, 0.f};
      mfma4(As, Bs[2], rowbase, colbase, quad, l16, acc);
#pragma unroll
      for (int ct = 0; ct < 4; ++ct)
#pragma unroll
        for (int i = 0; i < 4; ++i) {
          int rowL = rowbase + quad * 4 + i;
          int col = colbase + ct * 16 + l16;
          Cs[rowL * 128 + (((col >> 3) ^ (rowL & 15)) << 3) + (col & 7)] = f2bf(acc[ct][i]);
        }
    }
    __syncthreads();  // KVs complete block-wide
    for (int i = t; i < RPB * 128; i += 384) {  // 128 dwords/row: K|V
      int rL = i >> 7, cw = i & 127;
      unsigned u = *(const unsigned*)&KVs[rL * 256 + cw * 2];
      __hip_atomic_store((unsigned*)&kv[(size_t)(row0 + rL) * 256 + cw * 2],
                         u, __ATOMIC_RELAXED, __HIP_MEMORY_SCOPE_AGENT);
    }

    // -------- per-batch fence-free barrier: batch kv visible ---------------
    grid_barrier(bcnt, (unsigned)(BPB * (l + 1)));

    // Wo + W1c0 + W2c0 (96 KB) all land under the attention gather
    issue_tile(wt + 3 * TILE, Bs[0], w, lane);
    issue_tile(wt + 4 * TILE, Bs[1], w, lane);
    issue_tile(wt + 5 * TILE, Bs[2], w, lane);

    // ------- attention (48 rows x 8 heads, one per thread; cached loads) ---
    {
      const int rL = t >> 3, h = t & 7;
      const int s = row0 + rL - bS;
      const int cnt = sCnt[rL];
      float q[16];
      {
        u16x8 qa = *(const u16x8*)&Cs[rL * 128 + (((2 * h) ^ (rL & 15)) << 3)];
        u16x8 qb = *(const u16x8*)&Cs[rL * 128 + (((2 * h + 1) ^ (rL & 15)) << 3)];
#pragma unroll
        for (int j = 0; j < 8; ++j) { q[j] = bf2f(qa[j]); q[8 + j] = bf2f(qb[j]); }
      }
      float m = -1e30f, lsum = 0.f;
      float o16[16];
#pragma unroll
      for (int j = 0; j < 16; ++j) o16[j] = 0.f;
      for (int jb = 0; jb < cnt; jb += 4) {  // 4 neighbors in flight
        u16x8 K[4][2], V[4][2];
#pragma unroll
        for (int u = 0; u < 4; ++u) {
          int j = jb + u;
          int key = 0;
          if (j < cnt) key = (j < LKEY) ? sKeys[rL * LKEY + j] : adj[s * MAXDEG + j];
          const u16x8* kp = (const u16x8*)(kv + (size_t)(bS + key) * 256 + h * 16);
          K[u][0] = kp[0];  K[u][1] = kp[1];    // K: 16 halves
          V[u][0] = kp[16]; V[u][1] = kp[17];   // V: +128 halves
        }
#pragma unroll
        for (int u = 0; u < 4; ++u) {
          float dot = 0.f;
#pragma unroll
          for (int j = 0; j < 8; ++j) {
            dot = fmaf(q[j], bf2f(K[u][0][j]), dot);
            dot = fmaf(q[8 + j], bf2f(K[u][1][j]), dot);
          }
          dot *= 0.25f;  // 1/sqrt(HD)
          if (jb + u >= cnt) dot = -1e30f;
          const float mn = fmaxf(m, dot);
          const float rescale = __expf(m - mn);
          const float e = __expf(dot - mn);
          lsum = lsum * rescale + e;
#pragma unroll
          for (int j = 0; j < 8; ++j) {
            o16[j]     = o16[j]     * rescale + e * bf2f(V[u][0][j]);
            o16[8 + j] = o16[8 + j] * rescale + e * bf2f(V[u][1][j]);
          }
          m = mn;
        }
      }
      const float inv = 1.f / lsum;
      u16x8 pk0, pk1;
#pragma unroll
      for (int j = 0; j < 8; ++j) {
        pk0[j] = f2bf(o16[j] * inv);
        pk1[j] = f2bf(o16[8 + j] * inv);
      }
      *(u16x8*)&As[rL * 128 + (((2 * h) ^ (rL & 15)) << 3)] = pk0;
      *(u16x8*)&As[rL * 128 + (((2 * h + 1) ^ (rL & 15)) << 3)] = pk1;
    }
    __syncthreads();  // As(o) visible; Wo/W1c0/W2c0 drained

    // ---------------- Wo; x'; LN2*te -> As ---------------------------------
    f32x4 acc1[4];
#pragma unroll
    for (int j = 0; j < 4; ++j) acc1[j] = f32x4{0.f, 0.f, 0.f, 0.f};
    mfma4(As, Bs[0], rowbase, colbase, quad, l16, acc1);
    f32x4 xp[4];
#pragma unroll
    for (int ct = 0; ct < 4; ++ct)
#pragma unroll
      for (int i = 0; i < 4; ++i) xp[ct][i] = xreg[ct][i] + acc1[ct][i];
    float mu_[4], rs_[4];
#pragma unroll
    for (int i = 0; i < 4; ++i) {
      float s = 0.f, sq = 0.f;
#pragma unroll
      for (int ct = 0; ct < 4; ++ct) { s += xp[ct][i]; sq += xp[ct][i] * xp[ct][i]; }
      for (int off = 1; off < 16; off <<= 1) { s += __shfl_xor(s, off); sq += __shfl_xor(sq, off); }
      if (l16 == 0) { red1[wc][rowbase + quad * 4 + i] = s; red2[wc][rowbase + quad * 4 + i] = sq; }
    }
    __syncthreads();  // red visible; also all As(o) reads done
#pragma unroll
    for (int i = 0; i < 4; ++i) {
      int r = rowbase + quad * 4 + i;
      float mu = (red1[0][r] + red1[1][r]) * (1.f / 128.f);
      float var = (red2[0][r] + red2[1][r]) * (1.f / 128.f) - mu * mu;
      mu_[i] = mu;
      rs_[i] = rsqrtf(var + 1e-5f);
    }
#pragma unroll
    for (int ct = 0; ct < 4; ++ct)
#pragma unroll
      for (int i = 0; i < 4; ++i) {
        int rowL = rowbase + quad * 4 + i;
        int col = colbase + ct * 16 + l16;
        float h2 = (xp[ct][i] - mu_[i]) * rs_[i] * g2l[col] + b2l[col];
        h2 *= table[tbase + col];
        As[rowL * 128 + (((col >> 3) ^ (rowL & 15)) << 3) + (col & 7)] = f2bf(h2);
      }
    __syncthreads();  // h2 visible

    // ---------------- FFN: ring-scheduled stages ---------------------------
    // buffer ring: c0 W1@1 W2@2; c1 W1@0 W2@1; c2 W1@2 W2@0; c3 W1@1 W2@2.
    f32x4 acc2[4];
#pragma unroll
    for (int j = 0; j < 4; ++j) acc2[j] = f32x4{0.f, 0.f, 0.f, 0.f};
    const int bufW1[4] = {1, 0, 2, 1};
    const int bufW2[4] = {2, 1, 0, 2};
#pragma unroll
    for (int c = 0; c < 4; ++c) {
      f32x4 accF[4];
#pragma unroll
      for (int j = 0; j < 4; ++j) accF[j] = f32x4{0.f, 0.f, 0.f, 0.f};
      mfma4(As, Bs[bufW1[c]], rowbase, colbase, quad, l16, accF);
#pragma unroll
      for (int ct = 0; ct < 4; ++ct)
#pragma unroll
        for (int i = 0; i < 4; ++i) {
          int rowL = rowbase + quad * 4 + i;
          int col = colbase + ct * 16 + l16;
          Cs[rowL * 128 + (((col >> 3) ^ (rowL & 15)) << 3) + (col & 7)] =
              f2bf(fmaxf(accF[ct][i], 0.f));
        }
      __syncthreads();  // hf visible; W1c reads done; prior issues drained
      if (c < 3) issue_tile(wt + (4 + 2 * (c + 1)) * TILE, Bs[bufW1[c + 1]], w, lane);
      else if (l < L_ - 1) issue_tile(wt + WLAYER + 0 * TILE, Bs[0], w, lane);  // next K
      mfma4(Cs, Bs[bufW2[c]], rowbase, colbase, quad, l16, acc2);
      __syncthreads();  // Cs reads done (safe rewrite); W2c reads done
      if (c < 3) issue_tile(wt + (5 + 2 * (c + 1)) * TILE, Bs[bufW2[c + 1]], w, lane);
      else if (l < L_ - 1) {
        issue_tile(wt + WLAYER + 1 * TILE, Bs[1], w, lane);  // next V
        issue_tile(wt + WLAYER + 2 * TILE, Bs[2], w, lane);  // next Q
      }
    }
    // epilogue: x'' = x' + ffn (registers only)
    if (l < L_ - 1) {
#pragma unroll
      for (int ct = 0; ct < 4; ++ct)
#pragma unroll
        for (int i = 0; i < 4; ++i) xreg[ct][i] = xp[ct][i] + acc2[ct][i];
    } else {
      float pr[4] = {0.f, 0.f, 0.f, 0.f};
#pragma unroll
      for (int ct = 0; ct < 4; ++ct)
#pragma unroll
        for (int i = 0; i < 4; ++i)
          pr[i] += (xp[ct][i] + acc2[ct][i]) * fcw[colbase + ct * 16 + l16];
#pragma unroll
      for (int i = 0; i < 4; ++i) {
        float s = pr[i];
        for (int off = 1; off < 16; off <<= 1) s += __shfl_xor(s, off);
        if (l16 == 0) red1[wc][rowbase + quad * 4 + i] = s;
      }
      __syncthreads();
      if (wc == 0 && l16 == 0)
#pragma unroll
        for (int i = 0; i < 4; ++i) {
          int r = rowbase + quad * 4 + i;
          out[row0 + r] = red1[0][r] + red1[1][r] + fcb[0];
        }
    }
  }
}

// ---------------------------------------------------------------------------
extern "C" void kernel_launch(void* const* d_in, const int* in_sizes, int n_in,
                              void* d_out, int out_size, void* d_ws, size_t ws_size,
                              hipStream_t stream) {
  const float* r_t       = (const float*)d_in[0];
  const int*   t         = (const int*)d_in[1];
  const int*   pcm       = (const int*)d_in[2];
  const float* src_embed = (const float*)d_in[4];
  const float* time_tab  = (const float*)d_in[5];
  const float* Wq = (const float*)d_in[6];
  const float* Wk = (const float*)d_in[7];
  const float* Wv = (const float*)d_in[8];
  const float* Wo = (const float*)d_in[9];
  const float* W1 = (const float*)d_in[10];
  const float* W2 = (const float*)d_in[11];
  const float* g1 = (const float*)d_in[12];
  const float* b1 = (const float*)d_in[13];
  const float* g2 = (const float*)d_in[14];
  const float* b2 = (const float*)d_in[15];
  const float* fc_w = (const float*)d_in[16];
  const float* fc_b = (const float*)d_in[17];
  float* out = (float*)d_out;

  char* ws = (char*)d_ws;
  size_t off = 0;
  auto alloc = [&](size_t bytes) -> void* {
    void* p = ws + off;
    off = (off + bytes + 255) & ~(size_t)255;
    return p;
  };
  unsigned short* kv   = (unsigned short*)alloc((size_t)L_ * KVSZ * 2);  // per-layer
  int*            adj  = (int*)alloc((size_t)S_ * MAXDEG * 4);
  // adjcnt + bcnt contiguous -> one memset clears both
  int*            adjc = (int*)alloc((size_t)S_ * 4 + 8 * 32 * 4);
  unsigned*       bcnt = (unsigned*)(adjc + S_);
  unsigned short* wbf  = (unsigned short*)alloc((size_t)L_ * WLAYER * 2);

  hipMemsetAsync(adjc, 0, (size_t)S_ * 4 + 8 * 32 * 4, stream);
  setup_kernel<<<WBLK + ABLK, 256, 0, stream>>>(Wq, Wk, Wv, Wo, W1, W2, wbf,
                                                pcm, adj, adjc);
  mega_kernel<<<NBLK, 384, 0, stream>>>(r_t, src_embed, kv, wbf, g1, b1, g2, b2,
                                        t, time_tab, adj, adjc, fc_w, fc_b, out, bcnt);
}